// Round 2
// baseline (973.844 us; speedup 1.0000x reference)
//
#include <hip/hip_runtime.h>
#include <hip/hip_bf16.h>

using bf16 = __hip_bfloat16;
using bf16x8 = __attribute__((ext_vector_type(8))) short;
using f32x4 = __attribute__((ext_vector_type(4))) float;

static __device__ __forceinline__ float ldv(bf16 v) { return __bfloat162float(v); }
static __device__ __forceinline__ float ldv(float v) { return v; }
static __device__ __forceinline__ bf16 f2b(float v) { return __float2bfloat16(v); }
static __device__ __forceinline__ void stv(bf16* p, float v) { *p = __float2bfloat16(v); }
static __device__ __forceinline__ void stv(float* p, float v) { *p = v; }

// load 8 elements (bf16 passthrough / fp32 cvt) into LDS as bf16
static __device__ __forceinline__ void load8(const bf16* p, bf16* dst) {
  *(uint4*)dst = *(const uint4*)p;
}
static __device__ __forceinline__ void load8(const float* p, bf16* dst) {
  float4 a = *(const float4*)p, b = *(const float4*)(p + 4);
  dst[0] = f2b(a.x); dst[1] = f2b(a.y); dst[2] = f2b(a.z); dst[3] = f2b(a.w);
  dst[4] = f2b(b.x); dst[5] = f2b(b.y); dst[6] = f2b(b.z); dst[7] = f2b(b.w);
}

// ---------------------------------------------------------------------------
// LayerNorm (cols = 1024 fixed). out = (x - mean)*rsqrt(var+1e-5)*gamma [+ add]
// ---------------------------------------------------------------------------
__global__ __launch_bounds__(256) void ln_kernel(
    const float* __restrict__ x, const float* __restrict__ gamma,
    const float* __restrict__ add, bf16* __restrict__ out) {
  const int row = blockIdx.x;
  const float* xr = x + (size_t)row * 1024;
  float v[4];
  float s = 0.f, ss = 0.f;
#pragma unroll
  for (int i = 0; i < 4; ++i) {
    v[i] = xr[threadIdx.x + 256 * i];
    s += v[i];
    ss += v[i] * v[i];
  }
#pragma unroll
  for (int m = 1; m < 64; m <<= 1) {
    s += __shfl_xor(s, m);
    ss += __shfl_xor(ss, m);
  }
  __shared__ float red[8];
  const int wid = threadIdx.x >> 6;
  if ((threadIdx.x & 63) == 0) { red[wid] = s; red[wid + 4] = ss; }
  __syncthreads();
  s = red[0] + red[1] + red[2] + red[3];
  ss = red[4] + red[5] + red[6] + red[7];
  const float mean = s * (1.f / 1024.f);
  const float var = ss * (1.f / 1024.f) - mean * mean;
  const float rs = rsqrtf(var + 1e-5f);
  bf16* outr = out + (size_t)row * 1024;
#pragma unroll
  for (int i = 0; i < 4; ++i) {
    int c = threadIdx.x + 256 * i;
    float y = (v[i] - mean) * rs * gamma[c];
    if (add) y += add[(size_t)row * 1024 + c];
    outr[c] = f2b(y);
  }
}

// ---------------------------------------------------------------------------
// Per-head l2norm (+optional per-dim scales s1*s2, *mult). 1024 cols = 16 heads
// x 64 d. One row per block; in-place safe (each thread reads then writes its
// own 4 elems). Used to pre-normalize all attention Q/K once, so the attention
// kernels stage pure bf16 copies.
// ---------------------------------------------------------------------------
__global__ __launch_bounds__(256) void l2n_kernel(
    const bf16* __restrict__ in, int in_rs, bf16* __restrict__ out, int out_rs,
    const float* __restrict__ s1, const float* __restrict__ s2, float mult) {
  const int row = blockIdx.x, t = threadIdx.x;
  const int d0 = (t & 15) * 4, hoff = (t >> 4) * 64;
  const bf16* p = in + (size_t)row * in_rs + hoff + d0;
  bf16 b[4];
  *(ushort4*)b = *(const ushort4*)p;
  float v[4], ss = 0.f;
#pragma unroll
  for (int i = 0; i < 4; ++i) { v[i] = ldv(b[i]); ss += v[i] * v[i]; }
  ss += __shfl_xor(ss, 1);
  ss += __shfl_xor(ss, 2);
  ss += __shfl_xor(ss, 4);
  ss += __shfl_xor(ss, 8);
  const float inv = mult / fmaxf(sqrtf(ss), 1e-12f);
#pragma unroll
  for (int i = 0; i < 4; ++i) {
    float y = v[i] * inv;
    if (s1) y *= s1[d0 + i];
    if (s2) y *= s2[d0 + i];
    b[i] = f2b(y);
  }
  *(ushort4*)(out + (size_t)row * out_rs + hoff + d0) = *(ushort4*)b;
}

// ---------------------------------------------------------------------------
// Per-head V transpose: dst[h*64+d][n] = src[n][coff + h*64 + d].
// 64x64 tiles through LDS; removes the in-attn V transpose (was the 1.26e7
// LDS bank conflicts: ushort4 writes at stride 576B).
// ---------------------------------------------------------------------------
__global__ __launch_bounds__(256) void vtrans_kernel(
    const bf16* __restrict__ src, int rstride, int coff, int nrows,
    bf16* __restrict__ dst) {
  __shared__ bf16 tile[64][72];
  const int n0 = blockIdx.x * 64, h = blockIdx.y, t = threadIdx.x;
  {
    const int nr = t >> 2, dp = (t & 3) * 16;
    const bf16* s = src + (size_t)(n0 + nr) * rstride + coff + h * 64 + dp;
    *(uint4*)&tile[nr][dp] = *(const uint4*)s;
    *(uint4*)&tile[nr][dp + 8] = *(const uint4*)(s + 8);
  }
  __syncthreads();
  {
    const int dr = t >> 2, np = (t & 3) * 16;
    bf16 tmp[16];
#pragma unroll
    for (int i = 0; i < 16; ++i) tmp[i] = tile[np + i][dr];
    bf16* d = dst + (size_t)(h * 64 + dr) * nrows + n0 + np;
    *(uint4*)d = *(uint4*)&tmp[0];
    *(uint4*)(d + 8) = *(uint4*)&tmp[8];
  }
}

// ---------------------------------------------------------------------------
// MFMA GEMM  C[M,N] = Acat[M,K] @ B[K,N]
// A/A2: TA (bf16 ws / fp32 input), row-major. B: fp32 weights [K,N] (cvt->bf16
// during LDS staging, stored [n][k]). 128x128 block tile, 4 waves, each wave
// 64x64 via 4x4 mfma_f32_16x16x32_bf16. M,N %128==0, K %32==0, K1 %8==0.
// epilogue 1: sigmoid-gated EMA (new_states).
// ---------------------------------------------------------------------------
template <typename TA, typename TC>
__global__ __launch_bounds__(256) void mfma_gemm(
    const TA* __restrict__ A, int lda,
    const TA* __restrict__ A2, int lda2, int K1,
    const float* __restrict__ B, int ldb,
    TC* __restrict__ C, int ldc, int K,
    int epilogue,
    const float* __restrict__ b_gate, const float* __restrict__ ema_beta,
    const float* __restrict__ init_state) {
  __shared__ bf16 Asb[128][40];  // [m][k], pad 32->40
  __shared__ bf16 Bsb[128][40];  // [n][k], pad 32->40
  const int bm = blockIdx.y * 128, bn = blockIdx.x * 128;
  const int tid = threadIdx.x;
  const int w = tid >> 6, lane = tid & 63;
  const int wm = (w >> 1) * 64, wn = (w & 1) * 64;
  const int lr = lane & 15, quad = lane >> 4, ko = quad * 8;
  const int sn = tid & 127, skh = (tid >> 7) * 16;  // B staging map

  f32x4 acc[4][4] = {};

  for (int kt = 0; kt < K; kt += 32) {
    // ---- stage A (2 chunks of 8 per thread) ----
#pragma unroll
    for (int c = 0; c < 2; ++c) {
      const int q = tid + 256 * c;
      const int m = q >> 2, kk = (q & 3) * 8;
      const int gk = kt + kk;
      const TA* ap = (A2 && gk >= K1)
                         ? (A2 + (size_t)(bm + m) * lda2 + (gk - K1))
                         : (A + (size_t)(bm + m) * lda + gk);
      load8(ap, &Asb[m][kk]);
    }
    // ---- stage B: thread owns (n, half-k); column reads coalesce over lanes ----
    {
      bf16 tmp[16];
#pragma unroll
      for (int i = 0; i < 16; ++i)
        tmp[i] = f2b(B[(size_t)(kt + skh + i) * ldb + bn + sn]);
      *(uint4*)&Bsb[sn][skh] = *(uint4*)&tmp[0];
      *(uint4*)&Bsb[sn][skh + 8] = *(uint4*)&tmp[8];
    }
    __syncthreads();

    bf16x8 af[4], bfr[4];
#pragma unroll
    for (int i = 0; i < 4; ++i) af[i] = *(const bf16x8*)&Asb[wm + i * 16 + lr][ko];
#pragma unroll
    for (int j = 0; j < 4; ++j) bfr[j] = *(const bf16x8*)&Bsb[wn + j * 16 + lr][ko];
#pragma unroll
    for (int i = 0; i < 4; ++i)
#pragma unroll
      for (int j = 0; j < 4; ++j)
        acc[i][j] = __builtin_amdgcn_mfma_f32_16x16x32_bf16(af[i], bfr[j],
                                                            acc[i][j], 0, 0, 0);
    __syncthreads();
  }

  // ---- epilogue: D[row][col], row=quad*4+r (in-tile), col=lr ----
#pragma unroll
  for (int i = 0; i < 4; ++i) {
#pragma unroll
    for (int j = 0; j < 4; ++j) {
#pragma unroll
      for (int r = 0; r < 4; ++r) {
        const int row = bm + wm + i * 16 + quad * 4 + r;
        const int col = bn + wn + j * 16 + lr;
        float v = acc[i][j][r];
        if (epilogue == 1) {
          float z = v + b_gate[col];
          float d = 1.f / (1.f + __expf(-ema_beta[col]));
          v = d * z + (1.f - d) * init_state[(size_t)row * 1024 + col];
        }
        stv(&C[(size_t)row * ldc + col], v);
      }
    }
  }
}

// ---------------------------------------------------------------------------
// MFMA flash attention v2. Inputs pre-normalized bf16 (Q carries all scales),
// V pre-transposed per head (vtp[h*64+d][n]). 128q x 64k tiles, 4 waves, each
// wave 32 q-rows (2 m-frags): 32 MFMAs per tile between 2 barriers. psb rows
// are wave-private -> no barrier between softmax and PV (DS in-order per wave).
// ---------------------------------------------------------------------------
__global__ __launch_bounds__(256) void attn_mfma(
    const bf16* __restrict__ qp, int q_rstride,
    const bf16* __restrict__ kp, int k_rstride,
    const bf16* __restrict__ vtp, int v_nstride,
    const float* __restrict__ bias, int causal, int nkeys,
    int qrows_per_blk, int kbase0, int krows_per_blk,
    bf16* __restrict__ op, int o_rstride, int o_coff, int o_hstride) {
  __shared__ __align__(16) bf16 qsb[128][72];  // [qrow][d]
  __shared__ __align__(16) bf16 ksb[64][72];   // [krow][d]
  __shared__ __align__(16) bf16 vsb[64][72];   // [d][krow]
  __shared__ __align__(16) bf16 psb[128][72];  // [qrow][kcol]
  const int h = blockIdx.y, qt = blockIdx.x, zb = blockIdx.z;
  const int tid = threadIdx.x;
  const int w = tid >> 6, lane = tid & 63;
  const int lr = lane & 15, quad = lane >> 4;
  const int wq = w * 32;
  const int qbase = zb * qrows_per_blk + qt * 128;

  // ---- stage Q once (pure copy; 64B per thread) ----
  {
    const int qr = tid >> 1, qc = (tid & 1) * 32;
    const bf16* s = qp + (size_t)(qbase + qr) * q_rstride + h * 64 + qc;
#pragma unroll
    for (int c = 0; c < 4; ++c)
      *(uint4*)&qsb[qr][qc + c * 8] = *(const uint4*)(s + c * 8);
  }

  float m_i[2][4], l_i[2][4];
  f32x4 o_acc[2][4] = {};
#pragma unroll
  for (int i = 0; i < 2; ++i)
#pragma unroll
    for (int r = 0; r < 4; ++r) { m_i[i][r] = -3.0e38f; l_i[i][r] = 0.f; }

  const int kbase = kbase0 + zb * krows_per_blk;
  // causal: keys beyond qt*128+127+512 are fully masked -> skip those tiles
  const int ntk = causal ? min(nkeys, qt * 128 + 128 + 512) : nkeys;
  const int kr = tid >> 2, kc = (tid & 3) * 16;

  for (int jt = 0; jt < ntk; jt += 64) {
    __syncthreads();
    // ---- stage K tile (copy) ----
    {
      const int krow = kbase + jt + kr;
      if (krow >= 0) {
        const bf16* s = kp + (size_t)krow * k_rstride + h * 64 + kc;
        *(uint4*)&ksb[kr][kc] = *(const uint4*)s;
        *(uint4*)&ksb[kr][kc + 8] = *(const uint4*)(s + 8);
      } else {
        uint4 z{0, 0, 0, 0};
        *(uint4*)&ksb[kr][kc] = z;
        *(uint4*)&ksb[kr][kc + 8] = z;
      }
      // ---- stage V^T tile (copy; rows = d, cols = krow) ----
      const int col = kbase + jt + kc;  // kbase,jt,kc all %16==0 -> whole chunk
      if (col >= 0) {
        const bf16* s = vtp + (size_t)(h * 64 + kr) * v_nstride + col;
        *(uint4*)&vsb[kr][kc] = *(const uint4*)s;
        *(uint4*)&vsb[kr][kc + 8] = *(const uint4*)(s + 8);
      } else {
        uint4 z{0, 0, 0, 0};
        *(uint4*)&vsb[kr][kc] = z;
        *(uint4*)&vsb[kr][kc + 8] = z;
      }
    }
    __syncthreads();

    // ---- S[32x64] = Qhat @ Khat^T ----
    f32x4 s_acc[2][4] = {};
#pragma unroll
    for (int dc = 0; dc < 2; ++dc) {
      bf16x8 qf0 = *(const bf16x8*)&qsb[wq + lr][dc * 32 + quad * 8];
      bf16x8 qf1 = *(const bf16x8*)&qsb[wq + 16 + lr][dc * 32 + quad * 8];
#pragma unroll
      for (int j = 0; j < 4; ++j) {
        bf16x8 kf = *(const bf16x8*)&ksb[j * 16 + lr][dc * 32 + quad * 8];
        s_acc[0][j] = __builtin_amdgcn_mfma_f32_16x16x32_bf16(qf0, kf, s_acc[0][j], 0, 0, 0);
        s_acc[1][j] = __builtin_amdgcn_mfma_f32_16x16x32_bf16(qf1, kf, s_acc[1][j], 0, 0, 0);
      }
    }

    // ---- bias + causal + online softmax ----
#pragma unroll
    for (int i = 0; i < 2; ++i) {
#pragma unroll
      for (int r = 0; r < 4; ++r) {
        const int brow = wq + i * 16 + quad * 4 + r;
        const int qloc = qt * 128 + brow;
        float sv[4];
#pragma unroll
        for (int j = 0; j < 4; ++j) {
          const int jg = jt + j * 16 + lr;
          float s = s_acc[i][j][r];
          if (bias) s += bias[((size_t)h * 512 + qloc) * 1024 + jg];
          if (causal && jg > qloc + 512) s = -3.0e38f;
          sv[j] = s;
        }
        float rmax = fmaxf(fmaxf(sv[0], sv[1]), fmaxf(sv[2], sv[3]));
#pragma unroll
        for (int mm = 1; mm < 16; mm <<= 1) rmax = fmaxf(rmax, __shfl_xor(rmax, mm));
        const float mn = fmaxf(m_i[i][r], rmax);
        const float alpha = __expf(m_i[i][r] - mn);
        float p[4], rsum = 0.f;
#pragma unroll
        for (int j = 0; j < 4; ++j) { p[j] = __expf(sv[j] - mn); rsum += p[j]; }
#pragma unroll
        for (int mm = 1; mm < 16; mm <<= 1) rsum += __shfl_xor(rsum, mm);
        l_i[i][r] = l_i[i][r] * alpha + rsum;
        m_i[i][r] = mn;
#pragma unroll
        for (int dt = 0; dt < 4; ++dt) o_acc[i][dt][r] *= alpha;
#pragma unroll
        for (int j = 0; j < 4; ++j) psb[brow][j * 16 + lr] = f2b(p[j]);
      }
    }

    // ---- O[32x64] += P @ V (psb rows wave-private; no block barrier) ----
#pragma unroll
    for (int jc = 0; jc < 2; ++jc) {
      bf16x8 pf0 = *(const bf16x8*)&psb[wq + lr][jc * 32 + quad * 8];
      bf16x8 pf1 = *(const bf16x8*)&psb[wq + 16 + lr][jc * 32 + quad * 8];
#pragma unroll
      for (int dt = 0; dt < 4; ++dt) {
        bf16x8 vf = *(const bf16x8*)&vsb[dt * 16 + lr][jc * 32 + quad * 8];
        o_acc[0][dt] = __builtin_amdgcn_mfma_f32_16x16x32_bf16(pf0, vf, o_acc[0][dt], 0, 0, 0);
        o_acc[1][dt] = __builtin_amdgcn_mfma_f32_16x16x32_bf16(pf1, vf, o_acc[1][dt], 0, 0, 0);
      }
    }
  }

  // ---- epilogue ----
#pragma unroll
  for (int i = 0; i < 2; ++i) {
#pragma unroll
    for (int r = 0; r < 4; ++r) {
      const int qrow = qbase + wq + i * 16 + quad * 4 + r;
      const float invl = 1.f / l_i[i][r];
      bf16* orow = op + (size_t)qrow * o_rstride + o_coff + (size_t)h * o_hstride;
#pragma unroll
      for (int dt = 0; dt < 4; ++dt) orow[dt * 16 + lr] = f2b(o_acc[i][dt][r] * invl);
    }
  }
}

// ---------------------------------------------------------------------------
// memories (fp32 out): out[m][h][i][d] = qkv[(3584+i)*3072 + 1024*(m+1) + h*64 + d]
// (must run BEFORE the in-place l2norm of the qkv k-part)
// ---------------------------------------------------------------------------
__global__ __launch_bounds__(256) void memcopy_kernel(const bf16* __restrict__ qkv,
                                                      float* __restrict__ out) {
  const int idx = blockIdx.x * 256 + threadIdx.x;  // 2*16*512*64 = 1048576
  const int d = idx & 63;
  const int i = (idx >> 6) & 511;
  const int h = (idx >> 15) & 15;
  const int mm = idx >> 19;
  out[idx] = ldv(qkv[(size_t)(3584 + i) * 3072 + 1024 * (mm + 1) + h * 64 + d]);
}

// ---------------------------------------------------------------------------
extern "C" void kernel_launch(void* const* d_in, const int* in_sizes, int n_in,
                              void* d_out, int out_size, void* d_ws, size_t ws_size,
                              hipStream_t stream) {
  const float* x = (const float*)d_in[0];
  const float* rel_bias = (const float*)d_in[1];
  const float* gamma = (const float*)d_in[2];
  const float* w_qkv = (const float*)d_in[3];
  const float* q_scale = (const float*)d_in[4];
  const float* k_scale = (const float*)d_in[5];
  const float* w_out = (const float*)d_in[6];
  const float* s_gamma = (const float*)d_in[7];
  const float* w_q2s = (const float*)d_in[8];
  const float* w_qfs = (const float*)d_in[9];
  const float* w_sqkv = (const float*)d_in[10];
  const float* init_state = (const float*)d_in[11];
  const float* state_pos = (const float*)d_in[12];
  const float* w_sout = (const float*)d_in[13];
  const float* ts_qs = (const float*)d_in[14];
  const float* ts_ks = (const float*)d_in[15];
  const float* ss_qs = (const float*)d_in[16];
  const float* ss_ks = (const float*)d_in[17];
  const float* fs_qs = (const float*)d_in[18];
  const float* fs_ks = (const float*)d_in[19];
  const float* w_gate = (const float*)d_in[20];
  const float* b_gate = (const float*)d_in[21];
  const float* ema_beta = (const float*)d_in[22];

  // outputs: FP32
  float* out0 = (float*)d_out;         // [4096,1024]
  float* out_mem = out0 + 4194304;     // [2,16,512,64]
  float* out_ns = out0 + 5242880;      // [512,1024]

  // workspace (bf16 intermediates), 64 MiB total
  bf16* xn = (bf16*)d_ws;          // 4096x1024 (later reused as vT_loc)
  bf16* qkv = xn + 4194304;        // 4096x3072 (q/k parts l2norm'd in place)
  bf16* q2s = qkv + 12582912;      // 4096x1024 (l2norm'd in place)
  bf16* aloc = q2s + 4194304;      // 4096x1024
  bf16* ats = aloc + 4194304;      // 4096x1024
  bf16* st = ats + 4194304;        // 512x1024 (later reused as vT_s)
  bf16* sqkv = st + 524288;        // 512x3072 (q/k parts l2norm'd in place)
  bf16* qfs = sqkv + 1572864;      // 512x1024 (l2norm'd in place)
  bf16* socat = qfs + 524288;      // 512x2048
  bf16* soproj = socat + 1048576;  // 512x1024
  bf16* vT_loc = xn;               // [16*64][4096] after q2s gemm consumes xn
  bf16* vT_s = st;                 // [16*64][512]  after qfs gemm consumes st

  // 1. layernorms
  ln_kernel<<<4096, 256, 0, stream>>>(x, gamma, nullptr, xn);
  ln_kernel<<<512, 256, 0, stream>>>(init_state, s_gamma, state_pos, st);

  // 2. projections (MFMA)
  mfma_gemm<bf16, bf16><<<dim3(24, 32), 256, 0, stream>>>(
      xn, 1024, nullptr, 0, 0, w_qkv, 3072, qkv, 3072, 1024, 0, nullptr, nullptr, nullptr);
  mfma_gemm<bf16, bf16><<<dim3(8, 32), 256, 0, stream>>>(
      xn, 1024, nullptr, 0, 0, w_q2s, 1024, q2s, 1024, 1024, 0, nullptr, nullptr, nullptr);
  mfma_gemm<float, bf16><<<dim3(24, 4), 256, 0, stream>>>(
      init_state, 1024, nullptr, 0, 0, w_sqkv, 3072, sqkv, 3072, 1024, 0, nullptr, nullptr, nullptr);
  mfma_gemm<bf16, bf16><<<dim3(8, 4), 256, 0, stream>>>(
      st, 1024, nullptr, 0, 0, w_qfs, 1024, qfs, 1024, 1024, 0, nullptr, nullptr, nullptr);

  // 3. memories output (raw k/v, before in-place norm)
  memcopy_kernel<<<4096, 256, 0, stream>>>(qkv, out_mem);

  // 4. V transposes (into freed xn/st regions)
  vtrans_kernel<<<dim3(64, 16), 256, 0, stream>>>(qkv, 3072, 2048, 4096, vT_loc);
  vtrans_kernel<<<dim3(8, 16), 256, 0, stream>>>(sqkv, 3072, 2048, 512, vT_s);

  // 5. pre-normalize Q/K (scales folded into Q side: qs*ks*8; K plain l2norm)
  l2n_kernel<<<4096, 256, 0, stream>>>(qkv, 3072, qkv, 3072, q_scale, k_scale, 8.f);
  l2n_kernel<<<4096, 256, 0, stream>>>(qkv + 1024, 3072, qkv + 1024, 3072, nullptr, nullptr, 1.f);
  l2n_kernel<<<4096, 256, 0, stream>>>(q2s, 1024, q2s, 1024, ts_qs, ts_ks, 8.f);
  l2n_kernel<<<512, 256, 0, stream>>>(sqkv, 3072, sqkv, 3072, ss_qs, ss_ks, 8.f);
  l2n_kernel<<<512, 256, 0, stream>>>(sqkv + 1024, 3072, sqkv + 1024, 3072, nullptr, nullptr, 1.f);
  l2n_kernel<<<512, 256, 0, stream>>>(qfs, 1024, qfs, 1024, fs_qs, fs_ks, 8.f);

  // 6. attentions (MFMA flash, 128-row q tiles)
  attn_mfma<<<dim3(4, 16, 8), 256, 0, stream>>>(
      qkv, 3072, qkv + 1024, 3072, vT_loc, 4096, rel_bias, 1, 1024,
      512, -512, 512, aloc, 1024, 0, 64);
  attn_mfma<<<dim3(32, 16, 1), 256, 0, stream>>>(
      q2s, 1024, sqkv + 1024, 3072, vT_s, 512, nullptr, 0, 512,
      4096, 0, 0, ats, 1024, 0, 64);
  attn_mfma<<<dim3(4, 16, 1), 256, 0, stream>>>(
      sqkv, 3072, sqkv + 1024, 3072, vT_s, 512, nullptr, 0, 512,
      512, 0, 0, socat, 2048, 0, 128);
  attn_mfma<<<dim3(4, 16, 1), 256, 0, stream>>>(
      qfs, 1024, qkv + 1024, 3072, vT_loc, 4096, nullptr, 0, 512,
      512, 3584, 0, socat, 2048, 64, 128);

  // 7. out0 = [aloc | ats] @ w_out  (fp32 out)
  mfma_gemm<bf16, float><<<dim3(8, 32), 256, 0, stream>>>(
      aloc, 1024, ats, 1024, 1024, w_out, 1024, out0, 1024, 2048, 0, nullptr, nullptr, nullptr);

  // 8. state out path (new_states fp32 out)
  mfma_gemm<bf16, bf16><<<dim3(8, 4), 256, 0, stream>>>(
      socat, 2048, nullptr, 0, 0, w_sout, 1024, soproj, 1024, 2048, 0, nullptr, nullptr, nullptr);
  mfma_gemm<bf16, float><<<dim3(8, 4), 256, 0, stream>>>(
      soproj, 1024, nullptr, 0, 0, w_gate, 1024, out_ns, 1024, 1024, 1, b_gate, ema_beta,
      init_state);
}

// Round 3
// 890.096 us; speedup vs baseline: 1.0941x; 1.0941x over previous
//
#include <hip/hip_runtime.h>
#include <hip/hip_bf16.h>

using bf16 = __hip_bfloat16;
using bf16x8 = __attribute__((ext_vector_type(8))) short;
using f32x4 = __attribute__((ext_vector_type(4))) float;

static __device__ __forceinline__ float ldv(bf16 v) { return __bfloat162float(v); }
static __device__ __forceinline__ float ldv(float v) { return v; }
static __device__ __forceinline__ bf16 f2b(float v) { return __float2bfloat16(v); }
static __device__ __forceinline__ void stv(bf16* p, float v) { *p = __float2bfloat16(v); }
static __device__ __forceinline__ void stv(float* p, float v) { *p = v; }

// load 8 elements (bf16 passthrough / fp32 cvt) into LDS as bf16
static __device__ __forceinline__ void load8(const bf16* p, bf16* dst) {
  *(uint4*)dst = *(const uint4*)p;
}
static __device__ __forceinline__ void load8(const float* p, bf16* dst) {
  float4 a = *(const float4*)p, b = *(const float4*)(p + 4);
  dst[0] = f2b(a.x); dst[1] = f2b(a.y); dst[2] = f2b(a.z); dst[3] = f2b(a.w);
  dst[4] = f2b(b.x); dst[5] = f2b(b.y); dst[6] = f2b(b.z); dst[7] = f2b(b.w);
}

// ---------------------------------------------------------------------------
// LayerNorm (cols = 1024 fixed). out = (x - mean)*rsqrt(var+1e-5)*gamma [+ add]
// ---------------------------------------------------------------------------
__global__ __launch_bounds__(256) void ln_kernel(
    const float* __restrict__ x, const float* __restrict__ gamma,
    const float* __restrict__ add, bf16* __restrict__ out) {
  const int row = blockIdx.x;
  const float* xr = x + (size_t)row * 1024;
  float v[4];
  float s = 0.f, ss = 0.f;
#pragma unroll
  for (int i = 0; i < 4; ++i) {
    v[i] = xr[threadIdx.x + 256 * i];
    s += v[i];
    ss += v[i] * v[i];
  }
#pragma unroll
  for (int m = 1; m < 64; m <<= 1) {
    s += __shfl_xor(s, m);
    ss += __shfl_xor(ss, m);
  }
  __shared__ float red[8];
  const int wid = threadIdx.x >> 6;
  if ((threadIdx.x & 63) == 0) { red[wid] = s; red[wid + 4] = ss; }
  __syncthreads();
  s = red[0] + red[1] + red[2] + red[3];
  ss = red[4] + red[5] + red[6] + red[7];
  const float mean = s * (1.f / 1024.f);
  const float var = ss * (1.f / 1024.f) - mean * mean;
  const float rs = rsqrtf(var + 1e-5f);
  bf16* outr = out + (size_t)row * 1024;
#pragma unroll
  for (int i = 0; i < 4; ++i) {
    int c = threadIdx.x + 256 * i;
    float y = (v[i] - mean) * rs * gamma[c];
    if (add) y += add[(size_t)row * 1024 + c];
    outr[c] = f2b(y);
  }
}

// ---------------------------------------------------------------------------
// Per-head l2norm, in place. blockIdx.y = part (0: cols 0..1023 with scales
// s1*s2*mult; 1: cols 1024..2047 plain l2norm). 16 heads x 64 d per part.
// ---------------------------------------------------------------------------
__global__ __launch_bounds__(256) void l2n_kernel(
    bf16* __restrict__ buf, int rs,
    const float* __restrict__ s1, const float* __restrict__ s2, float mult) {
  const int row = blockIdx.x, part = blockIdx.y, t = threadIdx.x;
  const int d0 = (t & 15) * 4, hoff = (t >> 4) * 64 + part * 1024;
  bf16* p = buf + (size_t)row * rs + hoff + d0;
  bf16 b[4];
  *(ushort4*)b = *(const ushort4*)p;
  float v[4], ss = 0.f;
#pragma unroll
  for (int i = 0; i < 4; ++i) { v[i] = ldv(b[i]); ss += v[i] * v[i]; }
  ss += __shfl_xor(ss, 1);
  ss += __shfl_xor(ss, 2);
  ss += __shfl_xor(ss, 4);
  ss += __shfl_xor(ss, 8);
  const float inv = (part ? 1.f : mult) / fmaxf(sqrtf(ss), 1e-12f);
#pragma unroll
  for (int i = 0; i < 4; ++i) {
    float y = v[i] * inv;
    if (!part && s1) y *= s1[d0 + i];
    if (!part && s2) y *= s2[d0 + i];
    b[i] = f2b(y);
  }
  *(ushort4*)p = *(ushort4*)b;
}

// ---------------------------------------------------------------------------
// Per-head V transpose: dst[h*64+d][n] = src[n][coff + h*64 + d].
// ---------------------------------------------------------------------------
__global__ __launch_bounds__(256) void vtrans_kernel(
    const bf16* __restrict__ src, int rstride, int coff, int nrows,
    bf16* __restrict__ dst) {
  __shared__ bf16 tile[64][72];
  const int n0 = blockIdx.x * 64, h = blockIdx.y, t = threadIdx.x;
  {
    const int nr = t >> 2, dp = (t & 3) * 16;
    const bf16* s = src + (size_t)(n0 + nr) * rstride + coff + h * 64 + dp;
    *(uint4*)&tile[nr][dp] = *(const uint4*)s;
    *(uint4*)&tile[nr][dp + 8] = *(const uint4*)(s + 8);
  }
  __syncthreads();
  {
    const int dr = t >> 2, np = (t & 3) * 16;
    bf16 tmp[16];
#pragma unroll
    for (int i = 0; i < 16; ++i) tmp[i] = tile[np + i][dr];
    bf16* d = dst + (size_t)(h * 64 + dr) * nrows + n0 + np;
    *(uint4*)d = *(uint4*)&tmp[0];
    *(uint4*)(d + 8) = *(uint4*)&tmp[8];
  }
}

// ---------------------------------------------------------------------------
// Bias pre-shuffle: bshuf[h][q][jt][lr*4+j] = bf16(bias[h][q][jt*64 + j*16 + lr])
// so the attn inner loop does ONE ushort4 load per C-row instead of 4 scalar
// fp32 loads. Lives in the out0 region of d_out (16MB, written only at the end).
// ---------------------------------------------------------------------------
__global__ __launch_bounds__(256) void bshuf_kernel(const float* __restrict__ bias,
                                                    bf16* __restrict__ out) {
  const int q = blockIdx.x, h = blockIdx.y, t = threadIdx.x;
  const int jt = t >> 4, lr = t & 15;
  const float* src = bias + ((size_t)h * 512 + q) * 1024 + jt * 64 + lr;
  bf16 b[4];
#pragma unroll
  for (int j = 0; j < 4; ++j) b[j] = f2b(src[j * 16]);
  *(ushort4*)(out + (((size_t)h * 512 + q) * 16 + jt) * 64 + lr * 4) = *(ushort4*)b;
}

// ---------------------------------------------------------------------------
// MFMA GEMM  C[M,N] = Acat[M,K] @ B[K,N]  (unchanged from R1)
// ---------------------------------------------------------------------------
template <typename TA, typename TC>
__global__ __launch_bounds__(256) void mfma_gemm(
    const TA* __restrict__ A, int lda,
    const TA* __restrict__ A2, int lda2, int K1,
    const float* __restrict__ B, int ldb,
    TC* __restrict__ C, int ldc, int K,
    int epilogue,
    const float* __restrict__ b_gate, const float* __restrict__ ema_beta,
    const float* __restrict__ init_state) {
  __shared__ bf16 Asb[128][40];  // [m][k], pad 32->40
  __shared__ bf16 Bsb[128][40];  // [n][k], pad 32->40
  const int bm = blockIdx.y * 128, bn = blockIdx.x * 128;
  const int tid = threadIdx.x;
  const int w = tid >> 6, lane = tid & 63;
  const int wm = (w >> 1) * 64, wn = (w & 1) * 64;
  const int lr = lane & 15, quad = lane >> 4, ko = quad * 8;
  const int sn = tid & 127, skh = (tid >> 7) * 16;  // B staging map

  f32x4 acc[4][4] = {};

  for (int kt = 0; kt < K; kt += 32) {
#pragma unroll
    for (int c = 0; c < 2; ++c) {
      const int q = tid + 256 * c;
      const int m = q >> 2, kk = (q & 3) * 8;
      const int gk = kt + kk;
      const TA* ap = (A2 && gk >= K1)
                         ? (A2 + (size_t)(bm + m) * lda2 + (gk - K1))
                         : (A + (size_t)(bm + m) * lda + gk);
      load8(ap, &Asb[m][kk]);
    }
    {
      bf16 tmp[16];
#pragma unroll
      for (int i = 0; i < 16; ++i)
        tmp[i] = f2b(B[(size_t)(kt + skh + i) * ldb + bn + sn]);
      *(uint4*)&Bsb[sn][skh] = *(uint4*)&tmp[0];
      *(uint4*)&Bsb[sn][skh + 8] = *(uint4*)&tmp[8];
    }
    __syncthreads();

    bf16x8 af[4], bfr[4];
#pragma unroll
    for (int i = 0; i < 4; ++i) af[i] = *(const bf16x8*)&Asb[wm + i * 16 + lr][ko];
#pragma unroll
    for (int j = 0; j < 4; ++j) bfr[j] = *(const bf16x8*)&Bsb[wn + j * 16 + lr][ko];
#pragma unroll
    for (int i = 0; i < 4; ++i)
#pragma unroll
      for (int j = 0; j < 4; ++j)
        acc[i][j] = __builtin_amdgcn_mfma_f32_16x16x32_bf16(af[i], bfr[j],
                                                            acc[i][j], 0, 0, 0);
    __syncthreads();
  }

#pragma unroll
  for (int i = 0; i < 4; ++i) {
#pragma unroll
    for (int j = 0; j < 4; ++j) {
#pragma unroll
      for (int r = 0; r < 4; ++r) {
        const int row = bm + wm + i * 16 + quad * 4 + r;
        const int col = bn + wn + j * 16 + lr;
        float v = acc[i][j][r];
        if (epilogue == 1) {
          float z = v + b_gate[col];
          float d = 1.f / (1.f + __expf(-ema_beta[col]));
          v = d * z + (1.f - d) * init_state[(size_t)row * 1024 + col];
        }
        stv(&C[(size_t)row * ldc + col], v);
      }
    }
  }
}

// ---------------------------------------------------------------------------
// MFMA flash attention v3. Pre-normalized Q/K (Q carries all scales), V
// pre-transposed (vtp[h*64+d][n]), bias pre-shuffled bf16 (bshuf, may be null).
// 64q x 64k tiles, 4 waves x 16 q-rows. Q fragments live in registers across
// all tiles. K/V staged via register prefetch (async-split): global loads for
// tile jt+64 issue before compute on jt, LDS write after the trailing barrier.
// LDS 27.6KB -> 5 blocks/CU capacity; launch_bounds(256,4) caps VGPR at 128.
// ---------------------------------------------------------------------------
__global__ __launch_bounds__(256, 4) void attn_mfma(
    const bf16* __restrict__ qp, int q_rstride,
    const bf16* __restrict__ kp, int k_rstride,
    const bf16* __restrict__ vtp, int v_nstride,
    const bf16* __restrict__ bshuf, int causal, int nkeys,
    int qrows_per_blk, int kbase0, int krows_per_blk,
    bf16* __restrict__ op, int o_rstride, int o_coff, int o_hstride) {
  __shared__ __align__(16) bf16 ksb[64][72];  // [krow][d]
  __shared__ __align__(16) bf16 vsb[64][72];  // [d][krow]
  __shared__ __align__(16) bf16 psb[64][72];  // [qrow][kcol]
  const int h = blockIdx.y, qt = blockIdx.x, zb = blockIdx.z;
  const int tid = threadIdx.x;
  const int w = tid >> 6, lane = tid & 63;
  const int lr = lane & 15, quad = lane >> 4;
  const int wq = w * 16;
  const int qbase = zb * qrows_per_blk + qt * 64;

  // ---- Q fragments once, directly to registers (row=wq+lr, k=dc*32+quad*8) ----
  bf16x8 qf[2];
  {
    const bf16* qr = qp + (size_t)(qbase + wq + lr) * q_rstride + h * 64 + quad * 8;
    qf[0] = *(const bf16x8*)qr;
    qf[1] = *(const bf16x8*)(qr + 32);
  }

  float m_i[4], l_i[4];
  f32x4 o_acc[4] = {};
#pragma unroll
  for (int r = 0; r < 4; ++r) { m_i[r] = -3.0e38f; l_i[r] = 0.f; }

  const int kbase = kbase0 + zb * krows_per_blk;
  const int ntk = causal ? min(nkeys, qt * 64 + 64 + 512) : nkeys;
  const int kr = tid >> 2, kc = (tid & 3) * 16;

  uint4 kreg[2], vreg[2];
  const uint4 z4{0, 0, 0, 0};
  auto load_kv = [&](int jt) {
    const int krow = kbase + jt + kr;
    if (krow >= 0) {
      const bf16* s = kp + (size_t)krow * k_rstride + h * 64 + kc;
      kreg[0] = *(const uint4*)s;
      kreg[1] = *(const uint4*)(s + 8);
    } else { kreg[0] = z4; kreg[1] = z4; }
    const int col = kbase + jt + kc;
    if (col >= 0) {
      const bf16* s = vtp + (size_t)(h * 64 + kr) * v_nstride + col;
      vreg[0] = *(const uint4*)s;
      vreg[1] = *(const uint4*)(s + 8);
    } else { vreg[0] = z4; vreg[1] = z4; }
  };
  auto store_kv = [&]() {
    *(uint4*)&ksb[kr][kc] = kreg[0];
    *(uint4*)&ksb[kr][kc + 8] = kreg[1];
    *(uint4*)&vsb[kr][kc] = vreg[0];
    *(uint4*)&vsb[kr][kc + 8] = vreg[1];
  };

  load_kv(0);
  store_kv();

  for (int jt = 0; jt < ntk; jt += 64) {
    __syncthreads();  // staged tile visible to all waves
    const bool pre = jt + 64 < ntk;
    if (pre) load_kv(jt + 64);  // global loads in flight during compute

    // ---- S[16x64] = Q @ K^T ----
    f32x4 s_acc[4] = {};
#pragma unroll
    for (int dc = 0; dc < 2; ++dc) {
#pragma unroll
      for (int j = 0; j < 4; ++j) {
        bf16x8 kf = *(const bf16x8*)&ksb[j * 16 + lr][dc * 32 + quad * 8];
        s_acc[j] = __builtin_amdgcn_mfma_f32_16x16x32_bf16(qf[dc], kf, s_acc[j], 0, 0, 0);
      }
    }

    // ---- bias + causal + online softmax (row = quad*4+r) ----
#pragma unroll
    for (int r = 0; r < 4; ++r) {
      const int brow = wq + quad * 4 + r;
      const int qloc = qt * 64 + brow;
      float sv[4];
#pragma unroll
      for (int j = 0; j < 4; ++j) sv[j] = s_acc[j][r];
      if (bshuf) {
        bf16 bb[4];
        *(ushort4*)bb = *(const ushort4*)(bshuf +
            (((size_t)h * 512 + qloc) * 16 + (jt >> 6)) * 64 + lr * 4);
#pragma unroll
        for (int j = 0; j < 4; ++j) sv[j] += ldv(bb[j]);
      }
      if (causal) {
#pragma unroll
        for (int j = 0; j < 4; ++j)
          if (jt + j * 16 + lr > qloc + 512) sv[j] = -3.0e38f;
      }
      float rmax = fmaxf(fmaxf(sv[0], sv[1]), fmaxf(sv[2], sv[3]));
#pragma unroll
      for (int mm = 1; mm < 16; mm <<= 1) rmax = fmaxf(rmax, __shfl_xor(rmax, mm));
      const float mn = fmaxf(m_i[r], rmax);
      const float alpha = __expf(m_i[r] - mn);
      float p[4], rsum = 0.f;
#pragma unroll
      for (int j = 0; j < 4; ++j) { p[j] = __expf(sv[j] - mn); rsum += p[j]; }
#pragma unroll
      for (int mm = 1; mm < 16; mm <<= 1) rsum += __shfl_xor(rsum, mm);
      l_i[r] = l_i[r] * alpha + rsum;
      m_i[r] = mn;
#pragma unroll
      for (int dt = 0; dt < 4; ++dt) o_acc[dt][r] *= alpha;
#pragma unroll
      for (int j = 0; j < 4; ++j) psb[brow][j * 16 + lr] = f2b(p[j]);
    }

    // ---- O[16x64] += P @ V (psb rows wave-private; DS in-order per wave) ----
#pragma unroll
    for (int jc = 0; jc < 2; ++jc) {
      bf16x8 pf = *(const bf16x8*)&psb[wq + lr][jc * 32 + quad * 8];
#pragma unroll
      for (int dt = 0; dt < 4; ++dt) {
        bf16x8 vf = *(const bf16x8*)&vsb[dt * 16 + lr][jc * 32 + quad * 8];
        o_acc[dt] = __builtin_amdgcn_mfma_f32_16x16x32_bf16(pf, vf, o_acc[dt], 0, 0, 0);
      }
    }

    __syncthreads();  // all waves done with ksb/vsb
    if (pre) store_kv();
  }

  // ---- epilogue ----
#pragma unroll
  for (int r = 0; r < 4; ++r) {
    const int qrow = qbase + wq + quad * 4 + r;
    const float invl = 1.f / l_i[r];
    bf16* orow = op + (size_t)qrow * o_rstride + o_coff + (size_t)h * o_hstride;
#pragma unroll
    for (int dt = 0; dt < 4; ++dt) orow[dt * 16 + lr] = f2b(o_acc[dt][r] * invl);
  }
}

// ---------------------------------------------------------------------------
// memories (fp32 out): out[m][h][i][d] = qkv[(3584+i)*3072 + 1024*(m+1) + h*64 + d]
// (must run BEFORE the in-place l2norm of the qkv k-part)
// ---------------------------------------------------------------------------
__global__ __launch_bounds__(256) void memcopy_kernel(const bf16* __restrict__ qkv,
                                                      float* __restrict__ out) {
  const int idx = blockIdx.x * 256 + threadIdx.x;  // 2*16*512*64 = 1048576
  const int d = idx & 63;
  const int i = (idx >> 6) & 511;
  const int h = (idx >> 15) & 15;
  const int mm = idx >> 19;
  out[idx] = ldv(qkv[(size_t)(3584 + i) * 3072 + 1024 * (mm + 1) + h * 64 + d]);
}

// ---------------------------------------------------------------------------
extern "C" void kernel_launch(void* const* d_in, const int* in_sizes, int n_in,
                              void* d_out, int out_size, void* d_ws, size_t ws_size,
                              hipStream_t stream) {
  const float* x = (const float*)d_in[0];
  const float* rel_bias = (const float*)d_in[1];
  const float* gamma = (const float*)d_in[2];
  const float* w_qkv = (const float*)d_in[3];
  const float* q_scale = (const float*)d_in[4];
  const float* k_scale = (const float*)d_in[5];
  const float* w_out = (const float*)d_in[6];
  const float* s_gamma = (const float*)d_in[7];
  const float* w_q2s = (const float*)d_in[8];
  const float* w_qfs = (const float*)d_in[9];
  const float* w_sqkv = (const float*)d_in[10];
  const float* init_state = (const float*)d_in[11];
  const float* state_pos = (const float*)d_in[12];
  const float* w_sout = (const float*)d_in[13];
  const float* ts_qs = (const float*)d_in[14];
  const float* ts_ks = (const float*)d_in[15];
  const float* ss_qs = (const float*)d_in[16];
  const float* ss_ks = (const float*)d_in[17];
  const float* fs_qs = (const float*)d_in[18];
  const float* fs_ks = (const float*)d_in[19];
  const float* w_gate = (const float*)d_in[20];
  const float* b_gate = (const float*)d_in[21];
  const float* ema_beta = (const float*)d_in[22];

  // outputs: FP32
  float* out0 = (float*)d_out;         // [4096,1024]
  float* out_mem = out0 + 4194304;     // [2,16,512,64]
  float* out_ns = out0 + 5242880;      // [512,1024]

  // bias scratch in the out0 region (16MB; out0 is written only at step 7)
  bf16* bshuf = (bf16*)out0;           // [16][512][16][64] bf16

  // workspace (bf16 intermediates), 64 MiB total
  bf16* xn = (bf16*)d_ws;          // 4096x1024 (later reused as vT_loc)
  bf16* qkv = xn + 4194304;        // 4096x3072 (q/k parts l2norm'd in place)
  bf16* q2s = qkv + 12582912;      // 4096x1024 (l2norm'd in place)
  bf16* aloc = q2s + 4194304;      // 4096x1024
  bf16* ats = aloc + 4194304;      // 4096x1024
  bf16* st = ats + 4194304;        // 512x1024 (later reused as vT_s)
  bf16* sqkv = st + 524288;        // 512x3072 (q/k parts l2norm'd in place)
  bf16* qfs = sqkv + 1572864;      // 512x1024 (l2norm'd in place)
  bf16* socat = qfs + 524288;      // 512x2048
  bf16* soproj = socat + 1048576;  // 512x1024
  bf16* vT_loc = xn;               // [16*64][4096] after q2s gemm consumes xn
  bf16* vT_s = st;                 // [16*64][512]  after qfs gemm consumes st

  // 1. layernorms + bias shuffle
  ln_kernel<<<4096, 256, 0, stream>>>(x, gamma, nullptr, xn);
  ln_kernel<<<512, 256, 0, stream>>>(init_state, s_gamma, state_pos, st);
  bshuf_kernel<<<dim3(512, 16), 256, 0, stream>>>(rel_bias, bshuf);

  // 2. projections (MFMA)
  mfma_gemm<bf16, bf16><<<dim3(24, 32), 256, 0, stream>>>(
      xn, 1024, nullptr, 0, 0, w_qkv, 3072, qkv, 3072, 1024, 0, nullptr, nullptr, nullptr);
  mfma_gemm<bf16, bf16><<<dim3(8, 32), 256, 0, stream>>>(
      xn, 1024, nullptr, 0, 0, w_q2s, 1024, q2s, 1024, 1024, 0, nullptr, nullptr, nullptr);
  mfma_gemm<float, bf16><<<dim3(24, 4), 256, 0, stream>>>(
      init_state, 1024, nullptr, 0, 0, w_sqkv, 3072, sqkv, 3072, 1024, 0, nullptr, nullptr, nullptr);
  mfma_gemm<bf16, bf16><<<dim3(8, 4), 256, 0, stream>>>(
      st, 1024, nullptr, 0, 0, w_qfs, 1024, qfs, 1024, 1024, 0, nullptr, nullptr, nullptr);

  // 3. memories output (raw k/v, before in-place norm)
  memcopy_kernel<<<4096, 256, 0, stream>>>(qkv, out_mem);

  // 4. V transposes (into freed xn/st regions)
  vtrans_kernel<<<dim3(64, 16), 256, 0, stream>>>(qkv, 3072, 2048, 4096, vT_loc);
  vtrans_kernel<<<dim3(8, 16), 256, 0, stream>>>(sqkv, 3072, 2048, 512, vT_s);

  // 5. pre-normalize Q/K (q part carries qs*ks*8; k part plain l2norm)
  l2n_kernel<<<dim3(4096, 2), 256, 0, stream>>>(qkv, 3072, q_scale, k_scale, 8.f);
  l2n_kernel<<<dim3(512, 2), 256, 0, stream>>>(sqkv, 3072, ss_qs, ss_ks, 8.f);
  l2n_kernel<<<dim3(4096, 1), 256, 0, stream>>>(q2s, 1024, ts_qs, ts_ks, 8.f);
  l2n_kernel<<<dim3(512, 1), 256, 0, stream>>>(qfs, 1024, fs_qs, fs_ks, 8.f);

  // 6. attentions (MFMA flash v3, 64-row q tiles)
  attn_mfma<<<dim3(8, 16, 8), 256, 0, stream>>>(
      qkv, 3072, qkv + 1024, 3072, vT_loc, 4096, bshuf, 1, 1024,
      512, -512, 512, aloc, 1024, 0, 64);
  attn_mfma<<<dim3(64, 16, 1), 256, 0, stream>>>(
      q2s, 1024, sqkv + 1024, 3072, vT_s, 512, nullptr, 0, 512,
      4096, 0, 0, ats, 1024, 0, 64);
  attn_mfma<<<dim3(8, 16, 1), 256, 0, stream>>>(
      sqkv, 3072, sqkv + 1024, 3072, vT_s, 512, nullptr, 0, 512,
      512, 0, 0, socat, 2048, 0, 128);
  attn_mfma<<<dim3(8, 16, 1), 256, 0, stream>>>(
      qfs, 1024, qkv + 1024, 3072, vT_loc, 4096, nullptr, 0, 512,
      512, 3584, 0, socat, 2048, 64, 128);

  // 7. out0 = [aloc | ats] @ w_out  (fp32 out; overwrites bshuf scratch)
  mfma_gemm<bf16, float><<<dim3(8, 32), 256, 0, stream>>>(
      aloc, 1024, ats, 1024, 1024, w_out, 1024, out0, 1024, 2048, 0, nullptr, nullptr, nullptr);

  // 8. state out path (new_states fp32 out)
  mfma_gemm<bf16, bf16><<<dim3(8, 4), 256, 0, stream>>>(
      socat, 2048, nullptr, 0, 0, w_sout, 1024, soproj, 1024, 2048, 0, nullptr, nullptr, nullptr);
  mfma_gemm<bf16, float><<<dim3(8, 4), 256, 0, stream>>>(
      soproj, 1024, nullptr, 0, 0, w_gate, 1024, out_ns, 1024, 1024, 1, b_gate, ema_beta,
      init_state);
}

// Round 4
// 736.510 us; speedup vs baseline: 1.3222x; 1.2085x over previous
//
#include <hip/hip_runtime.h>
#include <hip/hip_bf16.h>

using bf16 = __hip_bfloat16;
using bf16x8 = __attribute__((ext_vector_type(8))) short;
using f32x4 = __attribute__((ext_vector_type(4))) float;

static __device__ __forceinline__ float ldv(bf16 v) { return __bfloat162float(v); }
static __device__ __forceinline__ float ldv(float v) { return v; }
static __device__ __forceinline__ bf16 f2b(float v) { return __float2bfloat16(v); }
static __device__ __forceinline__ void stv(bf16* p, float v) { *p = __float2bfloat16(v); }
static __device__ __forceinline__ void stv(float* p, float v) { *p = v; }

// load 8 elements (bf16 passthrough / fp32 cvt) into LDS as bf16
static __device__ __forceinline__ void load8(const bf16* p, bf16* dst) {
  *(uint4*)dst = *(const uint4*)p;
}
static __device__ __forceinline__ void load8(const float* p, bf16* dst) {
  float4 a = *(const float4*)p, b = *(const float4*)(p + 4);
  dst[0] = f2b(a.x); dst[1] = f2b(a.y); dst[2] = f2b(a.z); dst[3] = f2b(a.w);
  dst[4] = f2b(b.x); dst[5] = f2b(b.y); dst[6] = f2b(b.z); dst[7] = f2b(b.w);
}

// ---------------------------------------------------------------------------
// LayerNorm (cols = 1024 fixed). out = (x - mean)*rsqrt(var+1e-5)*gamma [+ add]
// ---------------------------------------------------------------------------
__global__ __launch_bounds__(256) void ln_kernel(
    const float* __restrict__ x, const float* __restrict__ gamma,
    const float* __restrict__ add, bf16* __restrict__ out) {
  const int row = blockIdx.x;
  const float* xr = x + (size_t)row * 1024;
  float v[4];
  float s = 0.f, ss = 0.f;
#pragma unroll
  for (int i = 0; i < 4; ++i) {
    v[i] = xr[threadIdx.x + 256 * i];
    s += v[i];
    ss += v[i] * v[i];
  }
#pragma unroll
  for (int m = 1; m < 64; m <<= 1) {
    s += __shfl_xor(s, m);
    ss += __shfl_xor(ss, m);
  }
  __shared__ float red[8];
  const int wid = threadIdx.x >> 6;
  if ((threadIdx.x & 63) == 0) { red[wid] = s; red[wid + 4] = ss; }
  __syncthreads();
  s = red[0] + red[1] + red[2] + red[3];
  ss = red[4] + red[5] + red[6] + red[7];
  const float mean = s * (1.f / 1024.f);
  const float var = ss * (1.f / 1024.f) - mean * mean;
  const float rs = rsqrtf(var + 1e-5f);
  bf16* outr = out + (size_t)row * 1024;
#pragma unroll
  for (int i = 0; i < 4; ++i) {
    int c = threadIdx.x + 256 * i;
    float y = (v[i] - mean) * rs * gamma[c];
    if (add) y += add[(size_t)row * 1024 + c];
    outr[c] = f2b(y);
  }
}

// ---------------------------------------------------------------------------
// Per-head l2norm, in place. blockIdx.y = part (0: cols 0..1023 with scales
// s1*s2*mult; 1: cols 1024..2047 plain l2norm). 16 heads x 64 d per part.
// ---------------------------------------------------------------------------
__global__ __launch_bounds__(256) void l2n_kernel(
    bf16* __restrict__ buf, int rs,
    const float* __restrict__ s1, const float* __restrict__ s2, float mult) {
  const int row = blockIdx.x, part = blockIdx.y, t = threadIdx.x;
  const int d0 = (t & 15) * 4, hoff = (t >> 4) * 64 + part * 1024;
  bf16* p = buf + (size_t)row * rs + hoff + d0;
  bf16 b[4];
  *(ushort4*)b = *(const ushort4*)p;
  float v[4], ss = 0.f;
#pragma unroll
  for (int i = 0; i < 4; ++i) { v[i] = ldv(b[i]); ss += v[i] * v[i]; }
  ss += __shfl_xor(ss, 1);
  ss += __shfl_xor(ss, 2);
  ss += __shfl_xor(ss, 4);
  ss += __shfl_xor(ss, 8);
  const float inv = (part ? 1.f : mult) / fmaxf(sqrtf(ss), 1e-12f);
#pragma unroll
  for (int i = 0; i < 4; ++i) {
    float y = v[i] * inv;
    if (!part && s1) y *= s1[d0 + i];
    if (!part && s2) y *= s2[d0 + i];
    b[i] = f2b(y);
  }
  *(ushort4*)p = *(ushort4*)b;
}

// ---------------------------------------------------------------------------
// Per-head V transpose: dst[h*64+d][n] = src[n][coff + h*64 + d].
// ---------------------------------------------------------------------------
__global__ __launch_bounds__(256) void vtrans_kernel(
    const bf16* __restrict__ src, int rstride, int coff, int nrows,
    bf16* __restrict__ dst) {
  __shared__ bf16 tile[64][72];
  const int n0 = blockIdx.x * 64, h = blockIdx.y, t = threadIdx.x;
  {
    const int nr = t >> 2, dp = (t & 3) * 16;
    const bf16* s = src + (size_t)(n0 + nr) * rstride + coff + h * 64 + dp;
    *(uint4*)&tile[nr][dp] = *(const uint4*)s;
    *(uint4*)&tile[nr][dp + 8] = *(const uint4*)(s + 8);
  }
  __syncthreads();
  {
    const int dr = t >> 2, np = (t & 3) * 16;
    bf16 tmp[16];
#pragma unroll
    for (int i = 0; i < 16; ++i) tmp[i] = tile[np + i][dr];
    bf16* d = dst + (size_t)(h * 64 + dr) * nrows + n0 + np;
    *(uint4*)d = *(uint4*)&tmp[0];
    *(uint4*)(d + 8) = *(uint4*)&tmp[8];
  }
}

// ---------------------------------------------------------------------------
// Weight transpose+cvt: dst[n][k] (bf16, row stride K) = src[k][n] (fp32).
// Makes GEMM B-staging a pure vector copy (kills 16 scalar fp32 loads + cvt
// per thread per k-tile, the VALU-bound staging anti-pattern).
// ---------------------------------------------------------------------------
__global__ __launch_bounds__(256) void wtrans_kernel(
    const float* __restrict__ src, int N, bf16* __restrict__ dst, int K) {
  __shared__ bf16 tile[64][72];
  const int k0 = blockIdx.x * 64, n0 = blockIdx.y * 64, t = threadIdx.x;
  {
    const int kr = t >> 2, np = (t & 3) * 16;
    const float* s = src + (size_t)(k0 + kr) * N + n0 + np;
    bf16 tmp[16];
#pragma unroll
    for (int i = 0; i < 16; ++i) tmp[i] = f2b(s[i]);
    *(uint4*)&tile[kr][np] = *(uint4*)&tmp[0];
    *(uint4*)&tile[kr][np + 8] = *(uint4*)&tmp[8];
  }
  __syncthreads();
  {
    const int nr = t >> 2, kp = (t & 3) * 16;
    bf16 tmp[16];
#pragma unroll
    for (int i = 0; i < 16; ++i) tmp[i] = tile[kp + i][nr];
    bf16* d = dst + (size_t)(n0 + nr) * K + k0 + kp;
    *(uint4*)d = *(uint4*)&tmp[0];
    *(uint4*)(d + 8) = *(uint4*)&tmp[8];
  }
}

// ---------------------------------------------------------------------------
// Bias pre-shuffle: bshuf[h][q][jt][lr*4+j] = bf16(bias[h][q][jt*64 + j*16 + lr])
// ---------------------------------------------------------------------------
__global__ __launch_bounds__(256) void bshuf_kernel(const float* __restrict__ bias,
                                                    bf16* __restrict__ out) {
  const int q = blockIdx.x, h = blockIdx.y, t = threadIdx.x;
  const int jt = t >> 4, lr = t & 15;
  const float* src = bias + ((size_t)h * 512 + q) * 1024 + jt * 64 + lr;
  bf16 b[4];
#pragma unroll
  for (int j = 0; j < 4; ++j) b[j] = f2b(src[j * 16]);
  *(ushort4*)(out + (((size_t)h * 512 + q) * 16 + jt) * 64 + lr * 4) = *(ushort4*)b;
}

// ---------------------------------------------------------------------------
// MFMA GEMM  C[M,N] = Acat[M,K] @ Bt^T   (Bt: bf16 [N][K], row stride K)
// A/A2: TA (bf16 ws / fp32 input), row-major. 128x128 tile, 4 waves, each
// 64x64 via 4x4 mfma_f32_16x16x32_bf16. epilogue 1: sigmoid-gated EMA.
// ---------------------------------------------------------------------------
template <typename TA, typename TC>
__global__ __launch_bounds__(256) void mfma_gemm(
    const TA* __restrict__ A, int lda,
    const TA* __restrict__ A2, int lda2, int K1,
    const bf16* __restrict__ Bt,
    TC* __restrict__ C, int ldc, int K,
    int epilogue,
    const float* __restrict__ b_gate, const float* __restrict__ ema_beta,
    const float* __restrict__ init_state) {
  __shared__ bf16 Asb[128][40];  // [m][k], pad 32->40
  __shared__ bf16 Bsb[128][40];  // [n][k], pad 32->40
  const int bm = blockIdx.y * 128, bn = blockIdx.x * 128;
  const int tid = threadIdx.x;
  const int w = tid >> 6, lane = tid & 63;
  const int wm = (w >> 1) * 64, wn = (w & 1) * 64;
  const int lr = lane & 15, quad = lane >> 4, ko = quad * 8;
  const int sn = tid >> 1, skh = (tid & 1) * 16;  // B staging map (vector copy)

  f32x4 acc[4][4] = {};

  for (int kt = 0; kt < K; kt += 32) {
    // ---- stage A (2 chunks of 8 per thread) ----
#pragma unroll
    for (int c = 0; c < 2; ++c) {
      const int q = tid + 256 * c;
      const int m = q >> 2, kk = (q & 3) * 8;
      const int gk = kt + kk;
      const TA* ap = (A2 && gk >= K1)
                         ? (A2 + (size_t)(bm + m) * lda2 + (gk - K1))
                         : (A + (size_t)(bm + m) * lda + gk);
      load8(ap, &Asb[m][kk]);
    }
    // ---- stage B: pure 32B vector copy per thread ----
    {
      const bf16* bp = Bt + (size_t)(bn + sn) * K + kt + skh;
      *(uint4*)&Bsb[sn][skh] = *(const uint4*)bp;
      *(uint4*)&Bsb[sn][skh + 8] = *(const uint4*)(bp + 8);
    }
    __syncthreads();

    bf16x8 af[4], bfr[4];
#pragma unroll
    for (int i = 0; i < 4; ++i) af[i] = *(const bf16x8*)&Asb[wm + i * 16 + lr][ko];
#pragma unroll
    for (int j = 0; j < 4; ++j) bfr[j] = *(const bf16x8*)&Bsb[wn + j * 16 + lr][ko];
#pragma unroll
    for (int i = 0; i < 4; ++i)
#pragma unroll
      for (int j = 0; j < 4; ++j)
        acc[i][j] = __builtin_amdgcn_mfma_f32_16x16x32_bf16(af[i], bfr[j],
                                                            acc[i][j], 0, 0, 0);
    __syncthreads();
  }

#pragma unroll
  for (int i = 0; i < 4; ++i) {
#pragma unroll
    for (int j = 0; j < 4; ++j) {
#pragma unroll
      for (int r = 0; r < 4; ++r) {
        const int row = bm + wm + i * 16 + quad * 4 + r;
        const int col = bn + wn + j * 16 + lr;
        float v = acc[i][j][r];
        if (epilogue == 1) {
          float z = v + b_gate[col];
          float d = 1.f / (1.f + __expf(-ema_beta[col]));
          v = d * z + (1.f - d) * init_state[(size_t)row * 1024 + col];
        }
        stv(&C[(size_t)row * ldc + col], v);
      }
    }
  }
}

// ---------------------------------------------------------------------------
// MFMA flash attention v4. Pre-normalized Q/K, V pre-transposed, bias
// pre-shuffled bf16. 64q x 64k tiles, 4 waves x 16 q-rows; Q in registers.
// K/V + bias register-prefetched one tile ahead (T14 split).
// swz!=0: 1D grid 1024, zb=B&7 qt=(B>>3)&7 h=B>>6 -> all 8 qt-blocks of an
// (h,zb) K/V group land on ONE XCD (B%8 == zb) for L2 reuse (T1).
// ---------------------------------------------------------------------------
__global__ __launch_bounds__(256, 4) void attn_mfma(
    const bf16* __restrict__ qp, int q_rstride,
    const bf16* __restrict__ kp, int k_rstride,
    const bf16* __restrict__ vtp, int v_nstride,
    const bf16* __restrict__ bshuf, int causal, int nkeys,
    int qrows_per_blk, int kbase0, int krows_per_blk, int swz,
    bf16* __restrict__ op, int o_rstride, int o_coff, int o_hstride) {
  __shared__ __align__(16) bf16 ksb[64][72];  // [krow][d]
  __shared__ __align__(16) bf16 vsb[64][72];  // [d][krow]
  __shared__ __align__(16) bf16 psb[64][72];  // [qrow][kcol]
  int qt, h, zb;
  if (swz) {
    const int B = blockIdx.x;
    zb = B & 7; qt = (B >> 3) & 7; h = B >> 6;
  } else {
    qt = blockIdx.x; h = blockIdx.y; zb = blockIdx.z;
  }
  const int tid = threadIdx.x;
  const int w = tid >> 6, lane = tid & 63;
  const int lr = lane & 15, quad = lane >> 4;
  const int wq = w * 16;
  const int qbase = zb * qrows_per_blk + qt * 64;

  // ---- Q fragments once, directly to registers (row=wq+lr, k=dc*32+quad*8) ----
  bf16x8 qf[2];
  {
    const bf16* qr = qp + (size_t)(qbase + wq + lr) * q_rstride + h * 64 + quad * 8;
    qf[0] = *(const bf16x8*)qr;
    qf[1] = *(const bf16x8*)(qr + 32);
  }

  float m_i[4], l_i[4];
  f32x4 o_acc[4] = {};
#pragma unroll
  for (int r = 0; r < 4; ++r) { m_i[r] = -3.0e38f; l_i[r] = 0.f; }

  const int kbase = kbase0 + zb * krows_per_blk;
  const int ntk = causal ? min(nkeys, qt * 64 + 64 + 512) : nkeys;
  const int kr = tid >> 2, kc = (tid & 3) * 16;

  uint4 kreg[2], vreg[2];
  ushort4 bcur[4], bnxt[4];
  const uint4 z4{0, 0, 0, 0};
  auto load_kv = [&](int jt) {
    const int krow = kbase + jt + kr;
    if (krow >= 0) {
      const bf16* s = kp + (size_t)krow * k_rstride + h * 64 + kc;
      kreg[0] = *(const uint4*)s;
      kreg[1] = *(const uint4*)(s + 8);
    } else { kreg[0] = z4; kreg[1] = z4; }
    const int col = kbase + jt + kc;
    if (col >= 0) {
      const bf16* s = vtp + (size_t)(h * 64 + kr) * v_nstride + col;
      vreg[0] = *(const uint4*)s;
      vreg[1] = *(const uint4*)(s + 8);
    } else { vreg[0] = z4; vreg[1] = z4; }
  };
  auto load_bias = [&](int jt, ushort4* br) {
#pragma unroll
    for (int r = 0; r < 4; ++r) {
      const int qloc = qt * 64 + wq + quad * 4 + r;
      br[r] = *(const ushort4*)(bshuf +
          (((size_t)h * 512 + qloc) * 16 + (jt >> 6)) * 64 + lr * 4);
    }
  };
  auto store_kv = [&]() {
    *(uint4*)&ksb[kr][kc] = kreg[0];
    *(uint4*)&ksb[kr][kc + 8] = kreg[1];
    *(uint4*)&vsb[kr][kc] = vreg[0];
    *(uint4*)&vsb[kr][kc + 8] = vreg[1];
  };

  load_kv(0);
  if (bshuf) load_bias(0, bcur);
  store_kv();

  for (int jt = 0; jt < ntk; jt += 64) {
    __syncthreads();  // staged tile visible to all waves
    const bool pre = jt + 64 < ntk;
    if (pre) {
      load_kv(jt + 64);  // global loads in flight during compute
      if (bshuf) load_bias(jt + 64, bnxt);
    }

    // ---- S[16x64] = Q @ K^T ----
    f32x4 s_acc[4] = {};
#pragma unroll
    for (int dc = 0; dc < 2; ++dc) {
#pragma unroll
      for (int j = 0; j < 4; ++j) {
        bf16x8 kf = *(const bf16x8*)&ksb[j * 16 + lr][dc * 32 + quad * 8];
        s_acc[j] = __builtin_amdgcn_mfma_f32_16x16x32_bf16(qf[dc], kf, s_acc[j], 0, 0, 0);
      }
    }

    // ---- bias + causal + online softmax (row = quad*4+r) ----
#pragma unroll
    for (int r = 0; r < 4; ++r) {
      const int brow = wq + quad * 4 + r;
      const int qloc = qt * 64 + brow;
      float sv[4];
#pragma unroll
      for (int j = 0; j < 4; ++j) sv[j] = s_acc[j][r];
      if (bshuf) {
        bf16 bb[4];
        *(ushort4*)bb = bcur[r];
#pragma unroll
        for (int j = 0; j < 4; ++j) sv[j] += ldv(bb[j]);
      }
      if (causal) {
#pragma unroll
        for (int j = 0; j < 4; ++j)
          if (jt + j * 16 + lr > qloc + 512) sv[j] = -3.0e38f;
      }
      float rmax = fmaxf(fmaxf(sv[0], sv[1]), fmaxf(sv[2], sv[3]));
#pragma unroll
      for (int mm = 1; mm < 16; mm <<= 1) rmax = fmaxf(rmax, __shfl_xor(rmax, mm));
      const float mn = fmaxf(m_i[r], rmax);
      const float alpha = __expf(m_i[r] - mn);
      float p[4], rsum = 0.f;
#pragma unroll
      for (int j = 0; j < 4; ++j) { p[j] = __expf(sv[j] - mn); rsum += p[j]; }
#pragma unroll
      for (int mm = 1; mm < 16; mm <<= 1) rsum += __shfl_xor(rsum, mm);
      l_i[r] = l_i[r] * alpha + rsum;
      m_i[r] = mn;
#pragma unroll
      for (int dt = 0; dt < 4; ++dt) o_acc[dt][r] *= alpha;
#pragma unroll
      for (int j = 0; j < 4; ++j) psb[brow][j * 16 + lr] = f2b(p[j]);
    }

    // ---- O[16x64] += P @ V (psb rows wave-private; DS in-order per wave) ----
#pragma unroll
    for (int jc = 0; jc < 2; ++jc) {
      bf16x8 pf = *(const bf16x8*)&psb[wq + lr][jc * 32 + quad * 8];
#pragma unroll
      for (int dt = 0; dt < 4; ++dt) {
        bf16x8 vf = *(const bf16x8*)&vsb[dt * 16 + lr][jc * 32 + quad * 8];
        o_acc[dt] = __builtin_amdgcn_mfma_f32_16x16x32_bf16(pf, vf, o_acc[dt], 0, 0, 0);
      }
    }

    __syncthreads();  // all waves done with ksb/vsb
    if (pre) {
      store_kv();
      if (bshuf) {
#pragma unroll
        for (int r = 0; r < 4; ++r) bcur[r] = bnxt[r];
      }
    }
  }

  // ---- epilogue ----
#pragma unroll
  for (int r = 0; r < 4; ++r) {
    const int qrow = qbase + wq + quad * 4 + r;
    const float invl = 1.f / l_i[r];
    bf16* orow = op + (size_t)qrow * o_rstride + o_coff + (size_t)h * o_hstride;
#pragma unroll
    for (int dt = 0; dt < 4; ++dt) orow[dt * 16 + lr] = f2b(o_acc[dt][r] * invl);
  }
}

// ---------------------------------------------------------------------------
// memories (fp32 out): out[m][h][i][d] = qkv[(3584+i)*3072 + 1024*(m+1) + h*64 + d]
// (must run BEFORE the in-place l2norm of the qkv k-part)
// ---------------------------------------------------------------------------
__global__ __launch_bounds__(256) void memcopy_kernel(const bf16* __restrict__ qkv,
                                                      float* __restrict__ out) {
  const int idx = blockIdx.x * 256 + threadIdx.x;  // 2*16*512*64 = 1048576
  const int d = idx & 63;
  const int i = (idx >> 6) & 511;
  const int h = (idx >> 15) & 15;
  const int mm = idx >> 19;
  out[idx] = ldv(qkv[(size_t)(3584 + i) * 3072 + 1024 * (mm + 1) + h * 64 + d]);
}

// ---------------------------------------------------------------------------
extern "C" void kernel_launch(void* const* d_in, const int* in_sizes, int n_in,
                              void* d_out, int out_size, void* d_ws, size_t ws_size,
                              hipStream_t stream) {
  const float* x = (const float*)d_in[0];
  const float* rel_bias = (const float*)d_in[1];
  const float* gamma = (const float*)d_in[2];
  const float* w_qkv = (const float*)d_in[3];
  const float* q_scale = (const float*)d_in[4];
  const float* k_scale = (const float*)d_in[5];
  const float* w_out = (const float*)d_in[6];
  const float* s_gamma = (const float*)d_in[7];
  const float* w_q2s = (const float*)d_in[8];
  const float* w_qfs = (const float*)d_in[9];
  const float* w_sqkv = (const float*)d_in[10];
  const float* init_state = (const float*)d_in[11];
  const float* state_pos = (const float*)d_in[12];
  const float* w_sout = (const float*)d_in[13];
  const float* ts_qs = (const float*)d_in[14];
  const float* ts_ks = (const float*)d_in[15];
  const float* ss_qs = (const float*)d_in[16];
  const float* ss_ks = (const float*)d_in[17];
  const float* fs_qs = (const float*)d_in[18];
  const float* fs_ks = (const float*)d_in[19];
  const float* w_gate = (const float*)d_in[20];
  const float* b_gate = (const float*)d_in[21];
  const float* ema_beta = (const float*)d_in[22];

  // outputs: FP32
  float* out0 = (float*)d_out;         // [4096,1024]
  float* out_mem = out0 + 4194304;     // [2,16,512,64]
  float* out_ns = out0 + 5242880;      // [512,1024]

  // workspace (bf16 intermediates), 64 MiB total
  bf16* xn = (bf16*)d_ws;          // 4096x1024 (reused: vT_loc, then wT_out/sout)
  bf16* qkv = xn + 4194304;        // 4096x3072 (q/k parts l2norm'd in place)
  bf16* q2s = qkv + 12582912;      // 4096x1024 (reused: wT_gate after attns)
  bf16* aloc = q2s + 4194304;      // 4096x1024
  bf16* ats = aloc + 4194304;      // 4096x1024
  bf16* st = ats + 4194304;        // 512x1024 (later reused as vT_s)
  bf16* sqkv = st + 524288;        // 512x3072 (q/k parts l2norm'd in place)
  bf16* qfs = sqkv + 1572864;      // 512x1024 (l2norm'd in place)
  bf16* socat = qfs + 524288;      // 512x2048
  bf16* soproj = socat + 1048576;  // 512x1024
  bf16* vT_loc = xn;               // [16*64][4096] after q2s gemm consumes xn
  bf16* vT_s = st;                 // [16*64][512]  after qfs gemm consumes st

  // out0 region (16.78MB) as bf16 scratch: early transposed weights, then bshuf
  bf16* out0b = (bf16*)out0;
  bf16* wT_qkv = out0b;                 // 3072x1024
  bf16* wT_q2s = wT_qkv + 3145728;      // 1024x1024
  bf16* wT_sqkv = wT_q2s + 1048576;     // 3072x1024
  bf16* wT_qfs = wT_sqkv + 3145728;     // 1024x1024  (exactly fills out0)
  bf16* bshuf = out0b;                  // [16][512][16][64] bf16 (after GEMMs 1-4)
  // late transposed weights into freed regions
  bf16* wT_out = xn;                    // 2048x1024 (vT_loc dead after attns)
  bf16* wT_sout = xn + 2097152;         // 2048x1024
  bf16* wT_gate = q2s;                  // 1024x1024 (q2s dead after attn 2)

  // 1. layernorms + weight transposes (wT into out0 scratch)
  ln_kernel<<<4096, 256, 0, stream>>>(x, gamma, nullptr, xn);
  ln_kernel<<<512, 256, 0, stream>>>(init_state, s_gamma, state_pos, st);
  wtrans_kernel<<<dim3(16, 48), 256, 0, stream>>>(w_qkv, 3072, wT_qkv, 1024);
  wtrans_kernel<<<dim3(16, 16), 256, 0, stream>>>(w_q2s, 1024, wT_q2s, 1024);
  wtrans_kernel<<<dim3(16, 48), 256, 0, stream>>>(w_sqkv, 3072, wT_sqkv, 1024);
  wtrans_kernel<<<dim3(16, 16), 256, 0, stream>>>(w_qfs, 1024, wT_qfs, 1024);

  // 2. projections (MFMA, bf16 transposed weights)
  mfma_gemm<bf16, bf16><<<dim3(24, 32), 256, 0, stream>>>(
      xn, 1024, nullptr, 0, 0, wT_qkv, qkv, 3072, 1024, 0, nullptr, nullptr, nullptr);
  mfma_gemm<bf16, bf16><<<dim3(8, 32), 256, 0, stream>>>(
      xn, 1024, nullptr, 0, 0, wT_q2s, q2s, 1024, 1024, 0, nullptr, nullptr, nullptr);
  mfma_gemm<float, bf16><<<dim3(24, 4), 256, 0, stream>>>(
      init_state, 1024, nullptr, 0, 0, wT_sqkv, sqkv, 3072, 1024, 0, nullptr, nullptr, nullptr);
  mfma_gemm<bf16, bf16><<<dim3(8, 4), 256, 0, stream>>>(
      st, 1024, nullptr, 0, 0, wT_qfs, qfs, 1024, 1024, 0, nullptr, nullptr, nullptr);

  // 3. memories output (raw k/v, before in-place norm)
  memcopy_kernel<<<4096, 256, 0, stream>>>(qkv, out_mem);

  // 4. V transposes (into freed xn/st regions) + bias shuffle (out0 free now)
  vtrans_kernel<<<dim3(64, 16), 256, 0, stream>>>(qkv, 3072, 2048, 4096, vT_loc);
  vtrans_kernel<<<dim3(8, 16), 256, 0, stream>>>(sqkv, 3072, 2048, 512, vT_s);
  bshuf_kernel<<<dim3(512, 16), 256, 0, stream>>>(rel_bias, bshuf);

  // 5. pre-normalize Q/K (q part carries qs*ks*8; k part plain l2norm)
  l2n_kernel<<<dim3(4096, 2), 256, 0, stream>>>(qkv, 3072, q_scale, k_scale, 8.f);
  l2n_kernel<<<dim3(512, 2), 256, 0, stream>>>(sqkv, 3072, ss_qs, ss_ks, 8.f);
  l2n_kernel<<<dim3(4096, 1), 256, 0, stream>>>(q2s, 1024, ts_qs, ts_ks, 8.f);
  l2n_kernel<<<dim3(512, 1), 256, 0, stream>>>(qfs, 1024, fs_qs, fs_ks, 8.f);

  // 6. attentions (MFMA flash v4; local uses XCD-grouped 1D swizzle)
  attn_mfma<<<1024, 256, 0, stream>>>(
      qkv, 3072, qkv + 1024, 3072, vT_loc, 4096, bshuf, 1, 1024,
      512, -512, 512, 1, aloc, 1024, 0, 64);
  attn_mfma<<<dim3(64, 16, 1), 256, 0, stream>>>(
      q2s, 1024, sqkv + 1024, 3072, vT_s, 512, nullptr, 0, 512,
      4096, 0, 0, 0, ats, 1024, 0, 64);
  attn_mfma<<<dim3(8, 16, 1), 256, 0, stream>>>(
      sqkv, 3072, sqkv + 1024, 3072, vT_s, 512, nullptr, 0, 512,
      512, 0, 0, 0, socat, 2048, 0, 128);
  attn_mfma<<<dim3(8, 16, 1), 256, 0, stream>>>(
      qfs, 1024, qkv + 1024, 3072, vT_loc, 4096, nullptr, 0, 512,
      512, 3584, 0, 0, socat, 2048, 64, 128);

  // 7. late weight transposes (vT_loc/q2s regions now dead)
  wtrans_kernel<<<dim3(32, 16), 256, 0, stream>>>(w_out, 1024, wT_out, 2048);
  wtrans_kernel<<<dim3(32, 16), 256, 0, stream>>>(w_sout, 1024, wT_sout, 2048);
  wtrans_kernel<<<dim3(16, 16), 256, 0, stream>>>(w_gate, 1024, wT_gate, 1024);

  // 8. out0 = [aloc | ats] @ w_out  (fp32 out; overwrites bshuf scratch)
  mfma_gemm<bf16, float><<<dim3(8, 32), 256, 0, stream>>>(
      aloc, 1024, ats, 1024, 1024, wT_out, out0, 1024, 2048, 0, nullptr, nullptr, nullptr);

  // 9. state out path (new_states fp32 out)
  mfma_gemm<bf16, bf16><<<dim3(8, 4), 256, 0, stream>>>(
      socat, 2048, nullptr, 0, 0, wT_sout, soproj, 1024, 2048, 0, nullptr, nullptr, nullptr);
  mfma_gemm<bf16, float><<<dim3(8, 4), 256, 0, stream>>>(
      soproj, 1024, nullptr, 0, 0, wT_gate, out_ns, 1024, 1024, 1, b_gate, ema_beta,
      init_state);
}

// Round 5
// 702.365 us; speedup vs baseline: 1.3865x; 1.0486x over previous
//
#include <hip/hip_runtime.h>
#include <hip/hip_bf16.h>

using bf16 = __hip_bfloat16;
using bf16x8 = __attribute__((ext_vector_type(8))) short;
using f32x4 = __attribute__((ext_vector_type(4))) float;

static __device__ __forceinline__ float ldv(bf16 v) { return __bfloat162float(v); }
static __device__ __forceinline__ float ldv(float v) { return v; }
static __device__ __forceinline__ bf16 f2b(float v) { return __float2bfloat16(v); }
static __device__ __forceinline__ void stv(bf16* p, float v) { *p = __float2bfloat16(v); }
static __device__ __forceinline__ void stv(float* p, float v) { *p = v; }

// load 8 elements (bf16 passthrough / fp32 cvt) into LDS as bf16
static __device__ __forceinline__ void load8(const bf16* p, bf16* dst) {
  *(uint4*)dst = *(const uint4*)p;
}
static __device__ __forceinline__ void load8(const float* p, bf16* dst) {
  float4 a = *(const float4*)p, b = *(const float4*)(p + 4);
  dst[0] = f2b(a.x); dst[1] = f2b(a.y); dst[2] = f2b(a.z); dst[3] = f2b(a.w);
  dst[4] = f2b(b.x); dst[5] = f2b(b.y); dst[6] = f2b(b.z); dst[7] = f2b(b.w);
}

// ---------------------------------------------------------------------------
// LayerNorm (cols = 1024 fixed). out = (x - mean)*rsqrt(var+1e-5)*gamma [+ add]
// ---------------------------------------------------------------------------
__global__ __launch_bounds__(256) void ln_kernel(
    const float* __restrict__ x, const float* __restrict__ gamma,
    const float* __restrict__ add, bf16* __restrict__ out) {
  const int row = blockIdx.x;
  const float* xr = x + (size_t)row * 1024;
  float v[4];
  float s = 0.f, ss = 0.f;
#pragma unroll
  for (int i = 0; i < 4; ++i) {
    v[i] = xr[threadIdx.x + 256 * i];
    s += v[i];
    ss += v[i] * v[i];
  }
#pragma unroll
  for (int m = 1; m < 64; m <<= 1) {
    s += __shfl_xor(s, m);
    ss += __shfl_xor(ss, m);
  }
  __shared__ float red[8];
  const int wid = threadIdx.x >> 6;
  if ((threadIdx.x & 63) == 0) { red[wid] = s; red[wid + 4] = ss; }
  __syncthreads();
  s = red[0] + red[1] + red[2] + red[3];
  ss = red[4] + red[5] + red[6] + red[7];
  const float mean = s * (1.f / 1024.f);
  const float var = ss * (1.f / 1024.f) - mean * mean;
  const float rs = rsqrtf(var + 1e-5f);
  bf16* outr = out + (size_t)row * 1024;
#pragma unroll
  for (int i = 0; i < 4; ++i) {
    int c = threadIdx.x + 256 * i;
    float y = (v[i] - mean) * rs * gamma[c];
    if (add) y += add[(size_t)row * 1024 + c];
    outr[c] = f2b(y);
  }
}

// ---------------------------------------------------------------------------
// Per-head l2norm, in place. blockIdx.y = part (0: cols 0..1023 with scales
// s1*s2*mult; 1: cols 1024..2047 plain l2norm). 16 heads x 64 d per part.
// ---------------------------------------------------------------------------
__global__ __launch_bounds__(256) void l2n_kernel(
    bf16* __restrict__ buf, int rs,
    const float* __restrict__ s1, const float* __restrict__ s2, float mult) {
  const int row = blockIdx.x, part = blockIdx.y, t = threadIdx.x;
  const int d0 = (t & 15) * 4, hoff = (t >> 4) * 64 + part * 1024;
  bf16* p = buf + (size_t)row * rs + hoff + d0;
  bf16 b[4];
  *(ushort4*)b = *(const ushort4*)p;
  float v[4], ss = 0.f;
#pragma unroll
  for (int i = 0; i < 4; ++i) { v[i] = ldv(b[i]); ss += v[i] * v[i]; }
  ss += __shfl_xor(ss, 1);
  ss += __shfl_xor(ss, 2);
  ss += __shfl_xor(ss, 4);
  ss += __shfl_xor(ss, 8);
  const float inv = (part ? 1.f : mult) / fmaxf(sqrtf(ss), 1e-12f);
#pragma unroll
  for (int i = 0; i < 4; ++i) {
    float y = v[i] * inv;
    if (!part && s1) y *= s1[d0 + i];
    if (!part && s2) y *= s2[d0 + i];
    b[i] = f2b(y);
  }
  *(ushort4*)p = *(ushort4*)b;
}

// ---------------------------------------------------------------------------
// Per-head V transpose: dst[h*64+d][n] = src[n][coff + h*64 + d].
// ---------------------------------------------------------------------------
__global__ __launch_bounds__(256) void vtrans_kernel(
    const bf16* __restrict__ src, int rstride, int coff, int nrows,
    bf16* __restrict__ dst) {
  __shared__ bf16 tile[64][72];
  const int n0 = blockIdx.x * 64, h = blockIdx.y, t = threadIdx.x;
  {
    const int nr = t >> 2, dp = (t & 3) * 16;
    const bf16* s = src + (size_t)(n0 + nr) * rstride + coff + h * 64 + dp;
    *(uint4*)&tile[nr][dp] = *(const uint4*)s;
    *(uint4*)&tile[nr][dp + 8] = *(const uint4*)(s + 8);
  }
  __syncthreads();
  {
    const int dr = t >> 2, np = (t & 3) * 16;
    bf16 tmp[16];
#pragma unroll
    for (int i = 0; i < 16; ++i) tmp[i] = tile[np + i][dr];
    bf16* d = dst + (size_t)(h * 64 + dr) * nrows + n0 + np;
    *(uint4*)d = *(uint4*)&tmp[0];
    *(uint4*)(d + 8) = *(uint4*)&tmp[8];
  }
}

// ---------------------------------------------------------------------------
// Weight transpose+cvt: dst[n][k] (bf16, row stride K) = src[k][n] (fp32).
// ---------------------------------------------------------------------------
__global__ __launch_bounds__(256) void wtrans_kernel(
    const float* __restrict__ src, int N, bf16* __restrict__ dst, int K) {
  __shared__ bf16 tile[64][72];
  const int k0 = blockIdx.x * 64, n0 = blockIdx.y * 64, t = threadIdx.x;
  {
    const int kr = t >> 2, np = (t & 3) * 16;
    const float* s = src + (size_t)(k0 + kr) * N + n0 + np;
    bf16 tmp[16];
#pragma unroll
    for (int i = 0; i < 16; ++i) tmp[i] = f2b(s[i]);
    *(uint4*)&tile[kr][np] = *(uint4*)&tmp[0];
    *(uint4*)&tile[kr][np + 8] = *(uint4*)&tmp[8];
  }
  __syncthreads();
  {
    const int nr = t >> 2, kp = (t & 3) * 16;
    bf16 tmp[16];
#pragma unroll
    for (int i = 0; i < 16; ++i) tmp[i] = tile[kp + i][nr];
    bf16* d = dst + (size_t)(n0 + nr) * K + k0 + kp;
    *(uint4*)d = *(uint4*)&tmp[0];
    *(uint4*)(d + 8) = *(uint4*)&tmp[8];
  }
}

// ---------------------------------------------------------------------------
// Bias pre-shuffle: bshuf[h][q][jt][lr*4+j] = bf16(bias[h][q][jt*64 + j*16 + lr])
// ---------------------------------------------------------------------------
__global__ __launch_bounds__(256) void bshuf_kernel(const float* __restrict__ bias,
                                                    bf16* __restrict__ out) {
  const int q = blockIdx.x, h = blockIdx.y, t = threadIdx.x;
  const int jt = t >> 4, lr = t & 15;
  const float* src = bias + ((size_t)h * 512 + q) * 1024 + jt * 64 + lr;
  bf16 b[4];
#pragma unroll
  for (int j = 0; j < 4; ++j) b[j] = f2b(src[j * 16]);
  *(ushort4*)(out + (((size_t)h * 512 + q) * 16 + jt) * 64 + lr * 4) = *(ushort4*)b;
}

// ---------------------------------------------------------------------------
// MFMA GEMM  C[M,N] = Acat[M,K] @ Bt^T   (Bt: bf16 [N][K], row stride K)
// ---------------------------------------------------------------------------
template <typename TA, typename TC>
__global__ __launch_bounds__(256) void mfma_gemm(
    const TA* __restrict__ A, int lda,
    const TA* __restrict__ A2, int lda2, int K1,
    const bf16* __restrict__ Bt,
    TC* __restrict__ C, int ldc, int K,
    int epilogue,
    const float* __restrict__ b_gate, const float* __restrict__ ema_beta,
    const float* __restrict__ init_state) {
  __shared__ bf16 Asb[128][40];  // [m][k], pad 32->40
  __shared__ bf16 Bsb[128][40];  // [n][k], pad 32->40
  const int bm = blockIdx.y * 128, bn = blockIdx.x * 128;
  const int tid = threadIdx.x;
  const int w = tid >> 6, lane = tid & 63;
  const int wm = (w >> 1) * 64, wn = (w & 1) * 64;
  const int lr = lane & 15, quad = lane >> 4, ko = quad * 8;
  const int sn = tid >> 1, skh = (tid & 1) * 16;  // B staging map (vector copy)

  f32x4 acc[4][4] = {};

  for (int kt = 0; kt < K; kt += 32) {
    // ---- stage A (2 chunks of 8 per thread) ----
#pragma unroll
    for (int c = 0; c < 2; ++c) {
      const int q = tid + 256 * c;
      const int m = q >> 2, kk = (q & 3) * 8;
      const int gk = kt + kk;
      const TA* ap = (A2 && gk >= K1)
                         ? (A2 + (size_t)(bm + m) * lda2 + (gk - K1))
                         : (A + (size_t)(bm + m) * lda + gk);
      load8(ap, &Asb[m][kk]);
    }
    // ---- stage B: pure 32B vector copy per thread ----
    {
      const bf16* bp = Bt + (size_t)(bn + sn) * K + kt + skh;
      *(uint4*)&Bsb[sn][skh] = *(const uint4*)bp;
      *(uint4*)&Bsb[sn][skh + 8] = *(const uint4*)(bp + 8);
    }
    __syncthreads();

    bf16x8 af[4], bfr[4];
#pragma unroll
    for (int i = 0; i < 4; ++i) af[i] = *(const bf16x8*)&Asb[wm + i * 16 + lr][ko];
#pragma unroll
    for (int j = 0; j < 4; ++j) bfr[j] = *(const bf16x8*)&Bsb[wn + j * 16 + lr][ko];
#pragma unroll
    for (int i = 0; i < 4; ++i)
#pragma unroll
      for (int j = 0; j < 4; ++j)
        acc[i][j] = __builtin_amdgcn_mfma_f32_16x16x32_bf16(af[i], bfr[j],
                                                            acc[i][j], 0, 0, 0);
    __syncthreads();
  }

#pragma unroll
  for (int i = 0; i < 4; ++i) {
#pragma unroll
    for (int j = 0; j < 4; ++j) {
#pragma unroll
      for (int r = 0; r < 4; ++r) {
        const int row = bm + wm + i * 16 + quad * 4 + r;
        const int col = bn + wn + j * 16 + lr;
        float v = acc[i][j][r];
        if (epilogue == 1) {
          float z = v + b_gate[col];
          float d = 1.f / (1.f + __expf(-ema_beta[col]));
          v = d * z + (1.f - d) * init_state[(size_t)row * 1024 + col];
        }
        stv(&C[(size_t)row * ldc + col], v);
      }
    }
  }
}

// ---------------------------------------------------------------------------
// MFMA flash attention v5.
// - STATIC-MAX softmax: cosine-sim attention bounds |S| <= 8*|qs|*|ks| (+small
//   bias), so softmax uses a FIXED shift M0=12 (shift-invariant => exact).
//   No running max, no alpha rescale, no cross-lane ops in the k-loop; the
//   l-sum 16-lane reduction is linear and deferred to the epilogue.
// - Chunked XCD swizzle: B' = (B%8)*(nblk/8) + B/8, zb fastest -> each XCD
//   owns whole heads: K/V AND bias slices stay in its L2.
// - K/V + bias register-prefetched one tile ahead.
// ---------------------------------------------------------------------------
__global__ __launch_bounds__(256, 4) void attn_mfma(
    const bf16* __restrict__ qp, int q_rstride,
    const bf16* __restrict__ kp, int k_rstride,
    const bf16* __restrict__ vtp, int v_nstride,
    const bf16* __restrict__ bshuf, int causal, int nkeys,
    int qrows_per_blk, int kbase0, int krows_per_blk, int nqt, int nzb,
    bf16* __restrict__ op, int o_rstride, int o_coff, int o_hstride) {
  __shared__ __align__(16) bf16 ksb[64][72];  // [krow][d]
  __shared__ __align__(16) bf16 vsb[64][72];  // [d][krow]
  __shared__ __align__(16) bf16 psb[64][72];  // [qrow][kcol]
  // chunked decode: hardware wgid%8 = XCD -> chunk c=B%8 owns B' range
  // [c*(nblk/8), (c+1)*(nblk/8)): contiguous (h,qt,zb) with zb fastest.
  const int Bp = (blockIdx.x & 7) * ((int)gridDim.x >> 3) + (blockIdx.x >> 3);
  const int zb = Bp % nzb;
  const int qt = (Bp / nzb) % nqt;
  const int h = Bp / (nzb * nqt);
  const int tid = threadIdx.x;
  const int w = tid >> 6, lane = tid & 63;
  const int lr = lane & 15, quad = lane >> 4;
  const int wq = w * 16;
  const int qbase = zb * qrows_per_blk + qt * 64;

  // ---- Q fragments once, directly to registers (row=wq+lr, k=dc*32+quad*8) ----
  bf16x8 qf[2];
  {
    const bf16* qr = qp + (size_t)(qbase + wq + lr) * q_rstride + h * 64 + quad * 8;
    qf[0] = *(const bf16x8*)qr;
    qf[1] = *(const bf16x8*)(qr + 32);
  }

  float l_i[4] = {0.f, 0.f, 0.f, 0.f};
  f32x4 o_acc[4] = {};

  const int kbase = kbase0 + zb * krows_per_blk;
  const int ntk = causal ? min(nkeys, qt * 64 + 64 + 512) : nkeys;
  const int kr = tid >> 2, kc = (tid & 3) * 16;

  uint4 kreg[2], vreg[2];
  ushort4 bcur[4], bnxt[4];
  const uint4 z4{0, 0, 0, 0};
  auto load_kv = [&](int jt) {
    const int krow = kbase + jt + kr;
    if (krow >= 0) {
      const bf16* s = kp + (size_t)krow * k_rstride + h * 64 + kc;
      kreg[0] = *(const uint4*)s;
      kreg[1] = *(const uint4*)(s + 8);
    } else { kreg[0] = z4; kreg[1] = z4; }
    const int col = kbase + jt + kc;
    if (col >= 0) {
      const bf16* s = vtp + (size_t)(h * 64 + kr) * v_nstride + col;
      vreg[0] = *(const uint4*)s;
      vreg[1] = *(const uint4*)(s + 8);
    } else { vreg[0] = z4; vreg[1] = z4; }
  };
  auto load_bias = [&](int jt, ushort4* br) {
#pragma unroll
    for (int r = 0; r < 4; ++r) {
      const int qloc = qt * 64 + wq + quad * 4 + r;
      br[r] = *(const ushort4*)(bshuf +
          (((size_t)h * 512 + qloc) * 16 + (jt >> 6)) * 64 + lr * 4);
    }
  };
  auto store_kv = [&]() {
    *(uint4*)&ksb[kr][kc] = kreg[0];
    *(uint4*)&ksb[kr][kc + 8] = kreg[1];
    *(uint4*)&vsb[kr][kc] = vreg[0];
    *(uint4*)&vsb[kr][kc + 8] = vreg[1];
  };

  load_kv(0);
  if (bshuf) load_bias(0, bcur);
  store_kv();

  for (int jt = 0; jt < ntk; jt += 64) {
    __syncthreads();  // staged tile visible to all waves
    const bool pre = jt + 64 < ntk;
    if (pre) {
      load_kv(jt + 64);  // global loads in flight during compute
      if (bshuf) load_bias(jt + 64, bnxt);
    }

    // ---- S[16x64] = Q @ K^T ----
    f32x4 s_acc[4] = {};
#pragma unroll
    for (int dc = 0; dc < 2; ++dc) {
#pragma unroll
      for (int j = 0; j < 4; ++j) {
        bf16x8 kf = *(const bf16x8*)&ksb[j * 16 + lr][dc * 32 + quad * 8];
        s_acc[j] = __builtin_amdgcn_mfma_f32_16x16x32_bf16(qf[dc], kf, s_acc[j], 0, 0, 0);
      }
    }

    // ---- bias + causal + static-max softmax (no cross-lane ops) ----
#pragma unroll
    for (int r = 0; r < 4; ++r) {
      const int brow = wq + quad * 4 + r;
      const int qloc = qt * 64 + brow;
      bf16 bb[4];
      if (bshuf) *(ushort4*)bb = bcur[r];
      float rsum = 0.f;
      bf16 pb[4];
#pragma unroll
      for (int j = 0; j < 4; ++j) {
        float s = s_acc[j][r];
        if (bshuf) s += ldv(bb[j]);
        if (causal && (jt + j * 16 + lr > qloc + 512)) s = -3.0e38f;
        const float p = __expf(s - 12.f);
        rsum += p;
        pb[j] = f2b(p);
      }
      l_i[r] += rsum;
#pragma unroll
      for (int j = 0; j < 4; ++j) psb[brow][j * 16 + lr] = pb[j];
    }

    // ---- O[16x64] += P @ V (psb rows wave-private; DS in-order per wave) ----
#pragma unroll
    for (int jc = 0; jc < 2; ++jc) {
      bf16x8 pf = *(const bf16x8*)&psb[wq + lr][jc * 32 + quad * 8];
#pragma unroll
      for (int dt = 0; dt < 4; ++dt) {
        bf16x8 vf = *(const bf16x8*)&vsb[dt * 16 + lr][jc * 32 + quad * 8];
        o_acc[dt] = __builtin_amdgcn_mfma_f32_16x16x32_bf16(pf, vf, o_acc[dt], 0, 0, 0);
      }
    }

    __syncthreads();  // all waves done with ksb/vsb
    if (pre) {
      store_kv();
      if (bshuf) {
#pragma unroll
        for (int r = 0; r < 4; ++r) bcur[r] = bnxt[r];
      }
    }
  }

  // ---- epilogue: finish the (linear) l reduction across the 16-lane group ----
#pragma unroll
  for (int r = 0; r < 4; ++r) {
#pragma unroll
    for (int mm = 1; mm < 16; mm <<= 1) l_i[r] += __shfl_xor(l_i[r], mm);
    const int qrow = qbase + wq + quad * 4 + r;
    const float invl = 1.f / l_i[r];
    bf16* orow = op + (size_t)qrow * o_rstride + o_coff + (size_t)h * o_hstride;
#pragma unroll
    for (int dt = 0; dt < 4; ++dt) orow[dt * 16 + lr] = f2b(o_acc[dt][r] * invl);
  }
}

// ---------------------------------------------------------------------------
// memories (fp32 out): out[m][h][i][d] = qkv[(3584+i)*3072 + 1024*(m+1) + h*64 + d]
// (must run BEFORE the in-place l2norm of the qkv k-part)
// ---------------------------------------------------------------------------
__global__ __launch_bounds__(256) void memcopy_kernel(const bf16* __restrict__ qkv,
                                                      float* __restrict__ out) {
  const int idx = blockIdx.x * 256 + threadIdx.x;  // 2*16*512*64 = 1048576
  const int d = idx & 63;
  const int i = (idx >> 6) & 511;
  const int h = (idx >> 15) & 15;
  const int mm = idx >> 19;
  out[idx] = ldv(qkv[(size_t)(3584 + i) * 3072 + 1024 * (mm + 1) + h * 64 + d]);
}

// ---------------------------------------------------------------------------
extern "C" void kernel_launch(void* const* d_in, const int* in_sizes, int n_in,
                              void* d_out, int out_size, void* d_ws, size_t ws_size,
                              hipStream_t stream) {
  const float* x = (const float*)d_in[0];
  const float* rel_bias = (const float*)d_in[1];
  const float* gamma = (const float*)d_in[2];
  const float* w_qkv = (const float*)d_in[3];
  const float* q_scale = (const float*)d_in[4];
  const float* k_scale = (const float*)d_in[5];
  const float* w_out = (const float*)d_in[6];
  const float* s_gamma = (const float*)d_in[7];
  const float* w_q2s = (const float*)d_in[8];
  const float* w_qfs = (const float*)d_in[9];
  const float* w_sqkv = (const float*)d_in[10];
  const float* init_state = (const float*)d_in[11];
  const float* state_pos = (const float*)d_in[12];
  const float* w_sout = (const float*)d_in[13];
  const float* ts_qs = (const float*)d_in[14];
  const float* ts_ks = (const float*)d_in[15];
  const float* ss_qs = (const float*)d_in[16];
  const float* ss_ks = (const float*)d_in[17];
  const float* fs_qs = (const float*)d_in[18];
  const float* fs_ks = (const float*)d_in[19];
  const float* w_gate = (const float*)d_in[20];
  const float* b_gate = (const float*)d_in[21];
  const float* ema_beta = (const float*)d_in[22];

  // outputs: FP32
  float* out0 = (float*)d_out;         // [4096,1024]
  float* out_mem = out0 + 4194304;     // [2,16,512,64]
  float* out_ns = out0 + 5242880;      // [512,1024]

  // workspace (bf16 intermediates), 64 MiB total
  bf16* xn = (bf16*)d_ws;          // 4096x1024 (reused: vT_loc, then wT_out/sout)
  bf16* qkv = xn + 4194304;        // 4096x3072 (q/k parts l2norm'd in place)
  bf16* q2s = qkv + 12582912;      // 4096x1024 (reused: wT_gate after attns)
  bf16* aloc = q2s + 4194304;      // 4096x1024
  bf16* ats = aloc + 4194304;      // 4096x1024
  bf16* st = ats + 4194304;        // 512x1024 (later reused as vT_s)
  bf16* sqkv = st + 524288;        // 512x3072 (q/k parts l2norm'd in place)
  bf16* qfs = sqkv + 1572864;      // 512x1024 (l2norm'd in place)
  bf16* socat = qfs + 524288;      // 512x2048
  bf16* soproj = socat + 1048576;  // 512x1024
  bf16* vT_loc = xn;               // [16*64][4096] after q2s gemm consumes xn
  bf16* vT_s = st;                 // [16*64][512]  after qfs gemm consumes st

  // out0 region (16.78MB) as bf16 scratch: early transposed weights, then bshuf
  bf16* out0b = (bf16*)out0;
  bf16* wT_qkv = out0b;                 // 3072x1024
  bf16* wT_q2s = wT_qkv + 3145728;      // 1024x1024
  bf16* wT_sqkv = wT_q2s + 1048576;     // 3072x1024
  bf16* wT_qfs = wT_sqkv + 3145728;     // 1024x1024  (exactly fills out0)
  bf16* bshuf = out0b;                  // [16][512][16][64] bf16 (after GEMMs 1-4)
  // late transposed weights into freed regions
  bf16* wT_out = xn;                    // 2048x1024 (vT_loc dead after attns)
  bf16* wT_sout = xn + 2097152;         // 2048x1024
  bf16* wT_gate = q2s;                  // 1024x1024 (q2s dead after attn 2)

  // 1. layernorms + weight transposes (wT into out0 scratch)
  ln_kernel<<<4096, 256, 0, stream>>>(x, gamma, nullptr, xn);
  ln_kernel<<<512, 256, 0, stream>>>(init_state, s_gamma, state_pos, st);
  wtrans_kernel<<<dim3(16, 48), 256, 0, stream>>>(w_qkv, 3072, wT_qkv, 1024);
  wtrans_kernel<<<dim3(16, 16), 256, 0, stream>>>(w_q2s, 1024, wT_q2s, 1024);
  wtrans_kernel<<<dim3(16, 48), 256, 0, stream>>>(w_sqkv, 3072, wT_sqkv, 1024);
  wtrans_kernel<<<dim3(16, 16), 256, 0, stream>>>(w_qfs, 1024, wT_qfs, 1024);

  // 2. projections (MFMA, bf16 transposed weights)
  mfma_gemm<bf16, bf16><<<dim3(24, 32), 256, 0, stream>>>(
      xn, 1024, nullptr, 0, 0, wT_qkv, qkv, 3072, 1024, 0, nullptr, nullptr, nullptr);
  mfma_gemm<bf16, bf16><<<dim3(8, 32), 256, 0, stream>>>(
      xn, 1024, nullptr, 0, 0, wT_q2s, q2s, 1024, 1024, 0, nullptr, nullptr, nullptr);
  mfma_gemm<float, bf16><<<dim3(24, 4), 256, 0, stream>>>(
      init_state, 1024, nullptr, 0, 0, wT_sqkv, sqkv, 3072, 1024, 0, nullptr, nullptr, nullptr);
  mfma_gemm<bf16, bf16><<<dim3(8, 4), 256, 0, stream>>>(
      st, 1024, nullptr, 0, 0, wT_qfs, qfs, 1024, 1024, 0, nullptr, nullptr, nullptr);

  // 3. memories output (raw k/v, before in-place norm)
  memcopy_kernel<<<4096, 256, 0, stream>>>(qkv, out_mem);

  // 4. V transposes (into freed xn/st regions) + bias shuffle (out0 free now)
  vtrans_kernel<<<dim3(64, 16), 256, 0, stream>>>(qkv, 3072, 2048, 4096, vT_loc);
  vtrans_kernel<<<dim3(8, 16), 256, 0, stream>>>(sqkv, 3072, 2048, 512, vT_s);
  bshuf_kernel<<<dim3(512, 16), 256, 0, stream>>>(rel_bias, bshuf);

  // 5. pre-normalize Q/K (q part carries qs*ks*8; k part plain l2norm)
  l2n_kernel<<<dim3(4096, 2), 256, 0, stream>>>(qkv, 3072, q_scale, k_scale, 8.f);
  l2n_kernel<<<dim3(512, 2), 256, 0, stream>>>(sqkv, 3072, ss_qs, ss_ks, 8.f);
  l2n_kernel<<<dim3(4096, 1), 256, 0, stream>>>(q2s, 1024, ts_qs, ts_ks, 8.f);
  l2n_kernel<<<dim3(512, 1), 256, 0, stream>>>(qfs, 1024, fs_qs, fs_ks, 8.f);

  // 6. attentions (MFMA flash v5; chunked XCD swizzle, zb fastest)
  attn_mfma<<<1024, 256, 0, stream>>>(
      qkv, 3072, qkv + 1024, 3072, vT_loc, 4096, bshuf, 1, 1024,
      512, -512, 512, 8, 8, aloc, 1024, 0, 64);
  attn_mfma<<<1024, 256, 0, stream>>>(
      q2s, 1024, sqkv + 1024, 3072, vT_s, 512, nullptr, 0, 512,
      4096, 0, 0, 64, 1, ats, 1024, 0, 64);
  attn_mfma<<<128, 256, 0, stream>>>(
      sqkv, 3072, sqkv + 1024, 3072, vT_s, 512, nullptr, 0, 512,
      512, 0, 0, 8, 1, socat, 2048, 0, 128);
  attn_mfma<<<128, 256, 0, stream>>>(
      qfs, 1024, qkv + 1024, 3072, vT_loc, 4096, nullptr, 0, 512,
      512, 3584, 0, 8, 1, socat, 2048, 64, 128);

  // 7. late weight transposes (vT_loc/q2s regions now dead)
  wtrans_kernel<<<dim3(32, 16), 256, 0, stream>>>(w_out, 1024, wT_out, 2048);
  wtrans_kernel<<<dim3(32, 16), 256, 0, stream>>>(w_sout, 1024, wT_sout, 2048);
  wtrans_kernel<<<dim3(16, 16), 256, 0, stream>>>(w_gate, 1024, wT_gate, 1024);

  // 8. out0 = [aloc | ats] @ w_out  (fp32 out; overwrites bshuf scratch)
  mfma_gemm<bf16, float><<<dim3(8, 32), 256, 0, stream>>>(
      aloc, 1024, ats, 1024, 1024, wT_out, out0, 1024, 2048, 0, nullptr, nullptr, nullptr);

  // 9. state out path (new_states fp32 out)
  mfma_gemm<bf16, bf16><<<dim3(8, 4), 256, 0, stream>>>(
      socat, 2048, nullptr, 0, 0, wT_sout, soproj, 1024, 2048, 0, nullptr, nullptr, nullptr);
  mfma_gemm<bf16, float><<<dim3(8, 4), 256, 0, stream>>>(
      soproj, 1024, nullptr, 0, 0, wT_gate, out_ns, 1024, 1024, 1, b_gate, ema_beta,
      init_state);
}

// Round 6
// 609.771 us; speedup vs baseline: 1.5971x; 1.1519x over previous
//
#include <hip/hip_runtime.h>
#include <hip/hip_bf16.h>

using bf16 = __hip_bfloat16;
using bf16x8 = __attribute__((ext_vector_type(8))) short;
using f32x4 = __attribute__((ext_vector_type(4))) float;

static __device__ __forceinline__ float ldv(bf16 v) { return __bfloat162float(v); }
static __device__ __forceinline__ float ldv(float v) { return v; }
static __device__ __forceinline__ bf16 f2b(float v) { return __float2bfloat16(v); }
static __device__ __forceinline__ void stv(bf16* p, float v) { *p = __float2bfloat16(v); }
static __device__ __forceinline__ void stv(float* p, float v) { *p = v; }

// load 8 elements (bf16 passthrough / fp32 cvt) into LDS as bf16
static __device__ __forceinline__ void load8(const bf16* p, bf16* dst) {
  *(uint4*)dst = *(const uint4*)p;
}
static __device__ __forceinline__ void load8(const float* p, bf16* dst) {
  float4 a = *(const float4*)p, b = *(const float4*)(p + 4);
  dst[0] = f2b(a.x); dst[1] = f2b(a.y); dst[2] = f2b(a.z); dst[3] = f2b(a.w);
  dst[4] = f2b(b.x); dst[5] = f2b(b.y); dst[6] = f2b(b.z); dst[7] = f2b(b.w);
}

// ---------------------------------------------------------------------------
// LayerNorm (cols = 1024 fixed). out = (x - mean)*rsqrt(var+1e-5)*gamma [+ add]
// ---------------------------------------------------------------------------
__global__ __launch_bounds__(256) void ln_kernel(
    const float* __restrict__ x, const float* __restrict__ gamma,
    const float* __restrict__ add, bf16* __restrict__ out) {
  const int row = blockIdx.x;
  const float* xr = x + (size_t)row * 1024;
  float v[4];
  float s = 0.f, ss = 0.f;
#pragma unroll
  for (int i = 0; i < 4; ++i) {
    v[i] = xr[threadIdx.x + 256 * i];
    s += v[i];
    ss += v[i] * v[i];
  }
#pragma unroll
  for (int m = 1; m < 64; m <<= 1) {
    s += __shfl_xor(s, m);
    ss += __shfl_xor(ss, m);
  }
  __shared__ float red[8];
  const int wid = threadIdx.x >> 6;
  if ((threadIdx.x & 63) == 0) { red[wid] = s; red[wid + 4] = ss; }
  __syncthreads();
  s = red[0] + red[1] + red[2] + red[3];
  ss = red[4] + red[5] + red[6] + red[7];
  const float mean = s * (1.f / 1024.f);
  const float var = ss * (1.f / 1024.f) - mean * mean;
  const float rs = rsqrtf(var + 1e-5f);
  bf16* outr = out + (size_t)row * 1024;
#pragma unroll
  for (int i = 0; i < 4; ++i) {
    int c = threadIdx.x + 256 * i;
    float y = (v[i] - mean) * rs * gamma[c];
    if (add) y += add[(size_t)row * 1024 + c];
    outr[c] = f2b(y);
  }
}

// ---------------------------------------------------------------------------
// Per-head l2norm, in place. blockIdx.y = part (0: cols 0..1023 with scales
// s1*s2*mult; 1: cols 1024..2047 plain l2norm). 16 heads x 64 d per part.
// ---------------------------------------------------------------------------
__global__ __launch_bounds__(256) void l2n_kernel(
    bf16* __restrict__ buf, int rs,
    const float* __restrict__ s1, const float* __restrict__ s2, float mult) {
  const int row = blockIdx.x, part = blockIdx.y, t = threadIdx.x;
  const int d0 = (t & 15) * 4, hoff = (t >> 4) * 64 + part * 1024;
  bf16* p = buf + (size_t)row * rs + hoff + d0;
  bf16 b[4];
  *(ushort4*)b = *(const ushort4*)p;
  float v[4], ss = 0.f;
#pragma unroll
  for (int i = 0; i < 4; ++i) { v[i] = ldv(b[i]); ss += v[i] * v[i]; }
  ss += __shfl_xor(ss, 1);
  ss += __shfl_xor(ss, 2);
  ss += __shfl_xor(ss, 4);
  ss += __shfl_xor(ss, 8);
  const float inv = (part ? 1.f : mult) / fmaxf(sqrtf(ss), 1e-12f);
#pragma unroll
  for (int i = 0; i < 4; ++i) {
    float y = v[i] * inv;
    if (!part && s1) y *= s1[d0 + i];
    if (!part && s2) y *= s2[d0 + i];
    b[i] = f2b(y);
  }
  *(ushort4*)p = *(ushort4*)b;
}

// ---------------------------------------------------------------------------
// Per-head V transpose: dst[h*64+d][n] = src[n][coff + h*64 + d].
// ---------------------------------------------------------------------------
__global__ __launch_bounds__(256) void vtrans_kernel(
    const bf16* __restrict__ src, int rstride, int coff, int nrows,
    bf16* __restrict__ dst) {
  __shared__ bf16 tile[64][72];
  const int n0 = blockIdx.x * 64, h = blockIdx.y, t = threadIdx.x;
  {
    const int nr = t >> 2, dp = (t & 3) * 16;
    const bf16* s = src + (size_t)(n0 + nr) * rstride + coff + h * 64 + dp;
    *(uint4*)&tile[nr][dp] = *(const uint4*)s;
    *(uint4*)&tile[nr][dp + 8] = *(const uint4*)(s + 8);
  }
  __syncthreads();
  {
    const int dr = t >> 2, np = (t & 3) * 16;
    bf16 tmp[16];
#pragma unroll
    for (int i = 0; i < 16; ++i) tmp[i] = tile[np + i][dr];
    bf16* d = dst + (size_t)(h * 64 + dr) * nrows + n0 + np;
    *(uint4*)d = *(uint4*)&tmp[0];
    *(uint4*)(d + 8) = *(uint4*)&tmp[8];
  }
}

// ---------------------------------------------------------------------------
// Weight transpose+cvt: dst[n][k] (bf16, row stride K) = src[k][n] (fp32).
// ---------------------------------------------------------------------------
__global__ __launch_bounds__(256) void wtrans_kernel(
    const float* __restrict__ src, int N, bf16* __restrict__ dst, int K) {
  __shared__ bf16 tile[64][72];
  const int k0 = blockIdx.x * 64, n0 = blockIdx.y * 64, t = threadIdx.x;
  {
    const int kr = t >> 2, np = (t & 3) * 16;
    const float* s = src + (size_t)(k0 + kr) * N + n0 + np;
    bf16 tmp[16];
#pragma unroll
    for (int i = 0; i < 16; ++i) tmp[i] = f2b(s[i]);
    *(uint4*)&tile[kr][np] = *(uint4*)&tmp[0];
    *(uint4*)&tile[kr][np + 8] = *(uint4*)&tmp[8];
  }
  __syncthreads();
  {
    const int nr = t >> 2, kp = (t & 3) * 16;
    bf16 tmp[16];
#pragma unroll
    for (int i = 0; i < 16; ++i) tmp[i] = tile[kp + i][nr];
    bf16* d = dst + (size_t)(n0 + nr) * K + k0 + kp;
    *(uint4*)d = *(uint4*)&tmp[0];
    *(uint4*)(d + 8) = *(uint4*)&tmp[8];
  }
}

// ---------------------------------------------------------------------------
// Bias pre-shuffle: bshuf[h][q][jt][lr*4+j] = bf16(bias[h][q][jt*64 + j*16 + lr])
// ---------------------------------------------------------------------------
__global__ __launch_bounds__(256) void bshuf_kernel(const float* __restrict__ bias,
                                                    bf16* __restrict__ out) {
  const int q = blockIdx.x, h = blockIdx.y, t = threadIdx.x;
  const int jt = t >> 4, lr = t & 15;
  const float* src = bias + ((size_t)h * 512 + q) * 1024 + jt * 64 + lr;
  bf16 b[4];
#pragma unroll
  for (int j = 0; j < 4; ++j) b[j] = f2b(src[j * 16]);
  *(ushort4*)(out + (((size_t)h * 512 + q) * 16 + jt) * 64 + lr * 4) = *(ushort4*)b;
}

// ---------------------------------------------------------------------------
// MFMA GEMM  C[M,N] = Acat[M,K] @ Bt^T   (Bt: bf16 [N][K], row stride K)
// ---------------------------------------------------------------------------
template <typename TA, typename TC>
__global__ __launch_bounds__(256) void mfma_gemm(
    const TA* __restrict__ A, int lda,
    const TA* __restrict__ A2, int lda2, int K1,
    const bf16* __restrict__ Bt,
    TC* __restrict__ C, int ldc, int K,
    int epilogue,
    const float* __restrict__ b_gate, const float* __restrict__ ema_beta,
    const float* __restrict__ init_state) {
  __shared__ bf16 Asb[128][40];  // [m][k], pad 32->40
  __shared__ bf16 Bsb[128][40];  // [n][k], pad 32->40
  const int bm = blockIdx.y * 128, bn = blockIdx.x * 128;
  const int tid = threadIdx.x;
  const int w = tid >> 6, lane = tid & 63;
  const int wm = (w >> 1) * 64, wn = (w & 1) * 64;
  const int lr = lane & 15, quad = lane >> 4, ko = quad * 8;
  const int sn = tid >> 1, skh = (tid & 1) * 16;  // B staging map (vector copy)

  f32x4 acc[4][4] = {};

  for (int kt = 0; kt < K; kt += 32) {
    // ---- stage A (2 chunks of 8 per thread) ----
#pragma unroll
    for (int c = 0; c < 2; ++c) {
      const int q = tid + 256 * c;
      const int m = q >> 2, kk = (q & 3) * 8;
      const int gk = kt + kk;
      const TA* ap = (A2 && gk >= K1)
                         ? (A2 + (size_t)(bm + m) * lda2 + (gk - K1))
                         : (A + (size_t)(bm + m) * lda + gk);
      load8(ap, &Asb[m][kk]);
    }
    // ---- stage B: pure 32B vector copy per thread ----
    {
      const bf16* bp = Bt + (size_t)(bn + sn) * K + kt + skh;
      *(uint4*)&Bsb[sn][skh] = *(const uint4*)bp;
      *(uint4*)&Bsb[sn][skh + 8] = *(const uint4*)(bp + 8);
    }
    __syncthreads();

    bf16x8 af[4], bfr[4];
#pragma unroll
    for (int i = 0; i < 4; ++i) af[i] = *(const bf16x8*)&Asb[wm + i * 16 + lr][ko];
#pragma unroll
    for (int j = 0; j < 4; ++j) bfr[j] = *(const bf16x8*)&Bsb[wn + j * 16 + lr][ko];
#pragma unroll
    for (int i = 0; i < 4; ++i)
#pragma unroll
      for (int j = 0; j < 4; ++j)
        acc[i][j] = __builtin_amdgcn_mfma_f32_16x16x32_bf16(af[i], bfr[j],
                                                            acc[i][j], 0, 0, 0);
    __syncthreads();
  }

#pragma unroll
  for (int i = 0; i < 4; ++i) {
#pragma unroll
    for (int j = 0; j < 4; ++j) {
#pragma unroll
      for (int r = 0; r < 4; ++r) {
        const int row = bm + wm + i * 16 + quad * 4 + r;
        const int col = bn + wn + j * 16 + lr;
        float v = acc[i][j][r];
        if (epilogue == 1) {
          float z = v + b_gate[col];
          float d = 1.f / (1.f + __expf(-ema_beta[col]));
          v = d * z + (1.f - d) * init_state[(size_t)row * 1024 + col];
        }
        stv(&C[(size_t)row * ldc + col], v);
      }
    }
  }
}

// ---------------------------------------------------------------------------
// MFMA flash attention v6. Same algorithm as v5 (static-max softmax, chunked
// XCD swizzle, 1-tile-ahead prefetch) but staging uses STRAIGHT-LINE macros
// into individually NAMED registers. v3-v5 used [&]-captured register arrays
// in lambdas; the compiler demoted them to scratch (VGPR_Count=60, WRITE_SIZE
// 154-210MB of scratch writeback vs 8MB real output). No arrays, no lambdas.
// ---------------------------------------------------------------------------
#define LOAD_KV(JT, K0, K1, V0, V1)                                        \
  {                                                                        \
    const int krow_ = kbase + (JT) + kr;                                   \
    if (krow_ >= 0) {                                                      \
      const bf16* s_ = kp + (size_t)krow_ * k_rstride + h * 64 + kc;       \
      K0 = *(const uint4*)s_;                                              \
      K1 = *(const uint4*)(s_ + 8);                                        \
    } else { K0 = z4; K1 = z4; }                                           \
    const int col_ = kbase + (JT) + kc;                                    \
    if (col_ >= 0) {                                                       \
      const bf16* s_ = vtp + (size_t)(h * 64 + kr) * v_nstride + col_;     \
      V0 = *(const uint4*)s_;                                              \
      V1 = *(const uint4*)(s_ + 8);                                        \
    } else { V0 = z4; V1 = z4; }                                           \
  }

#define STORE_KV(K0, K1, V0, V1)          \
  {                                       \
    *(uint4*)&ksb[kr][kc] = K0;           \
    *(uint4*)&ksb[kr][kc + 8] = K1;       \
    *(uint4*)&vsb[kr][kc] = V0;           \
    *(uint4*)&vsb[kr][kc + 8] = V1;       \
  }

#define LOAD_BIAS(JT, B0, B1, B2, B3)                                      \
  {                                                                        \
    const bf16* bp_ = bshuf + (((size_t)h * 512 + qt * 64 + wq +           \
                                quad * 4) * 16 + ((JT) >> 6)) * 64 + lr * 4; \
    B0 = *(const ushort4*)bp_;                                             \
    B1 = *(const ushort4*)(bp_ + 1024);                                    \
    B2 = *(const ushort4*)(bp_ + 2048);                                    \
    B3 = *(const ushort4*)(bp_ + 3072);                                    \
  }

__global__ __launch_bounds__(256, 4) void attn_mfma(
    const bf16* __restrict__ qp, int q_rstride,
    const bf16* __restrict__ kp, int k_rstride,
    const bf16* __restrict__ vtp, int v_nstride,
    const bf16* __restrict__ bshuf, int causal, int nkeys,
    int qrows_per_blk, int kbase0, int krows_per_blk, int nqt, int nzb,
    bf16* __restrict__ op, int o_rstride, int o_coff, int o_hstride) {
  __shared__ __align__(16) bf16 ksb[64][72];  // [krow][d]
  __shared__ __align__(16) bf16 vsb[64][72];  // [d][krow]
  __shared__ __align__(16) bf16 psb[64][72];  // [qrow][kcol]
  // chunked decode: hardware wgid%8 = XCD -> chunk c=B%8 owns B' range
  // [c*(nblk/8), (c+1)*(nblk/8)): contiguous (h,qt,zb) with zb fastest.
  const int Bp = (blockIdx.x & 7) * ((int)gridDim.x >> 3) + (blockIdx.x >> 3);
  const int zb = Bp % nzb;
  const int qt = (Bp / nzb) % nqt;
  const int h = Bp / (nzb * nqt);
  const int tid = threadIdx.x;
  const int w = tid >> 6, lane = tid & 63;
  const int lr = lane & 15, quad = lane >> 4;
  const int wq = w * 16;
  const int qbase = zb * qrows_per_blk + qt * 64;

  // ---- Q fragments once, directly to registers (row=wq+lr, k=dc*32+quad*8) ----
  bf16x8 qf0, qf1;
  {
    const bf16* qr = qp + (size_t)(qbase + wq + lr) * q_rstride + h * 64 + quad * 8;
    qf0 = *(const bf16x8*)qr;
    qf1 = *(const bf16x8*)(qr + 32);
  }

  float l_i[4] = {0.f, 0.f, 0.f, 0.f};
  f32x4 o_acc[4] = {};

  const int kbase = kbase0 + zb * krows_per_blk;
  const int ntk = causal ? min(nkeys, qt * 64 + 64 + 512) : nkeys;
  const int kr = tid >> 2, kc = (tid & 3) * 16;

  const uint4 z4{0, 0, 0, 0};
  uint4 ka0, ka1, va0, va1;
  ushort4 bc0{0,0,0,0}, bc1{0,0,0,0}, bc2{0,0,0,0}, bc3{0,0,0,0};

  LOAD_KV(0, ka0, ka1, va0, va1);
  if (bshuf) LOAD_BIAS(0, bc0, bc1, bc2, bc3);
  STORE_KV(ka0, ka1, va0, va1);

  for (int jt = 0; jt < ntk; jt += 64) {
    __syncthreads();  // staged tile visible to all waves
    const bool pre = jt + 64 < ntk;
    ushort4 bn0{0,0,0,0}, bn1{0,0,0,0}, bn2{0,0,0,0}, bn3{0,0,0,0};
    if (pre) {
      LOAD_KV(jt + 64, ka0, ka1, va0, va1);  // in flight during compute
      if (bshuf) LOAD_BIAS(jt + 64, bn0, bn1, bn2, bn3);
    }

    // ---- S[16x64] = Q @ K^T ----
    f32x4 s_acc[4] = {};
#pragma unroll
    for (int j = 0; j < 4; ++j) {
      bf16x8 kf = *(const bf16x8*)&ksb[j * 16 + lr][quad * 8];
      s_acc[j] = __builtin_amdgcn_mfma_f32_16x16x32_bf16(qf0, kf, s_acc[j], 0, 0, 0);
    }
#pragma unroll
    for (int j = 0; j < 4; ++j) {
      bf16x8 kf = *(const bf16x8*)&ksb[j * 16 + lr][32 + quad * 8];
      s_acc[j] = __builtin_amdgcn_mfma_f32_16x16x32_bf16(qf1, kf, s_acc[j], 0, 0, 0);
    }

    // ---- bias + causal + static-max softmax (no cross-lane ops) ----
#pragma unroll
    for (int r = 0; r < 4; ++r) {
      const int brow = wq + quad * 4 + r;
      const int qloc = qt * 64 + brow;
      float sv0 = s_acc[0][r], sv1 = s_acc[1][r], sv2 = s_acc[2][r], sv3 = s_acc[3][r];
      if (bshuf) {
        ushort4 bw = (r == 0) ? bc0 : (r == 1) ? bc1 : (r == 2) ? bc2 : bc3;
        bf16 bb[4];
        *(ushort4*)bb = bw;
        sv0 += ldv(bb[0]); sv1 += ldv(bb[1]); sv2 += ldv(bb[2]); sv3 += ldv(bb[3]);
      }
      if (causal) {
        const int lim = qloc + 512;
        if (jt + 0 * 16 + lr > lim) sv0 = -3.0e38f;
        if (jt + 1 * 16 + lr > lim) sv1 = -3.0e38f;
        if (jt + 2 * 16 + lr > lim) sv2 = -3.0e38f;
        if (jt + 3 * 16 + lr > lim) sv3 = -3.0e38f;
      }
      const float p0 = __expf(sv0 - 12.f), p1 = __expf(sv1 - 12.f);
      const float p2 = __expf(sv2 - 12.f), p3 = __expf(sv3 - 12.f);
      l_i[r] += (p0 + p1) + (p2 + p3);
      psb[brow][0 * 16 + lr] = f2b(p0);
      psb[brow][1 * 16 + lr] = f2b(p1);
      psb[brow][2 * 16 + lr] = f2b(p2);
      psb[brow][3 * 16 + lr] = f2b(p3);
    }

    // ---- O[16x64] += P @ V (psb rows wave-private; DS in-order per wave) ----
#pragma unroll
    for (int jc = 0; jc < 2; ++jc) {
      bf16x8 pf = *(const bf16x8*)&psb[wq + lr][jc * 32 + quad * 8];
#pragma unroll
      for (int dt = 0; dt < 4; ++dt) {
        bf16x8 vf = *(const bf16x8*)&vsb[dt * 16 + lr][jc * 32 + quad * 8];
        o_acc[dt] = __builtin_amdgcn_mfma_f32_16x16x32_bf16(pf, vf, o_acc[dt], 0, 0, 0);
      }
    }

    __syncthreads();  // all waves done with ksb/vsb
    if (pre) {
      STORE_KV(ka0, ka1, va0, va1);
      if (bshuf) { bc0 = bn0; bc1 = bn1; bc2 = bn2; bc3 = bn3; }
    }
  }

  // ---- epilogue: finish the (linear) l reduction across the 16-lane group ----
#pragma unroll
  for (int r = 0; r < 4; ++r) {
#pragma unroll
    for (int mm = 1; mm < 16; mm <<= 1) l_i[r] += __shfl_xor(l_i[r], mm);
    const int qrow = qbase + wq + quad * 4 + r;
    const float invl = 1.f / l_i[r];
    bf16* orow = op + (size_t)qrow * o_rstride + o_coff + (size_t)h * o_hstride;
#pragma unroll
    for (int dt = 0; dt < 4; ++dt) orow[dt * 16 + lr] = f2b(o_acc[dt][r] * invl);
  }
}

// ---------------------------------------------------------------------------
// memories (fp32 out): out[m][h][i][d] = qkv[(3584+i)*3072 + 1024*(m+1) + h*64 + d]
// (must run BEFORE the in-place l2norm of the qkv k-part)
// ---------------------------------------------------------------------------
__global__ __launch_bounds__(256) void memcopy_kernel(const bf16* __restrict__ qkv,
                                                      float* __restrict__ out) {
  const int idx = blockIdx.x * 256 + threadIdx.x;  // 2*16*512*64 = 1048576
  const int d = idx & 63;
  const int i = (idx >> 6) & 511;
  const int h = (idx >> 15) & 15;
  const int mm = idx >> 19;
  out[idx] = ldv(qkv[(size_t)(3584 + i) * 3072 + 1024 * (mm + 1) + h * 64 + d]);
}

// ---------------------------------------------------------------------------
extern "C" void kernel_launch(void* const* d_in, const int* in_sizes, int n_in,
                              void* d_out, int out_size, void* d_ws, size_t ws_size,
                              hipStream_t stream) {
  const float* x = (const float*)d_in[0];
  const float* rel_bias = (const float*)d_in[1];
  const float* gamma = (const float*)d_in[2];
  const float* w_qkv = (const float*)d_in[3];
  const float* q_scale = (const float*)d_in[4];
  const float* k_scale = (const float*)d_in[5];
  const float* w_out = (const float*)d_in[6];
  const float* s_gamma = (const float*)d_in[7];
  const float* w_q2s = (const float*)d_in[8];
  const float* w_qfs = (const float*)d_in[9];
  const float* w_sqkv = (const float*)d_in[10];
  const float* init_state = (const float*)d_in[11];
  const float* state_pos = (const float*)d_in[12];
  const float* w_sout = (const float*)d_in[13];
  const float* ts_qs = (const float*)d_in[14];
  const float* ts_ks = (const float*)d_in[15];
  const float* ss_qs = (const float*)d_in[16];
  const float* ss_ks = (const float*)d_in[17];
  const float* fs_qs = (const float*)d_in[18];
  const float* fs_ks = (const float*)d_in[19];
  const float* w_gate = (const float*)d_in[20];
  const float* b_gate = (const float*)d_in[21];
  const float* ema_beta = (const float*)d_in[22];

  // outputs: FP32
  float* out0 = (float*)d_out;         // [4096,1024]
  float* out_mem = out0 + 4194304;     // [2,16,512,64]
  float* out_ns = out0 + 5242880;      // [512,1024]

  // workspace (bf16 intermediates), 64 MiB total
  bf16* xn = (bf16*)d_ws;          // 4096x1024 (reused: vT_loc, then wT_out/sout)
  bf16* qkv = xn + 4194304;        // 4096x3072 (q/k parts l2norm'd in place)
  bf16* q2s = qkv + 12582912;      // 4096x1024 (reused: wT_gate after attns)
  bf16* aloc = q2s + 4194304;      // 4096x1024
  bf16* ats = aloc + 4194304;      // 4096x1024
  bf16* st = ats + 4194304;        // 512x1024 (later reused as vT_s)
  bf16* sqkv = st + 524288;        // 512x3072 (q/k parts l2norm'd in place)
  bf16* qfs = sqkv + 1572864;      // 512x1024 (l2norm'd in place)
  bf16* socat = qfs + 524288;      // 512x2048
  bf16* soproj = socat + 1048576;  // 512x1024
  bf16* vT_loc = xn;               // [16*64][4096] after q2s gemm consumes xn
  bf16* vT_s = st;                 // [16*64][512]  after qfs gemm consumes st

  // out0 region (16.78MB) as bf16 scratch: early transposed weights, then bshuf
  bf16* out0b = (bf16*)out0;
  bf16* wT_qkv = out0b;                 // 3072x1024
  bf16* wT_q2s = wT_qkv + 3145728;      // 1024x1024
  bf16* wT_sqkv = wT_q2s + 1048576;     // 3072x1024
  bf16* wT_qfs = wT_sqkv + 3145728;     // 1024x1024  (exactly fills out0)
  bf16* bshuf = out0b;                  // [16][512][16][64] bf16 (after GEMMs 1-4)
  // late transposed weights into freed regions
  bf16* wT_out = xn;                    // 2048x1024 (vT_loc dead after attns)
  bf16* wT_sout = xn + 2097152;         // 2048x1024
  bf16* wT_gate = q2s;                  // 1024x1024 (q2s dead after attn 2)

  // 1. layernorms + weight transposes (wT into out0 scratch)
  ln_kernel<<<4096, 256, 0, stream>>>(x, gamma, nullptr, xn);
  ln_kernel<<<512, 256, 0, stream>>>(init_state, s_gamma, state_pos, st);
  wtrans_kernel<<<dim3(16, 48), 256, 0, stream>>>(w_qkv, 3072, wT_qkv, 1024);
  wtrans_kernel<<<dim3(16, 16), 256, 0, stream>>>(w_q2s, 1024, wT_q2s, 1024);
  wtrans_kernel<<<dim3(16, 48), 256, 0, stream>>>(w_sqkv, 3072, wT_sqkv, 1024);
  wtrans_kernel<<<dim3(16, 16), 256, 0, stream>>>(w_qfs, 1024, wT_qfs, 1024);

  // 2. projections (MFMA, bf16 transposed weights)
  mfma_gemm<bf16, bf16><<<dim3(24, 32), 256, 0, stream>>>(
      xn, 1024, nullptr, 0, 0, wT_qkv, qkv, 3072, 1024, 0, nullptr, nullptr, nullptr);
  mfma_gemm<bf16, bf16><<<dim3(8, 32), 256, 0, stream>>>(
      xn, 1024, nullptr, 0, 0, wT_q2s, q2s, 1024, 1024, 0, nullptr, nullptr, nullptr);
  mfma_gemm<float, bf16><<<dim3(24, 4), 256, 0, stream>>>(
      init_state, 1024, nullptr, 0, 0, wT_sqkv, sqkv, 3072, 1024, 0, nullptr, nullptr, nullptr);
  mfma_gemm<bf16, bf16><<<dim3(8, 4), 256, 0, stream>>>(
      st, 1024, nullptr, 0, 0, wT_qfs, qfs, 1024, 1024, 0, nullptr, nullptr, nullptr);

  // 3. memories output (raw k/v, before in-place norm)
  memcopy_kernel<<<4096, 256, 0, stream>>>(qkv, out_mem);

  // 4. V transposes (into freed xn/st regions) + bias shuffle (out0 free now)
  vtrans_kernel<<<dim3(64, 16), 256, 0, stream>>>(qkv, 3072, 2048, 4096, vT_loc);
  vtrans_kernel<<<dim3(8, 16), 256, 0, stream>>>(sqkv, 3072, 2048, 512, vT_s);
  bshuf_kernel<<<dim3(512, 16), 256, 0, stream>>>(rel_bias, bshuf);

  // 5. pre-normalize Q/K (q part carries qs*ks*8; k part plain l2norm)
  l2n_kernel<<<dim3(4096, 2), 256, 0, stream>>>(qkv, 3072, q_scale, k_scale, 8.f);
  l2n_kernel<<<dim3(512, 2), 256, 0, stream>>>(sqkv, 3072, ss_qs, ss_ks, 8.f);
  l2n_kernel<<<dim3(4096, 1), 256, 0, stream>>>(q2s, 1024, ts_qs, ts_ks, 8.f);
  l2n_kernel<<<dim3(512, 1), 256, 0, stream>>>(qfs, 1024, fs_qs, fs_ks, 8.f);

  // 6. attentions (MFMA flash v6; chunked XCD swizzle, zb fastest)
  attn_mfma<<<1024, 256, 0, stream>>>(
      qkv, 3072, qkv + 1024, 3072, vT_loc, 4096, bshuf, 1, 1024,
      512, -512, 512, 8, 8, aloc, 1024, 0, 64);
  attn_mfma<<<1024, 256, 0, stream>>>(
      q2s, 1024, sqkv + 1024, 3072, vT_s, 512, nullptr, 0, 512,
      4096, 0, 0, 64, 1, ats, 1024, 0, 64);
  attn_mfma<<<128, 256, 0, stream>>>(
      sqkv, 3072, sqkv + 1024, 3072, vT_s, 512, nullptr, 0, 512,
      512, 0, 0, 8, 1, socat, 2048, 0, 128);
  attn_mfma<<<128, 256, 0, stream>>>(
      qfs, 1024, qkv + 1024, 3072, vT_loc, 4096, nullptr, 0, 512,
      512, 3584, 0, 8, 1, socat, 2048, 64, 128);

  // 7. late weight transposes (vT_loc/q2s regions now dead)
  wtrans_kernel<<<dim3(32, 16), 256, 0, stream>>>(w_out, 1024, wT_out, 2048);
  wtrans_kernel<<<dim3(32, 16), 256, 0, stream>>>(w_sout, 1024, wT_sout, 2048);
  wtrans_kernel<<<dim3(16, 16), 256, 0, stream>>>(w_gate, 1024, wT_gate, 1024);

  // 8. out0 = [aloc | ats] @ w_out  (fp32 out; overwrites bshuf scratch)
  mfma_gemm<bf16, float><<<dim3(8, 32), 256, 0, stream>>>(
      aloc, 1024, ats, 1024, 1024, wT_out, out0, 1024, 2048, 0, nullptr, nullptr, nullptr);

  // 9. state out path (new_states fp32 out)
  mfma_gemm<bf16, bf16><<<dim3(8, 4), 256, 0, stream>>>(
      socat, 2048, nullptr, 0, 0, wT_sout, soproj, 1024, 2048, 0, nullptr, nullptr, nullptr);
  mfma_gemm<bf16, float><<<dim3(8, 4), 256, 0, stream>>>(
      soproj, 1024, nullptr, 0, 0, wT_gate, out_ns, 1024, 1024, 1, b_gate, ema_beta,
      init_state);
}

// Round 7
// 578.655 us; speedup vs baseline: 1.6829x; 1.0538x over previous
//
#include <hip/hip_runtime.h>
#include <hip/hip_bf16.h>

using bf16 = __hip_bfloat16;
using bf16x8 = __attribute__((ext_vector_type(8))) short;
using f32x4 = __attribute__((ext_vector_type(4))) float;

static __device__ __forceinline__ float ldv(bf16 v) { return __bfloat162float(v); }
static __device__ __forceinline__ float ldv(float v) { return v; }
static __device__ __forceinline__ bf16 f2b(float v) { return __float2bfloat16(v); }
static __device__ __forceinline__ void stv(bf16* p, float v) { *p = __float2bfloat16(v); }
static __device__ __forceinline__ void stv(float* p, float v) { *p = v; }

// load 8 elements (bf16 passthrough / fp32 cvt) into LDS as bf16
static __device__ __forceinline__ void load8(const bf16* p, bf16* dst) {
  *(uint4*)dst = *(const uint4*)p;
}
static __device__ __forceinline__ void load8(const float* p, bf16* dst) {
  float4 a = *(const float4*)p, b = *(const float4*)(p + 4);
  dst[0] = f2b(a.x); dst[1] = f2b(a.y); dst[2] = f2b(a.z); dst[3] = f2b(a.w);
  dst[4] = f2b(b.x); dst[5] = f2b(b.y); dst[6] = f2b(b.z); dst[7] = f2b(b.w);
}

// ---------------------------------------------------------------------------
// LayerNorm (cols = 1024 fixed). out = (x - mean)*rsqrt(var+1e-5)*gamma [+ add]
// ---------------------------------------------------------------------------
__global__ __launch_bounds__(256) void ln_kernel(
    const float* __restrict__ x, const float* __restrict__ gamma,
    const float* __restrict__ add, bf16* __restrict__ out) {
  const int row = blockIdx.x;
  const float* xr = x + (size_t)row * 1024;
  float v[4];
  float s = 0.f, ss = 0.f;
#pragma unroll
  for (int i = 0; i < 4; ++i) {
    v[i] = xr[threadIdx.x + 256 * i];
    s += v[i];
    ss += v[i] * v[i];
  }
#pragma unroll
  for (int m = 1; m < 64; m <<= 1) {
    s += __shfl_xor(s, m);
    ss += __shfl_xor(ss, m);
  }
  __shared__ float red[8];
  const int wid = threadIdx.x >> 6;
  if ((threadIdx.x & 63) == 0) { red[wid] = s; red[wid + 4] = ss; }
  __syncthreads();
  s = red[0] + red[1] + red[2] + red[3];
  ss = red[4] + red[5] + red[6] + red[7];
  const float mean = s * (1.f / 1024.f);
  const float var = ss * (1.f / 1024.f) - mean * mean;
  const float rs = rsqrtf(var + 1e-5f);
  bf16* outr = out + (size_t)row * 1024;
#pragma unroll
  for (int i = 0; i < 4; ++i) {
    int c = threadIdx.x + 256 * i;
    float y = (v[i] - mean) * rs * gamma[c];
    if (add) y += add[(size_t)row * 1024 + c];
    outr[c] = f2b(y);
  }
}

// ---------------------------------------------------------------------------
// Per-head l2norm, in place. blockIdx.y = part (0: cols 0..1023 with scales
// s1*s2*mult; 1: cols 1024..2047 plain l2norm). 16 heads x 64 d per part.
// ---------------------------------------------------------------------------
__global__ __launch_bounds__(256) void l2n_kernel(
    bf16* __restrict__ buf, int rs,
    const float* __restrict__ s1, const float* __restrict__ s2, float mult) {
  const int row = blockIdx.x, part = blockIdx.y, t = threadIdx.x;
  const int d0 = (t & 15) * 4, hoff = (t >> 4) * 64 + part * 1024;
  bf16* p = buf + (size_t)row * rs + hoff + d0;
  bf16 b[4];
  *(ushort4*)b = *(const ushort4*)p;
  float v[4], ss = 0.f;
#pragma unroll
  for (int i = 0; i < 4; ++i) { v[i] = ldv(b[i]); ss += v[i] * v[i]; }
  ss += __shfl_xor(ss, 1);
  ss += __shfl_xor(ss, 2);
  ss += __shfl_xor(ss, 4);
  ss += __shfl_xor(ss, 8);
  const float inv = (part ? 1.f : mult) / fmaxf(sqrtf(ss), 1e-12f);
#pragma unroll
  for (int i = 0; i < 4; ++i) {
    float y = v[i] * inv;
    if (!part && s1) y *= s1[d0 + i];
    if (!part && s2) y *= s2[d0 + i];
    b[i] = f2b(y);
  }
  *(ushort4*)p = *(ushort4*)b;
}

// ---------------------------------------------------------------------------
// Per-head V transpose: dst[h*64+d][n] = src[n][coff + h*64 + d].
// ---------------------------------------------------------------------------
__global__ __launch_bounds__(256) void vtrans_kernel(
    const bf16* __restrict__ src, int rstride, int coff, int nrows,
    bf16* __restrict__ dst) {
  __shared__ bf16 tile[64][72];
  const int n0 = blockIdx.x * 64, h = blockIdx.y, t = threadIdx.x;
  {
    const int nr = t >> 2, dp = (t & 3) * 16;
    const bf16* s = src + (size_t)(n0 + nr) * rstride + coff + h * 64 + dp;
    *(uint4*)&tile[nr][dp] = *(const uint4*)s;
    *(uint4*)&tile[nr][dp + 8] = *(const uint4*)(s + 8);
  }
  __syncthreads();
  {
    const int dr = t >> 2, np = (t & 3) * 16;
    bf16 tmp[16];
#pragma unroll
    for (int i = 0; i < 16; ++i) tmp[i] = tile[np + i][dr];
    bf16* d = dst + (size_t)(h * 64 + dr) * nrows + n0 + np;
    *(uint4*)d = *(uint4*)&tmp[0];
    *(uint4*)(d + 8) = *(uint4*)&tmp[8];
  }
}

// ---------------------------------------------------------------------------
// Weight transpose+cvt: dst[n][k] (bf16, row stride K) = src[k][n] (fp32).
// ---------------------------------------------------------------------------
__global__ __launch_bounds__(256) void wtrans_kernel(
    const float* __restrict__ src, int N, bf16* __restrict__ dst, int K) {
  __shared__ bf16 tile[64][72];
  const int k0 = blockIdx.x * 64, n0 = blockIdx.y * 64, t = threadIdx.x;
  {
    const int kr = t >> 2, np = (t & 3) * 16;
    const float* s = src + (size_t)(k0 + kr) * N + n0 + np;
    bf16 tmp[16];
#pragma unroll
    for (int i = 0; i < 16; ++i) tmp[i] = f2b(s[i]);
    *(uint4*)&tile[kr][np] = *(uint4*)&tmp[0];
    *(uint4*)&tile[kr][np + 8] = *(uint4*)&tmp[8];
  }
  __syncthreads();
  {
    const int nr = t >> 2, kp = (t & 3) * 16;
    bf16 tmp[16];
#pragma unroll
    for (int i = 0; i < 16; ++i) tmp[i] = tile[kp + i][nr];
    bf16* d = dst + (size_t)(n0 + nr) * K + k0 + kp;
    *(uint4*)d = *(uint4*)&tmp[0];
    *(uint4*)(d + 8) = *(uint4*)&tmp[8];
  }
}

// ---------------------------------------------------------------------------
// Bias pre-shuffle: bshuf[h][q][jt][lr*4+j] = bf16(bias[h][q][jt*64 + j*16 + lr])
// ---------------------------------------------------------------------------
__global__ __launch_bounds__(256) void bshuf_kernel(const float* __restrict__ bias,
                                                    bf16* __restrict__ out) {
  const int q = blockIdx.x, h = blockIdx.y, t = threadIdx.x;
  const int jt = t >> 4, lr = t & 15;
  const float* src = bias + ((size_t)h * 512 + q) * 1024 + jt * 64 + lr;
  bf16 b[4];
#pragma unroll
  for (int j = 0; j < 4; ++j) b[j] = f2b(src[j * 16]);
  *(ushort4*)(out + (((size_t)h * 512 + q) * 16 + jt) * 64 + lr * 4) = *(ushort4*)b;
}

// ---------------------------------------------------------------------------
// MFMA GEMM v2  C[M,N] = Acat[M,K] @ Bt^T   (Bt: bf16 [N][K], row stride K)
// BK=64 (32 MFMA between barriers, half the barrier count of v1).
// 1D grid + chunked XCD swizzle: hardware id%8 = XCD; chunk c owns a cw x ch
// 2D sub-grid of (bn,bm) tiles -> A/B panels stay in one XCD's L2 (T1).
// K % 64 == 0. cw==0 disables the swizzle (tiny grids).
// ---------------------------------------------------------------------------
template <typename TA, typename TC>
__global__ __launch_bounds__(256) void mfma_gemm(
    int nx, int cw, int ch,
    const TA* __restrict__ A, int lda,
    const TA* __restrict__ A2, int lda2, int K1,
    const bf16* __restrict__ Bt,
    TC* __restrict__ C, int ldc, int K,
    int epilogue,
    const float* __restrict__ b_gate, const float* __restrict__ ema_beta,
    const float* __restrict__ init_state) {
  __shared__ bf16 Asb[128][72];  // [m][k], pad 64->72
  __shared__ bf16 Bsb[128][72];  // [n][k], pad 64->72
  int bxi, byi;
  if (cw) {
    const int c = blockIdx.x & 7, r = blockIdx.x >> 3;
    const int nchx = nx / cw;
    bxi = (c % nchx) * cw + r % cw;
    byi = (c / nchx) * ch + r / cw;
  } else {
    bxi = blockIdx.x % nx;
    byi = blockIdx.x / nx;
  }
  const int bm = byi * 128, bn = bxi * 128;
  const int tid = threadIdx.x;
  const int w = tid >> 6, lane = tid & 63;
  const int wm = (w >> 1) * 64, wn = (w & 1) * 64;
  const int lr = lane & 15, quad = lane >> 4, ko = quad * 8;
  const int sn = tid >> 1, skh = (tid & 1) * 32;  // B staging map

  f32x4 acc[4][4] = {};

  for (int kt = 0; kt < K; kt += 64) {
    // ---- stage A (4 chunks of 8 per thread) ----
#pragma unroll
    for (int c = 0; c < 4; ++c) {
      const int q = tid + 256 * c;
      const int m = q >> 3, kk = (q & 7) * 8;
      const int gk = kt + kk;
      const TA* ap = (A2 && gk >= K1)
                         ? (A2 + (size_t)(bm + m) * lda2 + (gk - K1))
                         : (A + (size_t)(bm + m) * lda + gk);
      load8(ap, &Asb[m][kk]);
    }
    // ---- stage B: 64B vector copy per thread ----
    {
      const bf16* bp = Bt + (size_t)(bn + sn) * K + kt + skh;
      *(uint4*)&Bsb[sn][skh] = *(const uint4*)bp;
      *(uint4*)&Bsb[sn][skh + 8] = *(const uint4*)(bp + 8);
      *(uint4*)&Bsb[sn][skh + 16] = *(const uint4*)(bp + 16);
      *(uint4*)&Bsb[sn][skh + 24] = *(const uint4*)(bp + 24);
    }
    __syncthreads();

#pragma unroll
    for (int dc = 0; dc < 2; ++dc) {
      bf16x8 af[4], bfr[4];
#pragma unroll
      for (int i = 0; i < 4; ++i)
        af[i] = *(const bf16x8*)&Asb[wm + i * 16 + lr][dc * 32 + ko];
#pragma unroll
      for (int j = 0; j < 4; ++j)
        bfr[j] = *(const bf16x8*)&Bsb[wn + j * 16 + lr][dc * 32 + ko];
#pragma unroll
      for (int i = 0; i < 4; ++i)
#pragma unroll
        for (int j = 0; j < 4; ++j)
          acc[i][j] = __builtin_amdgcn_mfma_f32_16x16x32_bf16(af[i], bfr[j],
                                                              acc[i][j], 0, 0, 0);
    }
    __syncthreads();
  }

#pragma unroll
  for (int i = 0; i < 4; ++i) {
#pragma unroll
    for (int j = 0; j < 4; ++j) {
#pragma unroll
      for (int r = 0; r < 4; ++r) {
        const int row = bm + wm + i * 16 + quad * 4 + r;
        const int col = bn + wn + j * 16 + lr;
        float v = acc[i][j][r];
        if (epilogue == 1) {
          float z = v + b_gate[col];
          float d = 1.f / (1.f + __expf(-ema_beta[col]));
          v = d * z + (1.f - d) * init_state[(size_t)row * 1024 + col];
        }
        stv(&C[(size_t)row * ldc + col], v);
      }
    }
  }
}

// ---------------------------------------------------------------------------
// MFMA flash attention v6 (unchanged from R6): static-max softmax, chunked
// XCD swizzle, 1-tile-ahead prefetch, straight-line named-register staging.
// ---------------------------------------------------------------------------
#define LOAD_KV(JT, K0, K1, V0, V1)                                        \
  {                                                                        \
    const int krow_ = kbase + (JT) + kr;                                   \
    if (krow_ >= 0) {                                                      \
      const bf16* s_ = kp + (size_t)krow_ * k_rstride + h * 64 + kc;       \
      K0 = *(const uint4*)s_;                                              \
      K1 = *(const uint4*)(s_ + 8);                                        \
    } else { K0 = z4; K1 = z4; }                                           \
    const int col_ = kbase + (JT) + kc;                                    \
    if (col_ >= 0) {                                                       \
      const bf16* s_ = vtp + (size_t)(h * 64 + kr) * v_nstride + col_;     \
      V0 = *(const uint4*)s_;                                              \
      V1 = *(const uint4*)(s_ + 8);                                        \
    } else { V0 = z4; V1 = z4; }                                           \
  }

#define STORE_KV(K0, K1, V0, V1)          \
  {                                       \
    *(uint4*)&ksb[kr][kc] = K0;           \
    *(uint4*)&ksb[kr][kc + 8] = K1;       \
    *(uint4*)&vsb[kr][kc] = V0;           \
    *(uint4*)&vsb[kr][kc + 8] = V1;       \
  }

#define LOAD_BIAS(JT, B0, B1, B2, B3)                                      \
  {                                                                        \
    const bf16* bp_ = bshuf + (((size_t)h * 512 + qt * 64 + wq +           \
                                quad * 4) * 16 + ((JT) >> 6)) * 64 + lr * 4; \
    B0 = *(const ushort4*)bp_;                                             \
    B1 = *(const ushort4*)(bp_ + 1024);                                    \
    B2 = *(const ushort4*)(bp_ + 2048);                                    \
    B3 = *(const ushort4*)(bp_ + 3072);                                    \
  }

__global__ __launch_bounds__(256, 4) void attn_mfma(
    const bf16* __restrict__ qp, int q_rstride,
    const bf16* __restrict__ kp, int k_rstride,
    const bf16* __restrict__ vtp, int v_nstride,
    const bf16* __restrict__ bshuf, int causal, int nkeys,
    int qrows_per_blk, int kbase0, int krows_per_blk, int nqt, int nzb,
    bf16* __restrict__ op, int o_rstride, int o_coff, int o_hstride) {
  __shared__ __align__(16) bf16 ksb[64][72];  // [krow][d]
  __shared__ __align__(16) bf16 vsb[64][72];  // [d][krow]
  __shared__ __align__(16) bf16 psb[64][72];  // [qrow][kcol]
  const int Bp = (blockIdx.x & 7) * ((int)gridDim.x >> 3) + (blockIdx.x >> 3);
  const int zb = Bp % nzb;
  const int qt = (Bp / nzb) % nqt;
  const int h = Bp / (nzb * nqt);
  const int tid = threadIdx.x;
  const int w = tid >> 6, lane = tid & 63;
  const int lr = lane & 15, quad = lane >> 4;
  const int wq = w * 16;
  const int qbase = zb * qrows_per_blk + qt * 64;

  bf16x8 qf0, qf1;
  {
    const bf16* qr = qp + (size_t)(qbase + wq + lr) * q_rstride + h * 64 + quad * 8;
    qf0 = *(const bf16x8*)qr;
    qf1 = *(const bf16x8*)(qr + 32);
  }

  float l_i[4] = {0.f, 0.f, 0.f, 0.f};
  f32x4 o_acc[4] = {};

  const int kbase = kbase0 + zb * krows_per_blk;
  const int ntk = causal ? min(nkeys, qt * 64 + 64 + 512) : nkeys;
  const int kr = tid >> 2, kc = (tid & 3) * 16;

  const uint4 z4{0, 0, 0, 0};
  uint4 ka0, ka1, va0, va1;
  ushort4 bc0{0,0,0,0}, bc1{0,0,0,0}, bc2{0,0,0,0}, bc3{0,0,0,0};

  LOAD_KV(0, ka0, ka1, va0, va1);
  if (bshuf) LOAD_BIAS(0, bc0, bc1, bc2, bc3);
  STORE_KV(ka0, ka1, va0, va1);

  for (int jt = 0; jt < ntk; jt += 64) {
    __syncthreads();
    const bool pre = jt + 64 < ntk;
    ushort4 bn0{0,0,0,0}, bn1{0,0,0,0}, bn2{0,0,0,0}, bn3{0,0,0,0};
    if (pre) {
      LOAD_KV(jt + 64, ka0, ka1, va0, va1);
      if (bshuf) LOAD_BIAS(jt + 64, bn0, bn1, bn2, bn3);
    }

    // ---- S[16x64] = Q @ K^T ----
    f32x4 s_acc[4] = {};
#pragma unroll
    for (int j = 0; j < 4; ++j) {
      bf16x8 kf = *(const bf16x8*)&ksb[j * 16 + lr][quad * 8];
      s_acc[j] = __builtin_amdgcn_mfma_f32_16x16x32_bf16(qf0, kf, s_acc[j], 0, 0, 0);
    }
#pragma unroll
    for (int j = 0; j < 4; ++j) {
      bf16x8 kf = *(const bf16x8*)&ksb[j * 16 + lr][32 + quad * 8];
      s_acc[j] = __builtin_amdgcn_mfma_f32_16x16x32_bf16(qf1, kf, s_acc[j], 0, 0, 0);
    }

    // ---- bias + causal + static-max softmax (no cross-lane ops) ----
#pragma unroll
    for (int r = 0; r < 4; ++r) {
      const int brow = wq + quad * 4 + r;
      const int qloc = qt * 64 + brow;
      float sv0 = s_acc[0][r], sv1 = s_acc[1][r], sv2 = s_acc[2][r], sv3 = s_acc[3][r];
      if (bshuf) {
        ushort4 bw = (r == 0) ? bc0 : (r == 1) ? bc1 : (r == 2) ? bc2 : bc3;
        bf16 bb[4];
        *(ushort4*)bb = bw;
        sv0 += ldv(bb[0]); sv1 += ldv(bb[1]); sv2 += ldv(bb[2]); sv3 += ldv(bb[3]);
      }
      if (causal) {
        const int lim = qloc + 512;
        if (jt + 0 * 16 + lr > lim) sv0 = -3.0e38f;
        if (jt + 1 * 16 + lr > lim) sv1 = -3.0e38f;
        if (jt + 2 * 16 + lr > lim) sv2 = -3.0e38f;
        if (jt + 3 * 16 + lr > lim) sv3 = -3.0e38f;
      }
      const float p0 = __expf(sv0 - 12.f), p1 = __expf(sv1 - 12.f);
      const float p2 = __expf(sv2 - 12.f), p3 = __expf(sv3 - 12.f);
      l_i[r] += (p0 + p1) + (p2 + p3);
      psb[brow][0 * 16 + lr] = f2b(p0);
      psb[brow][1 * 16 + lr] = f2b(p1);
      psb[brow][2 * 16 + lr] = f2b(p2);
      psb[brow][3 * 16 + lr] = f2b(p3);
    }

    // ---- O[16x64] += P @ V ----
#pragma unroll
    for (int jc = 0; jc < 2; ++jc) {
      bf16x8 pf = *(const bf16x8*)&psb[wq + lr][jc * 32 + quad * 8];
#pragma unroll
      for (int dt = 0; dt < 4; ++dt) {
        bf16x8 vf = *(const bf16x8*)&vsb[dt * 16 + lr][jc * 32 + quad * 8];
        o_acc[dt] = __builtin_amdgcn_mfma_f32_16x16x32_bf16(pf, vf, o_acc[dt], 0, 0, 0);
      }
    }

    __syncthreads();
    if (pre) {
      STORE_KV(ka0, ka1, va0, va1);
      if (bshuf) { bc0 = bn0; bc1 = bn1; bc2 = bn2; bc3 = bn3; }
    }
  }

  // ---- epilogue ----
#pragma unroll
  for (int r = 0; r < 4; ++r) {
#pragma unroll
    for (int mm = 1; mm < 16; mm <<= 1) l_i[r] += __shfl_xor(l_i[r], mm);
    const int qrow = qbase + wq + quad * 4 + r;
    const float invl = 1.f / l_i[r];
    bf16* orow = op + (size_t)qrow * o_rstride + o_coff + (size_t)h * o_hstride;
#pragma unroll
    for (int dt = 0; dt < 4; ++dt) orow[dt * 16 + lr] = f2b(o_acc[dt][r] * invl);
  }
}

// ---------------------------------------------------------------------------
// memories (fp32 out): out[m][h][i][d] = qkv[(3584+i)*3072 + 1024*(m+1) + h*64 + d]
// (must run BEFORE the in-place l2norm of the qkv k-part)
// ---------------------------------------------------------------------------
__global__ __launch_bounds__(256) void memcopy_kernel(const bf16* __restrict__ qkv,
                                                      float* __restrict__ out) {
  const int idx = blockIdx.x * 256 + threadIdx.x;  // 2*16*512*64 = 1048576
  const int d = idx & 63;
  const int i = (idx >> 6) & 511;
  const int h = (idx >> 15) & 15;
  const int mm = idx >> 19;
  out[idx] = ldv(qkv[(size_t)(3584 + i) * 3072 + 1024 * (mm + 1) + h * 64 + d]);
}

// ---------------------------------------------------------------------------
extern "C" void kernel_launch(void* const* d_in, const int* in_sizes, int n_in,
                              void* d_out, int out_size, void* d_ws, size_t ws_size,
                              hipStream_t stream) {
  const float* x = (const float*)d_in[0];
  const float* rel_bias = (const float*)d_in[1];
  const float* gamma = (const float*)d_in[2];
  const float* w_qkv = (const float*)d_in[3];
  const float* q_scale = (const float*)d_in[4];
  const float* k_scale = (const float*)d_in[5];
  const float* w_out = (const float*)d_in[6];
  const float* s_gamma = (const float*)d_in[7];
  const float* w_q2s = (const float*)d_in[8];
  const float* w_qfs = (const float*)d_in[9];
  const float* w_sqkv = (const float*)d_in[10];
  const float* init_state = (const float*)d_in[11];
  const float* state_pos = (const float*)d_in[12];
  const float* w_sout = (const float*)d_in[13];
  const float* ts_qs = (const float*)d_in[14];
  const float* ts_ks = (const float*)d_in[15];
  const float* ss_qs = (const float*)d_in[16];
  const float* ss_ks = (const float*)d_in[17];
  const float* fs_qs = (const float*)d_in[18];
  const float* fs_ks = (const float*)d_in[19];
  const float* w_gate = (const float*)d_in[20];
  const float* b_gate = (const float*)d_in[21];
  const float* ema_beta = (const float*)d_in[22];

  // outputs: FP32
  float* out0 = (float*)d_out;         // [4096,1024]
  float* out_mem = out0 + 4194304;     // [2,16,512,64]
  float* out_ns = out0 + 5242880;      // [512,1024]

  // workspace (bf16 intermediates), 64 MiB total
  bf16* xn = (bf16*)d_ws;          // 4096x1024 (reused: vT_loc, then wT_out/sout)
  bf16* qkv = xn + 4194304;        // 4096x3072 (q/k parts l2norm'd in place)
  bf16* q2s = qkv + 12582912;      // 4096x1024 (reused: wT_gate after attns)
  bf16* aloc = q2s + 4194304;      // 4096x1024
  bf16* ats = aloc + 4194304;      // 4096x1024
  bf16* st = ats + 4194304;        // 512x1024 (later reused as vT_s)
  bf16* sqkv = st + 524288;        // 512x3072 (q/k parts l2norm'd in place)
  bf16* qfs = sqkv + 1572864;      // 512x1024 (l2norm'd in place)
  bf16* socat = qfs + 524288;      // 512x2048
  bf16* soproj = socat + 1048576;  // 512x1024
  bf16* vT_loc = xn;               // [16*64][4096] after q2s gemm consumes xn
  bf16* vT_s = st;                 // [16*64][512]  after qfs gemm consumes st

  // out0 region (16.78MB) as bf16 scratch: early transposed weights, then bshuf
  bf16* out0b = (bf16*)out0;
  bf16* wT_qkv = out0b;                 // 3072x1024
  bf16* wT_q2s = wT_qkv + 3145728;      // 1024x1024
  bf16* wT_sqkv = wT_q2s + 1048576;     // 3072x1024
  bf16* wT_qfs = wT_sqkv + 3145728;     // 1024x1024  (exactly fills out0)
  bf16* bshuf = out0b;                  // [16][512][16][64] bf16 (after GEMMs 1-4)
  // late transposed weights into freed regions
  bf16* wT_out = xn;                    // 2048x1024 (vT_loc dead after attns)
  bf16* wT_sout = xn + 2097152;         // 2048x1024
  bf16* wT_gate = q2s;                  // 1024x1024 (q2s dead after attn 2)

  // 1. layernorms + weight transposes (wT into out0 scratch)
  ln_kernel<<<4096, 256, 0, stream>>>(x, gamma, nullptr, xn);
  ln_kernel<<<512, 256, 0, stream>>>(init_state, s_gamma, state_pos, st);
  wtrans_kernel<<<dim3(16, 48), 256, 0, stream>>>(w_qkv, 3072, wT_qkv, 1024);
  wtrans_kernel<<<dim3(16, 16), 256, 0, stream>>>(w_q2s, 1024, wT_q2s, 1024);
  wtrans_kernel<<<dim3(16, 48), 256, 0, stream>>>(w_sqkv, 3072, wT_sqkv, 1024);
  wtrans_kernel<<<dim3(16, 16), 256, 0, stream>>>(w_qfs, 1024, wT_qfs, 1024);

  // 2. projections (MFMA v2: BK=64, chunked XCD swizzle on the big grids)
  mfma_gemm<bf16, bf16><<<768, 256, 0, stream>>>(
      24, 12, 8, xn, 1024, nullptr, 0, 0, wT_qkv, qkv, 3072, 1024, 0,
      nullptr, nullptr, nullptr);
  mfma_gemm<bf16, bf16><<<256, 256, 0, stream>>>(
      8, 8, 4, xn, 1024, nullptr, 0, 0, wT_q2s, q2s, 1024, 1024, 0,
      nullptr, nullptr, nullptr);
  mfma_gemm<float, bf16><<<96, 256, 0, stream>>>(
      24, 0, 0, init_state, 1024, nullptr, 0, 0, wT_sqkv, sqkv, 3072, 1024, 0,
      nullptr, nullptr, nullptr);
  mfma_gemm<bf16, bf16><<<32, 256, 0, stream>>>(
      8, 0, 0, st, 1024, nullptr, 0, 0, wT_qfs, qfs, 1024, 1024, 0,
      nullptr, nullptr, nullptr);

  // 3. memories output (raw k/v, before in-place norm)
  memcopy_kernel<<<4096, 256, 0, stream>>>(qkv, out_mem);

  // 4. V transposes (into freed xn/st regions) + bias shuffle (out0 free now)
  vtrans_kernel<<<dim3(64, 16), 256, 0, stream>>>(qkv, 3072, 2048, 4096, vT_loc);
  vtrans_kernel<<<dim3(8, 16), 256, 0, stream>>>(sqkv, 3072, 2048, 512, vT_s);
  bshuf_kernel<<<dim3(512, 16), 256, 0, stream>>>(rel_bias, bshuf);

  // 5. pre-normalize Q/K (q part carries qs*ks*8; k part plain l2norm)
  l2n_kernel<<<dim3(4096, 2), 256, 0, stream>>>(qkv, 3072, q_scale, k_scale, 8.f);
  l2n_kernel<<<dim3(512, 2), 256, 0, stream>>>(sqkv, 3072, ss_qs, ss_ks, 8.f);
  l2n_kernel<<<dim3(4096, 1), 256, 0, stream>>>(q2s, 1024, ts_qs, ts_ks, 8.f);
  l2n_kernel<<<dim3(512, 1), 256, 0, stream>>>(qfs, 1024, fs_qs, fs_ks, 8.f);

  // 6. attentions (MFMA flash v6; chunked XCD swizzle, zb fastest)
  attn_mfma<<<1024, 256, 0, stream>>>(
      qkv, 3072, qkv + 1024, 3072, vT_loc, 4096, bshuf, 1, 1024,
      512, -512, 512, 8, 8, aloc, 1024, 0, 64);
  attn_mfma<<<1024, 256, 0, stream>>>(
      q2s, 1024, sqkv + 1024, 3072, vT_s, 512, nullptr, 0, 512,
      4096, 0, 0, 64, 1, ats, 1024, 0, 64);
  attn_mfma<<<128, 256, 0, stream>>>(
      sqkv, 3072, sqkv + 1024, 3072, vT_s, 512, nullptr, 0, 512,
      512, 0, 0, 8, 1, socat, 2048, 0, 128);
  attn_mfma<<<128, 256, 0, stream>>>(
      qfs, 1024, qkv + 1024, 3072, vT_loc, 4096, nullptr, 0, 512,
      512, 3584, 0, 8, 1, socat, 2048, 64, 128);

  // 7. late weight transposes (vT_loc/q2s regions now dead)
  wtrans_kernel<<<dim3(32, 16), 256, 0, stream>>>(w_out, 1024, wT_out, 2048);
  wtrans_kernel<<<dim3(32, 16), 256, 0, stream>>>(w_sout, 1024, wT_sout, 2048);
  wtrans_kernel<<<dim3(16, 16), 256, 0, stream>>>(w_gate, 1024, wT_gate, 1024);

  // 8. out0 = [aloc | ats] @ w_out  (fp32 out; overwrites bshuf scratch)
  mfma_gemm<bf16, float><<<256, 256, 0, stream>>>(
      8, 8, 4, aloc, 1024, ats, 1024, 1024, wT_out, out0, 1024, 2048, 0,
      nullptr, nullptr, nullptr);

  // 9. state out path (new_states fp32 out)
  mfma_gemm<bf16, bf16><<<32, 256, 0, stream>>>(
      8, 0, 0, socat, 2048, nullptr, 0, 0, wT_sout, soproj, 1024, 2048, 0,
      nullptr, nullptr, nullptr);
  mfma_gemm<bf16, float><<<32, 256, 0, stream>>>(
      8, 0, 0, soproj, 1024, nullptr, 0, 0, wT_gate, out_ns, 1024, 1024, 1,
      b_gate, ema_beta, init_state);
}

// Round 8
// 564.253 us; speedup vs baseline: 1.7259x; 1.0255x over previous
//
#include <hip/hip_runtime.h>
#include <hip/hip_bf16.h>

using bf16 = __hip_bfloat16;
using bf16x8 = __attribute__((ext_vector_type(8))) short;
using f32x4 = __attribute__((ext_vector_type(4))) float;

static __device__ __forceinline__ float ldv(bf16 v) { return __bfloat162float(v); }
static __device__ __forceinline__ float ldv(float v) { return v; }
static __device__ __forceinline__ bf16 f2b(float v) { return __float2bfloat16(v); }
static __device__ __forceinline__ void stv(bf16* p, float v) { *p = __float2bfloat16(v); }
static __device__ __forceinline__ void stv(float* p, float v) { *p = v; }

// async global->LDS 16B copy: lds dest = wave-uniform base + lane*16 (HW)
static __device__ __forceinline__ void gload_lds16(const bf16* g, bf16* l) {
  __builtin_amdgcn_global_load_lds(
      (const __attribute__((address_space(1))) unsigned int*)g,
      (__attribute__((address_space(3))) unsigned int*)l, 16, 0, 0);
}

// ---------------------------------------------------------------------------
// LayerNorm (cols = 1024 fixed). out = (x - mean)*rsqrt(var+1e-5)*gamma [+ add]
// ---------------------------------------------------------------------------
__global__ __launch_bounds__(256) void ln_kernel(
    const float* __restrict__ x, const float* __restrict__ gamma,
    const float* __restrict__ add, bf16* __restrict__ out) {
  const int row = blockIdx.x;
  const float* xr = x + (size_t)row * 1024;
  float v[4];
  float s = 0.f, ss = 0.f;
#pragma unroll
  for (int i = 0; i < 4; ++i) {
    v[i] = xr[threadIdx.x + 256 * i];
    s += v[i];
    ss += v[i] * v[i];
  }
#pragma unroll
  for (int m = 1; m < 64; m <<= 1) {
    s += __shfl_xor(s, m);
    ss += __shfl_xor(ss, m);
  }
  __shared__ float red[8];
  const int wid = threadIdx.x >> 6;
  if ((threadIdx.x & 63) == 0) { red[wid] = s; red[wid + 4] = ss; }
  __syncthreads();
  s = red[0] + red[1] + red[2] + red[3];
  ss = red[4] + red[5] + red[6] + red[7];
  const float mean = s * (1.f / 1024.f);
  const float var = ss * (1.f / 1024.f) - mean * mean;
  const float rs = rsqrtf(var + 1e-5f);
  bf16* outr = out + (size_t)row * 1024;
#pragma unroll
  for (int i = 0; i < 4; ++i) {
    int c = threadIdx.x + 256 * i;
    float y = (v[i] - mean) * rs * gamma[c];
    if (add) y += add[(size_t)row * 1024 + c];
    outr[c] = f2b(y);
  }
}

// ---------------------------------------------------------------------------
// fp32 -> bf16 elementwise convert (8 elems/thread)
// ---------------------------------------------------------------------------
__global__ __launch_bounds__(256) void cvt_kernel(const float* __restrict__ in,
                                                  bf16* __restrict__ out) {
  const int i = (blockIdx.x * 256 + threadIdx.x) * 8;
  float4 a = *(const float4*)(in + i), b = *(const float4*)(in + i + 4);
  bf16 t[8];
  t[0] = f2b(a.x); t[1] = f2b(a.y); t[2] = f2b(a.z); t[3] = f2b(a.w);
  t[4] = f2b(b.x); t[5] = f2b(b.y); t[6] = f2b(b.z); t[7] = f2b(b.w);
  *(uint4*)(out + i) = *(uint4*)t;
}

// ---------------------------------------------------------------------------
// Per-head l2norm, in place. blockIdx.y = part (0: cols 0..1023 with scales
// s1*s2*mult; 1: cols 1024..2047 plain l2norm). 16 heads x 64 d per part.
// ---------------------------------------------------------------------------
__global__ __launch_bounds__(256) void l2n_kernel(
    bf16* __restrict__ buf, int rs,
    const float* __restrict__ s1, const float* __restrict__ s2, float mult) {
  const int row = blockIdx.x, part = blockIdx.y, t = threadIdx.x;
  const int d0 = (t & 15) * 4, hoff = (t >> 4) * 64 + part * 1024;
  bf16* p = buf + (size_t)row * rs + hoff + d0;
  bf16 b[4];
  *(ushort4*)b = *(const ushort4*)p;
  float v[4], ss = 0.f;
#pragma unroll
  for (int i = 0; i < 4; ++i) { v[i] = ldv(b[i]); ss += v[i] * v[i]; }
  ss += __shfl_xor(ss, 1);
  ss += __shfl_xor(ss, 2);
  ss += __shfl_xor(ss, 4);
  ss += __shfl_xor(ss, 8);
  const float inv = (part ? 1.f : mult) / fmaxf(sqrtf(ss), 1e-12f);
#pragma unroll
  for (int i = 0; i < 4; ++i) {
    float y = v[i] * inv;
    if (!part && s1) y *= s1[d0 + i];
    if (!part && s2) y *= s2[d0 + i];
    b[i] = f2b(y);
  }
  *(ushort4*)p = *(ushort4*)b;
}

// ---------------------------------------------------------------------------
// Per-head V transpose: dst[h*64+d][n] = src[n][coff + h*64 + d].
// ---------------------------------------------------------------------------
__global__ __launch_bounds__(256) void vtrans_kernel(
    const bf16* __restrict__ src, int rstride, int coff, int nrows,
    bf16* __restrict__ dst) {
  __shared__ bf16 tile[64][72];
  const int n0 = blockIdx.x * 64, h = blockIdx.y, t = threadIdx.x;
  {
    const int nr = t >> 2, dp = (t & 3) * 16;
    const bf16* s = src + (size_t)(n0 + nr) * rstride + coff + h * 64 + dp;
    *(uint4*)&tile[nr][dp] = *(const uint4*)s;
    *(uint4*)&tile[nr][dp + 8] = *(const uint4*)(s + 8);
  }
  __syncthreads();
  {
    const int dr = t >> 2, np = (t & 3) * 16;
    bf16 tmp[16];
#pragma unroll
    for (int i = 0; i < 16; ++i) tmp[i] = tile[np + i][dr];
    bf16* d = dst + (size_t)(h * 64 + dr) * nrows + n0 + np;
    *(uint4*)d = *(uint4*)&tmp[0];
    *(uint4*)(d + 8) = *(uint4*)&tmp[8];
  }
}

// ---------------------------------------------------------------------------
// Weight transpose+cvt: dst[n][k] (bf16, row stride K) = src[k][n] (fp32).
// ---------------------------------------------------------------------------
__global__ __launch_bounds__(256) void wtrans_kernel(
    const float* __restrict__ src, int N, bf16* __restrict__ dst, int K) {
  __shared__ bf16 tile[64][72];
  const int k0 = blockIdx.x * 64, n0 = blockIdx.y * 64, t = threadIdx.x;
  {
    const int kr = t >> 2, np = (t & 3) * 16;
    const float* s = src + (size_t)(k0 + kr) * N + n0 + np;
    bf16 tmp[16];
#pragma unroll
    for (int i = 0; i < 16; ++i) tmp[i] = f2b(s[i]);
    *(uint4*)&tile[kr][np] = *(uint4*)&tmp[0];
    *(uint4*)&tile[kr][np + 8] = *(uint4*)&tmp[8];
  }
  __syncthreads();
  {
    const int nr = t >> 2, kp = (t & 3) * 16;
    bf16 tmp[16];
#pragma unroll
    for (int i = 0; i < 16; ++i) tmp[i] = tile[kp + i][nr];
    bf16* d = dst + (size_t)(n0 + nr) * K + k0 + kp;
    *(uint4*)d = *(uint4*)&tmp[0];
    *(uint4*)(d + 8) = *(uint4*)&tmp[8];
  }
}

// ---------------------------------------------------------------------------
// Bias pre-shuffle: bshuf[h][q][jt][lr*4+j] = bf16(bias[h][q][jt*64 + j*16 + lr])
// ---------------------------------------------------------------------------
__global__ __launch_bounds__(256) void bshuf_kernel(const float* __restrict__ bias,
                                                    bf16* __restrict__ out) {
  const int q = blockIdx.x, h = blockIdx.y, t = threadIdx.x;
  const int jt = t >> 4, lr = t & 15;
  const float* src = bias + ((size_t)h * 512 + q) * 1024 + jt * 64 + lr;
  bf16 b[4];
#pragma unroll
  for (int j = 0; j < 4; ++j) b[j] = f2b(src[j * 16]);
  *(ushort4*)(out + (((size_t)h * 512 + q) * 16 + jt) * 64 + lr * 4) = *(ushort4*)b;
}

// ---------------------------------------------------------------------------
// MFMA GEMM v3  C[M,N] = Acat[M,K] @ Bt^T   (A, A2, Bt all bf16; Bt [N][K])
// BK=64. Staging via global_load_lds width=16 (no VGPR round trip).
// LDS tiles are LINEAR [128][64] (gload_lds writes base+lane*16); the 16-way
// read conflict of a 128B-row layout is fixed by the XOR-chunk swizzle applied
// to BOTH the global source (inverse perm) and the ds_read address (rule #21):
//   storage chunk of logical (row, ck) is ck ^ (row&7)  (16B chunks, 8/row)
//   staging: lane loads global chunk (lane&7)^(lane>>3) -> linear slot lane
//   read:    fragment chunk (dc*4+quad) ^ (lr&7)        -> 2-way conflict=free
// 1D grid + chunked XCD swizzle (cw x ch chunk per XCD; cw==0 disables).
// ---------------------------------------------------------------------------
template <typename TC>
__global__ __launch_bounds__(256) void mfma_gemm(
    int nx, int cw, int ch,
    const bf16* __restrict__ A, int lda,
    const bf16* __restrict__ A2, int lda2, int K1,
    const bf16* __restrict__ Bt,
    TC* __restrict__ C, int ldc, int K,
    int epilogue,
    const float* __restrict__ b_gate, const float* __restrict__ ema_beta,
    const float* __restrict__ init_state) {
  __shared__ bf16 Asb[128][64];
  __shared__ bf16 Bsb[128][64];
  int bxi, byi;
  if (cw) {
    const int c = blockIdx.x & 7, r = blockIdx.x >> 3;
    const int nchx = nx / cw;
    bxi = (c % nchx) * cw + r % cw;
    byi = (c / nchx) * ch + r / cw;
  } else {
    bxi = blockIdx.x % nx;
    byi = blockIdx.x / nx;
  }
  const int bm = byi * 128, bn = bxi * 128;
  const int tid = threadIdx.x;
  const int w = tid >> 6, lane = tid & 63;
  const int wm = (w >> 1) * 64, wn = (w & 1) * 64;
  const int lr = lane & 15, quad = lane >> 4;
  // staging geometry: issue c covers rows (w*4+c)*8 + (lane>>3), lane's 16B
  // chunk is linear slot lane&7; global source chunk = (lane&7)^(lane>>3).
  const int srow = (lane >> 3);              // + (w*4+c)*8
  const int sck = ((lane & 7) ^ (lane >> 3)) * 8;  // source k-offset (elems)

  f32x4 acc[4][4] = {};

  for (int kt = 0; kt < K; kt += 64) {
#pragma unroll
    for (int c = 0; c < 4; ++c) {
      const int m = (w * 4 + c) * 8 + srow;
      const int gk = kt + sck;
      const bf16* ap = (A2 && gk >= K1)
                           ? (A2 + (size_t)(bm + m) * lda2 + (gk - K1))
                           : (A + (size_t)(bm + m) * lda + gk);
      gload_lds16(ap, &Asb[0][0] + (w * 4 + c) * 512);
    }
#pragma unroll
    for (int c = 0; c < 4; ++c) {
      const int n = (w * 4 + c) * 8 + srow;
      gload_lds16(Bt + (size_t)(bn + n) * K + kt + sck,
                  &Bsb[0][0] + (w * 4 + c) * 512);
    }
    __syncthreads();

#pragma unroll
    for (int dc = 0; dc < 2; ++dc) {
      const int csw = (((dc * 4 + quad) ^ (lr & 7))) * 8;  // swizzled chunk
      bf16x8 af[4], bfr[4];
#pragma unroll
      for (int i = 0; i < 4; ++i)
        af[i] = *(const bf16x8*)&Asb[wm + i * 16 + lr][csw];
#pragma unroll
      for (int j = 0; j < 4; ++j)
        bfr[j] = *(const bf16x8*)&Bsb[wn + j * 16 + lr][csw];
#pragma unroll
      for (int i = 0; i < 4; ++i)
#pragma unroll
        for (int j = 0; j < 4; ++j)
          acc[i][j] = __builtin_amdgcn_mfma_f32_16x16x32_bf16(af[i], bfr[j],
                                                              acc[i][j], 0, 0, 0);
    }
    __syncthreads();
  }

#pragma unroll
  for (int i = 0; i < 4; ++i) {
#pragma unroll
    for (int j = 0; j < 4; ++j) {
#pragma unroll
      for (int r = 0; r < 4; ++r) {
        const int row = bm + wm + i * 16 + quad * 4 + r;
        const int col = bn + wn + j * 16 + lr;
        float v = acc[i][j][r];
        if (epilogue == 1) {
          float z = v + b_gate[col];
          float d = 1.f / (1.f + __expf(-ema_beta[col]));
          v = d * z + (1.f - d) * init_state[(size_t)row * 1024 + col];
        }
        stv(&C[(size_t)row * ldc + col], v);
      }
    }
  }
}

// ---------------------------------------------------------------------------
// MFMA flash attention v6 (unchanged): static-max softmax, chunked XCD
// swizzle, 1-tile-ahead prefetch, straight-line named-register staging.
// ---------------------------------------------------------------------------
#define LOAD_KV(JT, K0, K1, V0, V1)                                        \
  {                                                                        \
    const int krow_ = kbase + (JT) + kr;                                   \
    if (krow_ >= 0) {                                                      \
      const bf16* s_ = kp + (size_t)krow_ * k_rstride + h * 64 + kc;       \
      K0 = *(const uint4*)s_;                                              \
      K1 = *(const uint4*)(s_ + 8);                                        \
    } else { K0 = z4; K1 = z4; }                                           \
    const int col_ = kbase + (JT) + kc;                                    \
    if (col_ >= 0) {                                                       \
      const bf16* s_ = vtp + (size_t)(h * 64 + kr) * v_nstride + col_;     \
      V0 = *(const uint4*)s_;                                              \
      V1 = *(const uint4*)(s_ + 8);                                        \
    } else { V0 = z4; V1 = z4; }                                           \
  }

#define STORE_KV(K0, K1, V0, V1)          \
  {                                       \
    *(uint4*)&ksb[kr][kc] = K0;           \
    *(uint4*)&ksb[kr][kc + 8] = K1;       \
    *(uint4*)&vsb[kr][kc] = V0;           \
    *(uint4*)&vsb[kr][kc + 8] = V1;       \
  }

#define LOAD_BIAS(JT, B0, B1, B2, B3)                                      \
  {                                                                        \
    const bf16* bp_ = bshuf + (((size_t)h * 512 + qt * 64 + wq +           \
                                quad * 4) * 16 + ((JT) >> 6)) * 64 + lr * 4; \
    B0 = *(const ushort4*)bp_;                                             \
    B1 = *(const ushort4*)(bp_ + 1024);                                    \
    B2 = *(const ushort4*)(bp_ + 2048);                                    \
    B3 = *(const ushort4*)(bp_ + 3072);                                    \
  }

__global__ __launch_bounds__(256, 4) void attn_mfma(
    const bf16* __restrict__ qp, int q_rstride,
    const bf16* __restrict__ kp, int k_rstride,
    const bf16* __restrict__ vtp, int v_nstride,
    const bf16* __restrict__ bshuf, int causal, int nkeys,
    int qrows_per_blk, int kbase0, int krows_per_blk, int nqt, int nzb,
    bf16* __restrict__ op, int o_rstride, int o_coff, int o_hstride) {
  __shared__ __align__(16) bf16 ksb[64][72];  // [krow][d]
  __shared__ __align__(16) bf16 vsb[64][72];  // [d][krow]
  __shared__ __align__(16) bf16 psb[64][72];  // [qrow][kcol]
  const int Bp = (blockIdx.x & 7) * ((int)gridDim.x >> 3) + (blockIdx.x >> 3);
  const int zb = Bp % nzb;
  const int qt = (Bp / nzb) % nqt;
  const int h = Bp / (nzb * nqt);
  const int tid = threadIdx.x;
  const int w = tid >> 6, lane = tid & 63;
  const int lr = lane & 15, quad = lane >> 4;
  const int wq = w * 16;
  const int qbase = zb * qrows_per_blk + qt * 64;

  bf16x8 qf0, qf1;
  {
    const bf16* qr = qp + (size_t)(qbase + wq + lr) * q_rstride + h * 64 + quad * 8;
    qf0 = *(const bf16x8*)qr;
    qf1 = *(const bf16x8*)(qr + 32);
  }

  float l_i[4] = {0.f, 0.f, 0.f, 0.f};
  f32x4 o_acc[4] = {};

  const int kbase = kbase0 + zb * krows_per_blk;
  const int ntk = causal ? min(nkeys, qt * 64 + 64 + 512) : nkeys;
  const int kr = tid >> 2, kc = (tid & 3) * 16;

  const uint4 z4{0, 0, 0, 0};
  uint4 ka0, ka1, va0, va1;
  ushort4 bc0{0,0,0,0}, bc1{0,0,0,0}, bc2{0,0,0,0}, bc3{0,0,0,0};

  LOAD_KV(0, ka0, ka1, va0, va1);
  if (bshuf) LOAD_BIAS(0, bc0, bc1, bc2, bc3);
  STORE_KV(ka0, ka1, va0, va1);

  for (int jt = 0; jt < ntk; jt += 64) {
    __syncthreads();
    const bool pre = jt + 64 < ntk;
    ushort4 bn0{0,0,0,0}, bn1{0,0,0,0}, bn2{0,0,0,0}, bn3{0,0,0,0};
    if (pre) {
      LOAD_KV(jt + 64, ka0, ka1, va0, va1);
      if (bshuf) LOAD_BIAS(jt + 64, bn0, bn1, bn2, bn3);
    }

    // ---- S[16x64] = Q @ K^T ----
    f32x4 s_acc[4] = {};
#pragma unroll
    for (int j = 0; j < 4; ++j) {
      bf16x8 kf = *(const bf16x8*)&ksb[j * 16 + lr][quad * 8];
      s_acc[j] = __builtin_amdgcn_mfma_f32_16x16x32_bf16(qf0, kf, s_acc[j], 0, 0, 0);
    }
#pragma unroll
    for (int j = 0; j < 4; ++j) {
      bf16x8 kf = *(const bf16x8*)&ksb[j * 16 + lr][32 + quad * 8];
      s_acc[j] = __builtin_amdgcn_mfma_f32_16x16x32_bf16(qf1, kf, s_acc[j], 0, 0, 0);
    }

    // ---- bias + causal + static-max softmax (no cross-lane ops) ----
#pragma unroll
    for (int r = 0; r < 4; ++r) {
      const int brow = wq + quad * 4 + r;
      const int qloc = qt * 64 + brow;
      float sv0 = s_acc[0][r], sv1 = s_acc[1][r], sv2 = s_acc[2][r], sv3 = s_acc[3][r];
      if (bshuf) {
        ushort4 bw = (r == 0) ? bc0 : (r == 1) ? bc1 : (r == 2) ? bc2 : bc3;
        bf16 bb[4];
        *(ushort4*)bb = bw;
        sv0 += ldv(bb[0]); sv1 += ldv(bb[1]); sv2 += ldv(bb[2]); sv3 += ldv(bb[3]);
      }
      if (causal) {
        const int lim = qloc + 512;
        if (jt + 0 * 16 + lr > lim) sv0 = -3.0e38f;
        if (jt + 1 * 16 + lr > lim) sv1 = -3.0e38f;
        if (jt + 2 * 16 + lr > lim) sv2 = -3.0e38f;
        if (jt + 3 * 16 + lr > lim) sv3 = -3.0e38f;
      }
      const float p0 = __expf(sv0 - 12.f), p1 = __expf(sv1 - 12.f);
      const float p2 = __expf(sv2 - 12.f), p3 = __expf(sv3 - 12.f);
      l_i[r] += (p0 + p1) + (p2 + p3);
      psb[brow][0 * 16 + lr] = f2b(p0);
      psb[brow][1 * 16 + lr] = f2b(p1);
      psb[brow][2 * 16 + lr] = f2b(p2);
      psb[brow][3 * 16 + lr] = f2b(p3);
    }

    // ---- O[16x64] += P @ V ----
#pragma unroll
    for (int jc = 0; jc < 2; ++jc) {
      bf16x8 pf = *(const bf16x8*)&psb[wq + lr][jc * 32 + quad * 8];
#pragma unroll
      for (int dt = 0; dt < 4; ++dt) {
        bf16x8 vf = *(const bf16x8*)&vsb[dt * 16 + lr][jc * 32 + quad * 8];
        o_acc[dt] = __builtin_amdgcn_mfma_f32_16x16x32_bf16(pf, vf, o_acc[dt], 0, 0, 0);
      }
    }

    __syncthreads();
    if (pre) {
      STORE_KV(ka0, ka1, va0, va1);
      if (bshuf) { bc0 = bn0; bc1 = bn1; bc2 = bn2; bc3 = bn3; }
    }
  }

  // ---- epilogue ----
#pragma unroll
  for (int r = 0; r < 4; ++r) {
#pragma unroll
    for (int mm = 1; mm < 16; mm <<= 1) l_i[r] += __shfl_xor(l_i[r], mm);
    const int qrow = qbase + wq + quad * 4 + r;
    const float invl = 1.f / l_i[r];
    bf16* orow = op + (size_t)qrow * o_rstride + o_coff + (size_t)h * o_hstride;
#pragma unroll
    for (int dt = 0; dt < 4; ++dt) orow[dt * 16 + lr] = f2b(o_acc[dt][r] * invl);
  }
}

// ---------------------------------------------------------------------------
// memories (fp32 out): out[m][h][i][d] = qkv[(3584+i)*3072 + 1024*(m+1) + h*64 + d]
// (must run BEFORE the in-place l2norm of the qkv k-part)
// ---------------------------------------------------------------------------
__global__ __launch_bounds__(256) void memcopy_kernel(const bf16* __restrict__ qkv,
                                                      float* __restrict__ out) {
  const int idx = blockIdx.x * 256 + threadIdx.x;  // 2*16*512*64 = 1048576
  const int d = idx & 63;
  const int i = (idx >> 6) & 511;
  const int h = (idx >> 15) & 15;
  const int mm = idx >> 19;
  out[idx] = ldv(qkv[(size_t)(3584 + i) * 3072 + 1024 * (mm + 1) + h * 64 + d]);
}

// ---------------------------------------------------------------------------
extern "C" void kernel_launch(void* const* d_in, const int* in_sizes, int n_in,
                              void* d_out, int out_size, void* d_ws, size_t ws_size,
                              hipStream_t stream) {
  const float* x = (const float*)d_in[0];
  const float* rel_bias = (const float*)d_in[1];
  const float* gamma = (const float*)d_in[2];
  const float* w_qkv = (const float*)d_in[3];
  const float* q_scale = (const float*)d_in[4];
  const float* k_scale = (const float*)d_in[5];
  const float* w_out = (const float*)d_in[6];
  const float* s_gamma = (const float*)d_in[7];
  const float* w_q2s = (const float*)d_in[8];
  const float* w_qfs = (const float*)d_in[9];
  const float* w_sqkv = (const float*)d_in[10];
  const float* init_state = (const float*)d_in[11];
  const float* state_pos = (const float*)d_in[12];
  const float* w_sout = (const float*)d_in[13];
  const float* ts_qs = (const float*)d_in[14];
  const float* ts_ks = (const float*)d_in[15];
  const float* ss_qs = (const float*)d_in[16];
  const float* ss_ks = (const float*)d_in[17];
  const float* fs_qs = (const float*)d_in[18];
  const float* fs_ks = (const float*)d_in[19];
  const float* w_gate = (const float*)d_in[20];
  const float* b_gate = (const float*)d_in[21];
  const float* ema_beta = (const float*)d_in[22];

  // outputs: FP32
  float* out0 = (float*)d_out;         // [4096,1024]
  float* out_mem = out0 + 4194304;     // [2,16,512,64]
  float* out_ns = out0 + 5242880;      // [512,1024]

  // workspace (bf16 intermediates), 64 MiB total
  bf16* xn = (bf16*)d_ws;          // 4096x1024 (reused: vT_loc, then wT_out/sout)
  bf16* qkv = xn + 4194304;        // 4096x3072 (q/k parts l2norm'd in place)
  bf16* q2s = qkv + 12582912;      // 4096x1024 (reused: wT_gate after attns)
  bf16* aloc = q2s + 4194304;      // 4096x1024
  bf16* ats = aloc + 4194304;      // 4096x1024
  bf16* st = ats + 4194304;        // 512x1024 (later reused as vT_s)
  bf16* sqkv = st + 524288;        // 512x3072 (q/k parts l2norm'd in place)
  bf16* qfs = sqkv + 1572864;      // 512x1024 (l2norm'd in place)
  bf16* socat = qfs + 524288;      // 512x2048
  bf16* soproj = socat + 1048576;  // 512x1024 (early reuse: ist16)
  bf16* vT_loc = xn;               // [16*64][4096] after q2s gemm consumes xn
  bf16* vT_s = st;                 // [16*64][512]  after qfs gemm consumes st
  bf16* ist16 = soproj;            // bf16 copy of init_state (dead before step 9)

  // out0 region (16.78MB) as bf16 scratch: early transposed weights, then bshuf
  bf16* out0b = (bf16*)out0;
  bf16* wT_qkv = out0b;                 // 3072x1024
  bf16* wT_q2s = wT_qkv + 3145728;      // 1024x1024
  bf16* wT_sqkv = wT_q2s + 1048576;     // 3072x1024
  bf16* wT_qfs = wT_sqkv + 3145728;     // 1024x1024  (exactly fills out0)
  bf16* bshuf = out0b;                  // [16][512][16][64] bf16 (after GEMMs 1-4)
  // late transposed weights into freed regions
  bf16* wT_out = xn;                    // 2048x1024 (vT_loc dead after attns)
  bf16* wT_sout = xn + 2097152;         // 2048x1024
  bf16* wT_gate = q2s;                  // 1024x1024 (q2s dead after attn 2)

  // 1. layernorms + init_state cvt + weight transposes (wT into out0 scratch)
  ln_kernel<<<4096, 256, 0, stream>>>(x, gamma, nullptr, xn);
  ln_kernel<<<512, 256, 0, stream>>>(init_state, s_gamma, state_pos, st);
  cvt_kernel<<<256, 256, 0, stream>>>(init_state, ist16);
  wtrans_kernel<<<dim3(16, 48), 256, 0, stream>>>(w_qkv, 3072, wT_qkv, 1024);
  wtrans_kernel<<<dim3(16, 16), 256, 0, stream>>>(w_q2s, 1024, wT_q2s, 1024);
  wtrans_kernel<<<dim3(16, 48), 256, 0, stream>>>(w_sqkv, 3072, wT_sqkv, 1024);
  wtrans_kernel<<<dim3(16, 16), 256, 0, stream>>>(w_qfs, 1024, wT_qfs, 1024);

  // 2. projections (MFMA v3: BK=64, global_load_lds staging, XCD swizzle)
  mfma_gemm<bf16><<<768, 256, 0, stream>>>(
      24, 12, 8, xn, 1024, nullptr, 0, 0, wT_qkv, qkv, 3072, 1024, 0,
      nullptr, nullptr, nullptr);
  mfma_gemm<bf16><<<256, 256, 0, stream>>>(
      8, 8, 4, xn, 1024, nullptr, 0, 0, wT_q2s, q2s, 1024, 1024, 0,
      nullptr, nullptr, nullptr);
  mfma_gemm<bf16><<<96, 256, 0, stream>>>(
      24, 0, 0, ist16, 1024, nullptr, 0, 0, wT_sqkv, sqkv, 3072, 1024, 0,
      nullptr, nullptr, nullptr);
  mfma_gemm<bf16><<<32, 256, 0, stream>>>(
      8, 0, 0, st, 1024, nullptr, 0, 0, wT_qfs, qfs, 1024, 1024, 0,
      nullptr, nullptr, nullptr);

  // 3. memories output (raw k/v, before in-place norm)
  memcopy_kernel<<<4096, 256, 0, stream>>>(qkv, out_mem);

  // 4. V transposes (into freed xn/st regions) + bias shuffle (out0 free now)
  vtrans_kernel<<<dim3(64, 16), 256, 0, stream>>>(qkv, 3072, 2048, 4096, vT_loc);
  vtrans_kernel<<<dim3(8, 16), 256, 0, stream>>>(sqkv, 3072, 2048, 512, vT_s);
  bshuf_kernel<<<dim3(512, 16), 256, 0, stream>>>(rel_bias, bshuf);

  // 5. pre-normalize Q/K (q part carries qs*ks*8; k part plain l2norm)
  l2n_kernel<<<dim3(4096, 2), 256, 0, stream>>>(qkv, 3072, q_scale, k_scale, 8.f);
  l2n_kernel<<<dim3(512, 2), 256, 0, stream>>>(sqkv, 3072, ss_qs, ss_ks, 8.f);
  l2n_kernel<<<dim3(4096, 1), 256, 0, stream>>>(q2s, 1024, ts_qs, ts_ks, 8.f);
  l2n_kernel<<<dim3(512, 1), 256, 0, stream>>>(qfs, 1024, fs_qs, fs_ks, 8.f);

  // 6. attentions (MFMA flash v6; chunked XCD swizzle, zb fastest)
  attn_mfma<<<1024, 256, 0, stream>>>(
      qkv, 3072, qkv + 1024, 3072, vT_loc, 4096, bshuf, 1, 1024,
      512, -512, 512, 8, 8, aloc, 1024, 0, 64);
  attn_mfma<<<1024, 256, 0, stream>>>(
      q2s, 1024, sqkv + 1024, 3072, vT_s, 512, nullptr, 0, 512,
      4096, 0, 0, 64, 1, ats, 1024, 0, 64);
  attn_mfma<<<128, 256, 0, stream>>>(
      sqkv, 3072, sqkv + 1024, 3072, vT_s, 512, nullptr, 0, 512,
      512, 0, 0, 8, 1, socat, 2048, 0, 128);
  attn_mfma<<<128, 256, 0, stream>>>(
      qfs, 1024, qkv + 1024, 3072, vT_loc, 4096, nullptr, 0, 512,
      512, 3584, 0, 8, 1, socat, 2048, 64, 128);

  // 7. late weight transposes (vT_loc/q2s regions now dead)
  wtrans_kernel<<<dim3(32, 16), 256, 0, stream>>>(w_out, 1024, wT_out, 2048);
  wtrans_kernel<<<dim3(32, 16), 256, 0, stream>>>(w_sout, 1024, wT_sout, 2048);
  wtrans_kernel<<<dim3(16, 16), 256, 0, stream>>>(w_gate, 1024, wT_gate, 1024);

  // 8. out0 = [aloc | ats] @ w_out  (fp32 out; overwrites bshuf scratch)
  mfma_gemm<float><<<256, 256, 0, stream>>>(
      8, 8, 4, aloc, 1024, ats, 1024, 1024, wT_out, out0, 1024, 2048, 0,
      nullptr, nullptr, nullptr);

  // 9. state out path (new_states fp32 out)
  mfma_gemm<bf16><<<32, 256, 0, stream>>>(
      8, 0, 0, socat, 2048, nullptr, 0, 0, wT_sout, soproj, 1024, 2048, 0,
      nullptr, nullptr, nullptr);
  mfma_gemm<float><<<32, 256, 0, stream>>>(
      8, 0, 0, soproj, 1024, nullptr, 0, 0, wT_gate, out_ns, 1024, 1024, 1,
      b_gate, ema_beta, init_state);
}

// Round 9
// 526.055 us; speedup vs baseline: 1.8512x; 1.0726x over previous
//
#include <hip/hip_runtime.h>
#include <hip/hip_bf16.h>

using bf16 = __hip_bfloat16;
using bf16x8 = __attribute__((ext_vector_type(8))) short;
using f32x4 = __attribute__((ext_vector_type(4))) float;

static __device__ __forceinline__ float ldv(bf16 v) { return __bfloat162float(v); }
static __device__ __forceinline__ float ldv(float v) { return v; }
static __device__ __forceinline__ bf16 f2b(float v) { return __float2bfloat16(v); }
static __device__ __forceinline__ void stv(bf16* p, float v) { *p = __float2bfloat16(v); }
static __device__ __forceinline__ void stv(float* p, float v) { *p = v; }

// async global->LDS 16B copy: lds dest = wave-uniform base + lane*16 (HW)
static __device__ __forceinline__ void gload_lds16(const bf16* g, bf16* l) {
  __builtin_amdgcn_global_load_lds(
      (const __attribute__((address_space(1))) unsigned int*)g,
      (__attribute__((address_space(3))) unsigned int*)l, 16, 0, 0);
}

// ---------------------------------------------------------------------------
// LayerNorm (cols = 1024 fixed). out = (x - mean)*rsqrt(var+1e-5)*gamma [+ add]
// raw (optional): also emits bf16(x) unnormalized (folds the cvt pass).
// ---------------------------------------------------------------------------
__global__ __launch_bounds__(256) void ln_kernel(
    const float* __restrict__ x, const float* __restrict__ gamma,
    const float* __restrict__ add, bf16* __restrict__ out,
    bf16* __restrict__ raw) {
  const int row = blockIdx.x;
  const float* xr = x + (size_t)row * 1024;
  float v[4];
  float s = 0.f, ss = 0.f;
#pragma unroll
  for (int i = 0; i < 4; ++i) {
    v[i] = xr[threadIdx.x + 256 * i];
    s += v[i];
    ss += v[i] * v[i];
  }
  if (raw) {
#pragma unroll
    for (int i = 0; i < 4; ++i) raw[(size_t)row * 1024 + threadIdx.x + 256 * i] = f2b(v[i]);
  }
#pragma unroll
  for (int m = 1; m < 64; m <<= 1) {
    s += __shfl_xor(s, m);
    ss += __shfl_xor(ss, m);
  }
  __shared__ float red[8];
  const int wid = threadIdx.x >> 6;
  if ((threadIdx.x & 63) == 0) { red[wid] = s; red[wid + 4] = ss; }
  __syncthreads();
  s = red[0] + red[1] + red[2] + red[3];
  ss = red[4] + red[5] + red[6] + red[7];
  const float mean = s * (1.f / 1024.f);
  const float var = ss * (1.f / 1024.f) - mean * mean;
  const float rs = rsqrtf(var + 1e-5f);
  bf16* outr = out + (size_t)row * 1024;
#pragma unroll
  for (int i = 0; i < 4; ++i) {
    int c = threadIdx.x + 256 * i;
    float y = (v[i] - mean) * rs * gamma[c];
    if (add) y += add[(size_t)row * 1024 + c];
    outr[c] = f2b(y);
  }
}

// ---------------------------------------------------------------------------
// Per-head l2norm, in place, 3 parts per launch (part = blockIdx.y).
// Each part: its own buffer/stride/col-offset/scales. 16 heads x 64 d.
// ---------------------------------------------------------------------------
struct L2nPart {
  bf16* buf;
  int rs;
  int coff;
  const float* s1;
  const float* s2;
  float mult;
};

__global__ __launch_bounds__(256) void l2n_kernel(L2nPart p0, L2nPart p1, L2nPart p2) {
  const int row = blockIdx.x, part = blockIdx.y, t = threadIdx.x;
  L2nPart p = (part == 0) ? p0 : (part == 1) ? p1 : p2;
  const int d0 = (t & 15) * 4, hoff = (t >> 4) * 64;
  bf16* ptr = p.buf + (size_t)row * p.rs + p.coff + hoff + d0;
  bf16 b[4];
  *(ushort4*)b = *(const ushort4*)ptr;
  float v[4], ss = 0.f;
#pragma unroll
  for (int i = 0; i < 4; ++i) { v[i] = ldv(b[i]); ss += v[i] * v[i]; }
  ss += __shfl_xor(ss, 1);
  ss += __shfl_xor(ss, 2);
  ss += __shfl_xor(ss, 4);
  ss += __shfl_xor(ss, 8);
  const float inv = p.mult / fmaxf(sqrtf(ss), 1e-12f);
#pragma unroll
  for (int i = 0; i < 4; ++i) {
    float y = v[i] * inv;
    if (p.s1) y *= p.s1[d0 + i];
    if (p.s2) y *= p.s2[d0 + i];
    b[i] = f2b(y);
  }
  *(ushort4*)ptr = *(ushort4*)b;
}

// ---------------------------------------------------------------------------
// Per-head V transpose: dst[h*64+d][n] = src[n][coff + h*64 + d].
// ---------------------------------------------------------------------------
__global__ __launch_bounds__(256) void vtrans_kernel(
    const bf16* __restrict__ src, int rstride, int coff, int nrows,
    bf16* __restrict__ dst) {
  __shared__ bf16 tile[64][72];
  const int n0 = blockIdx.x * 64, h = blockIdx.y, t = threadIdx.x;
  {
    const int nr = t >> 2, dp = (t & 3) * 16;
    const bf16* s = src + (size_t)(n0 + nr) * rstride + coff + h * 64 + dp;
    *(uint4*)&tile[nr][dp] = *(const uint4*)s;
    *(uint4*)&tile[nr][dp + 8] = *(const uint4*)(s + 8);
  }
  __syncthreads();
  {
    const int dr = t >> 2, np = (t & 3) * 16;
    bf16 tmp[16];
#pragma unroll
    for (int i = 0; i < 16; ++i) tmp[i] = tile[np + i][dr];
    bf16* d = dst + (size_t)(h * 64 + dr) * nrows + n0 + np;
    *(uint4*)d = *(uint4*)&tmp[0];
    *(uint4*)(d + 8) = *(uint4*)&tmp[8];
  }
}

// ---------------------------------------------------------------------------
// Weight transpose+cvt, 4 sources per launch (dispatch on blockIdx.y range):
// dst[n][k] (bf16, row stride K) = src[k][n] (fp32).
// ---------------------------------------------------------------------------
struct WtPart {
  const float* src;
  int N;
  bf16* dst;
  int K;
};

__global__ __launch_bounds__(256) void wtrans_kernel(
    WtPart pa, int ya, WtPart pb, int yb, WtPart pc, int yc, WtPart pd) {
  __shared__ bf16 tile[64][72];
  const int y = blockIdx.y, t = threadIdx.x;
  WtPart p;
  int n0;
  if (y < ya) { p = pa; n0 = y * 64; }
  else if (y < yb) { p = pb; n0 = (y - ya) * 64; }
  else if (y < yc) { p = pc; n0 = (y - yb) * 64; }
  else { p = pd; n0 = (y - yc) * 64; }
  const int k0 = blockIdx.x * 64;
  if (k0 >= p.K) return;
  {
    const int kr = t >> 2, np = (t & 3) * 16;
    const float* s = p.src + (size_t)(k0 + kr) * p.N + n0 + np;
    bf16 tmp[16];
#pragma unroll
    for (int i = 0; i < 16; ++i) tmp[i] = f2b(s[i]);
    *(uint4*)&tile[kr][np] = *(uint4*)&tmp[0];
    *(uint4*)&tile[kr][np + 8] = *(uint4*)&tmp[8];
  }
  __syncthreads();
  {
    const int nr = t >> 2, kp = (t & 3) * 16;
    bf16 tmp[16];
#pragma unroll
    for (int i = 0; i < 16; ++i) tmp[i] = tile[kp + i][nr];
    bf16* d = p.dst + (size_t)(n0 + nr) * p.K + k0 + kp;
    *(uint4*)d = *(uint4*)&tmp[0];
    *(uint4*)(d + 8) = *(uint4*)&tmp[8];
  }
}

// ---------------------------------------------------------------------------
// Bias pre-shuffle: bshuf[h][q][jt][lr*4+j] = bf16(bias[h][q][jt*64 + j*16 + lr])
// ---------------------------------------------------------------------------
__global__ __launch_bounds__(256) void bshuf_kernel(const float* __restrict__ bias,
                                                    bf16* __restrict__ out) {
  const int q = blockIdx.x, h = blockIdx.y, t = threadIdx.x;
  const int jt = t >> 4, lr = t & 15;
  const float* src = bias + ((size_t)h * 512 + q) * 1024 + jt * 64 + lr;
  bf16 b[4];
#pragma unroll
  for (int j = 0; j < 4; ++j) b[j] = f2b(src[j * 16]);
  *(ushort4*)(out + (((size_t)h * 512 + q) * 16 + jt) * 64 + lr * 4) = *(ushort4*)b;
}

// ---------------------------------------------------------------------------
// MFMA GEMM v3  C[M,N] = Acat[M,K] @ Bt^T   (A, A2, Bt all bf16; Bt [N][K])
// BK=64; global_load_lds width-16 staging; XOR-chunk swizzle on both the
// global source and the ds_read (rule #21); chunked XCD swizzle (cw x ch).
// ---------------------------------------------------------------------------
template <typename TC>
__global__ __launch_bounds__(256) void mfma_gemm(
    int nx, int cw, int ch,
    const bf16* __restrict__ A, int lda,
    const bf16* __restrict__ A2, int lda2, int K1,
    const bf16* __restrict__ Bt,
    TC* __restrict__ C, int ldc, int K,
    int epilogue,
    const float* __restrict__ b_gate, const float* __restrict__ ema_beta,
    const float* __restrict__ init_state) {
  __shared__ bf16 Asb[128][64];
  __shared__ bf16 Bsb[128][64];
  int bxi, byi;
  if (cw) {
    const int c = blockIdx.x & 7, r = blockIdx.x >> 3;
    const int nchx = nx / cw;
    bxi = (c % nchx) * cw + r % cw;
    byi = (c / nchx) * ch + r / cw;
  } else {
    bxi = blockIdx.x % nx;
    byi = blockIdx.x / nx;
  }
  const int bm = byi * 128, bn = bxi * 128;
  const int tid = threadIdx.x;
  const int w = tid >> 6, lane = tid & 63;
  const int wm = (w >> 1) * 64, wn = (w & 1) * 64;
  const int lr = lane & 15, quad = lane >> 4;
  const int srow = (lane >> 3);                    // + (w*4+c)*8
  const int sck = ((lane & 7) ^ (lane >> 3)) * 8;  // source k-offset (elems)

  f32x4 acc[4][4] = {};

  for (int kt = 0; kt < K; kt += 64) {
#pragma unroll
    for (int c = 0; c < 4; ++c) {
      const int m = (w * 4 + c) * 8 + srow;
      const int gk = kt + sck;
      const bf16* ap = (A2 && gk >= K1)
                           ? (A2 + (size_t)(bm + m) * lda2 + (gk - K1))
                           : (A + (size_t)(bm + m) * lda + gk);
      gload_lds16(ap, &Asb[0][0] + (w * 4 + c) * 512);
    }
#pragma unroll
    for (int c = 0; c < 4; ++c) {
      const int n = (w * 4 + c) * 8 + srow;
      gload_lds16(Bt + (size_t)(bn + n) * K + kt + sck,
                  &Bsb[0][0] + (w * 4 + c) * 512);
    }
    __syncthreads();

#pragma unroll
    for (int dc = 0; dc < 2; ++dc) {
      const int csw = (((dc * 4 + quad) ^ (lr & 7))) * 8;  // swizzled chunk
      bf16x8 af[4], bfr[4];
#pragma unroll
      for (int i = 0; i < 4; ++i)
        af[i] = *(const bf16x8*)&Asb[wm + i * 16 + lr][csw];
#pragma unroll
      for (int j = 0; j < 4; ++j)
        bfr[j] = *(const bf16x8*)&Bsb[wn + j * 16 + lr][csw];
#pragma unroll
      for (int i = 0; i < 4; ++i)
#pragma unroll
        for (int j = 0; j < 4; ++j)
          acc[i][j] = __builtin_amdgcn_mfma_f32_16x16x32_bf16(af[i], bfr[j],
                                                              acc[i][j], 0, 0, 0);
    }
    __syncthreads();
  }

#pragma unroll
  for (int i = 0; i < 4; ++i) {
#pragma unroll
    for (int j = 0; j < 4; ++j) {
#pragma unroll
      for (int r = 0; r < 4; ++r) {
        const int row = bm + wm + i * 16 + quad * 4 + r;
        const int col = bn + wn + j * 16 + lr;
        float v = acc[i][j][r];
        if (epilogue == 1) {
          float z = v + b_gate[col];
          float d = 1.f / (1.f + __expf(-ema_beta[col]));
          v = d * z + (1.f - d) * init_state[(size_t)row * 1024 + col];
        }
        stv(&C[(size_t)row * ldc + col], v);
      }
    }
  }
}

// ---------------------------------------------------------------------------
// MFMA flash attention v6 (unchanged): static-max softmax, chunked XCD
// swizzle, 1-tile-ahead prefetch, straight-line named-register staging.
// ---------------------------------------------------------------------------
#define LOAD_KV(JT, K0, K1, V0, V1)                                        \
  {                                                                        \
    const int krow_ = kbase + (JT) + kr;                                   \
    if (krow_ >= 0) {                                                      \
      const bf16* s_ = kp + (size_t)krow_ * k_rstride + h * 64 + kc;       \
      K0 = *(const uint4*)s_;                                              \
      K1 = *(const uint4*)(s_ + 8);                                        \
    } else { K0 = z4; K1 = z4; }                                           \
    const int col_ = kbase + (JT) + kc;                                    \
    if (col_ >= 0) {                                                       \
      const bf16* s_ = vtp + (size_t)(h * 64 + kr) * v_nstride + col_;     \
      V0 = *(const uint4*)s_;                                              \
      V1 = *(const uint4*)(s_ + 8);                                        \
    } else { V0 = z4; V1 = z4; }                                           \
  }

#define STORE_KV(K0, K1, V0, V1)          \
  {                                       \
    *(uint4*)&ksb[kr][kc] = K0;           \
    *(uint4*)&ksb[kr][kc + 8] = K1;       \
    *(uint4*)&vsb[kr][kc] = V0;           \
    *(uint4*)&vsb[kr][kc + 8] = V1;       \
  }

#define LOAD_BIAS(JT, B0, B1, B2, B3)                                      \
  {                                                                        \
    const bf16* bp_ = bshuf + (((size_t)h * 512 + qt * 64 + wq +           \
                                quad * 4) * 16 + ((JT) >> 6)) * 64 + lr * 4; \
    B0 = *(const ushort4*)bp_;                                             \
    B1 = *(const ushort4*)(bp_ + 1024);                                    \
    B2 = *(const ushort4*)(bp_ + 2048);                                    \
    B3 = *(const ushort4*)(bp_ + 3072);                                    \
  }

__global__ __launch_bounds__(256, 4) void attn_mfma(
    const bf16* __restrict__ qp, int q_rstride,
    const bf16* __restrict__ kp, int k_rstride,
    const bf16* __restrict__ vtp, int v_nstride,
    const bf16* __restrict__ bshuf, int causal, int nkeys,
    int qrows_per_blk, int kbase0, int krows_per_blk, int nqt, int nzb,
    bf16* __restrict__ op, int o_rstride, int o_coff, int o_hstride) {
  __shared__ __align__(16) bf16 ksb[64][72];  // [krow][d]
  __shared__ __align__(16) bf16 vsb[64][72];  // [d][krow]
  __shared__ __align__(16) bf16 psb[64][72];  // [qrow][kcol]
  const int Bp = (blockIdx.x & 7) * ((int)gridDim.x >> 3) + (blockIdx.x >> 3);
  const int zb = Bp % nzb;
  const int qt = (Bp / nzb) % nqt;
  const int h = Bp / (nzb * nqt);
  const int tid = threadIdx.x;
  const int w = tid >> 6, lane = tid & 63;
  const int lr = lane & 15, quad = lane >> 4;
  const int wq = w * 16;
  const int qbase = zb * qrows_per_blk + qt * 64;

  bf16x8 qf0, qf1;
  {
    const bf16* qr = qp + (size_t)(qbase + wq + lr) * q_rstride + h * 64 + quad * 8;
    qf0 = *(const bf16x8*)qr;
    qf1 = *(const bf16x8*)(qr + 32);
  }

  float l_i[4] = {0.f, 0.f, 0.f, 0.f};
  f32x4 o_acc[4] = {};

  const int kbase = kbase0 + zb * krows_per_blk;
  const int ntk = causal ? min(nkeys, qt * 64 + 64 + 512) : nkeys;
  const int kr = tid >> 2, kc = (tid & 3) * 16;

  const uint4 z4{0, 0, 0, 0};
  uint4 ka0, ka1, va0, va1;
  ushort4 bc0{0,0,0,0}, bc1{0,0,0,0}, bc2{0,0,0,0}, bc3{0,0,0,0};

  LOAD_KV(0, ka0, ka1, va0, va1);
  if (bshuf) LOAD_BIAS(0, bc0, bc1, bc2, bc3);
  STORE_KV(ka0, ka1, va0, va1);

  for (int jt = 0; jt < ntk; jt += 64) {
    __syncthreads();
    const bool pre = jt + 64 < ntk;
    ushort4 bn0{0,0,0,0}, bn1{0,0,0,0}, bn2{0,0,0,0}, bn3{0,0,0,0};
    if (pre) {
      LOAD_KV(jt + 64, ka0, ka1, va0, va1);
      if (bshuf) LOAD_BIAS(jt + 64, bn0, bn1, bn2, bn3);
    }

    // ---- S[16x64] = Q @ K^T ----
    f32x4 s_acc[4] = {};
#pragma unroll
    for (int j = 0; j < 4; ++j) {
      bf16x8 kf = *(const bf16x8*)&ksb[j * 16 + lr][quad * 8];
      s_acc[j] = __builtin_amdgcn_mfma_f32_16x16x32_bf16(qf0, kf, s_acc[j], 0, 0, 0);
    }
#pragma unroll
    for (int j = 0; j < 4; ++j) {
      bf16x8 kf = *(const bf16x8*)&ksb[j * 16 + lr][32 + quad * 8];
      s_acc[j] = __builtin_amdgcn_mfma_f32_16x16x32_bf16(qf1, kf, s_acc[j], 0, 0, 0);
    }

    // ---- bias + causal + static-max softmax (no cross-lane ops) ----
#pragma unroll
    for (int r = 0; r < 4; ++r) {
      const int brow = wq + quad * 4 + r;
      const int qloc = qt * 64 + brow;
      float sv0 = s_acc[0][r], sv1 = s_acc[1][r], sv2 = s_acc[2][r], sv3 = s_acc[3][r];
      if (bshuf) {
        ushort4 bw = (r == 0) ? bc0 : (r == 1) ? bc1 : (r == 2) ? bc2 : bc3;
        bf16 bb[4];
        *(ushort4*)bb = bw;
        sv0 += ldv(bb[0]); sv1 += ldv(bb[1]); sv2 += ldv(bb[2]); sv3 += ldv(bb[3]);
      }
      if (causal) {
        const int lim = qloc + 512;
        if (jt + 0 * 16 + lr > lim) sv0 = -3.0e38f;
        if (jt + 1 * 16 + lr > lim) sv1 = -3.0e38f;
        if (jt + 2 * 16 + lr > lim) sv2 = -3.0e38f;
        if (jt + 3 * 16 + lr > lim) sv3 = -3.0e38f;
      }
      const float p0 = __expf(sv0 - 12.f), p1 = __expf(sv1 - 12.f);
      const float p2 = __expf(sv2 - 12.f), p3 = __expf(sv3 - 12.f);
      l_i[r] += (p0 + p1) + (p2 + p3);
      psb[brow][0 * 16 + lr] = f2b(p0);
      psb[brow][1 * 16 + lr] = f2b(p1);
      psb[brow][2 * 16 + lr] = f2b(p2);
      psb[brow][3 * 16 + lr] = f2b(p3);
    }

    // ---- O[16x64] += P @ V ----
#pragma unroll
    for (int jc = 0; jc < 2; ++jc) {
      bf16x8 pf = *(const bf16x8*)&psb[wq + lr][jc * 32 + quad * 8];
#pragma unroll
      for (int dt = 0; dt < 4; ++dt) {
        bf16x8 vf = *(const bf16x8*)&vsb[dt * 16 + lr][jc * 32 + quad * 8];
        o_acc[dt] = __builtin_amdgcn_mfma_f32_16x16x32_bf16(pf, vf, o_acc[dt], 0, 0, 0);
      }
    }

    __syncthreads();
    if (pre) {
      STORE_KV(ka0, ka1, va0, va1);
      if (bshuf) { bc0 = bn0; bc1 = bn1; bc2 = bn2; bc3 = bn3; }
    }
  }

  // ---- epilogue ----
#pragma unroll
  for (int r = 0; r < 4; ++r) {
#pragma unroll
    for (int mm = 1; mm < 16; mm <<= 1) l_i[r] += __shfl_xor(l_i[r], mm);
    const int qrow = qbase + wq + quad * 4 + r;
    const float invl = 1.f / l_i[r];
    bf16* orow = op + (size_t)qrow * o_rstride + o_coff + (size_t)h * o_hstride;
#pragma unroll
    for (int dt = 0; dt < 4; ++dt) orow[dt * 16 + lr] = f2b(o_acc[dt][r] * invl);
  }
}

// ---------------------------------------------------------------------------
// memories (fp32 out): out[m][h][i][d] = proj[(3584+i)*4096 + 1024*(m+1) + h*64 + d]
// (runs BEFORE the in-place l2norm of the proj k-part)
// ---------------------------------------------------------------------------
__global__ __launch_bounds__(256) void memcopy_kernel(const bf16* __restrict__ proj,
                                                      float* __restrict__ out) {
  const int idx = blockIdx.x * 256 + threadIdx.x;  // 2*16*512*64 = 1048576
  const int d = idx & 63;
  const int i = (idx >> 6) & 511;
  const int h = (idx >> 15) & 15;
  const int mm = idx >> 19;
  out[idx] = ldv(proj[(size_t)(3584 + i) * 4096 + 1024 * (mm + 1) + h * 64 + d]);
}

// ---------------------------------------------------------------------------
extern "C" void kernel_launch(void* const* d_in, const int* in_sizes, int n_in,
                              void* d_out, int out_size, void* d_ws, size_t ws_size,
                              hipStream_t stream) {
  const float* x = (const float*)d_in[0];
  const float* rel_bias = (const float*)d_in[1];
  const float* gamma = (const float*)d_in[2];
  const float* w_qkv = (const float*)d_in[3];
  const float* q_scale = (const float*)d_in[4];
  const float* k_scale = (const float*)d_in[5];
  const float* w_out = (const float*)d_in[6];
  const float* s_gamma = (const float*)d_in[7];
  const float* w_q2s = (const float*)d_in[8];
  const float* w_qfs = (const float*)d_in[9];
  const float* w_sqkv = (const float*)d_in[10];
  const float* init_state = (const float*)d_in[11];
  const float* state_pos = (const float*)d_in[12];
  const float* w_sout = (const float*)d_in[13];
  const float* ts_qs = (const float*)d_in[14];
  const float* ts_ks = (const float*)d_in[15];
  const float* ss_qs = (const float*)d_in[16];
  const float* ss_ks = (const float*)d_in[17];
  const float* fs_qs = (const float*)d_in[18];
  const float* fs_ks = (const float*)d_in[19];
  const float* w_gate = (const float*)d_in[20];
  const float* b_gate = (const float*)d_in[21];
  const float* ema_beta = (const float*)d_in[22];

  // outputs: FP32
  float* out0 = (float*)d_out;         // [4096,1024]
  float* out_mem = out0 + 4194304;     // [2,16,512,64]
  float* out_ns = out0 + 5242880;      // [512,1024]

  // workspace (bf16 intermediates), 64 MiB total
  bf16* xn = (bf16*)d_ws;          // 4096x1024 (reused: vT_loc, then wT_out/sout)
  bf16* proj = xn + 4194304;       // 4096x4096: [q|k|v|q2s] cols 0/1024/2048/3072
  bf16* aloc = proj + 16777216;    // 4096x1024
  bf16* ats = aloc + 4194304;      // 4096x1024
  bf16* st = ats + 4194304;        // 512x1024 (later reused as vT_s)
  bf16* sqkv = st + 524288;        // 512x3072 (q/k parts l2norm'd in place)
  bf16* qfs = sqkv + 1572864;      // 512x1024 (l2norm'd in place)
  bf16* socat = qfs + 524288;      // 512x2048
  bf16* soproj = socat + 1048576;  // 512x1024 (early reuse: ist16)
  bf16* vT_loc = xn;               // [16*64][4096] after proj gemm consumes xn
  bf16* vT_s = st;                 // [16*64][512]  after qfs gemm consumes st
  bf16* ist16 = soproj;            // bf16 copy of init_state (dead before step 9)

  // out0 region (16.78MB) as bf16 scratch: early transposed weights, then bshuf
  bf16* out0b = (bf16*)out0;
  bf16* wT_qkv = out0b;                 // 3072x1024 (rows 0-3071 of fused Bt)
  bf16* wT_q2s = wT_qkv + 3145728;      // 1024x1024 (rows 3072-4095, contiguous)
  bf16* wT_sqkv = wT_q2s + 1048576;     // 3072x1024
  bf16* wT_qfs = wT_sqkv + 3145728;     // 1024x1024  (exactly fills out0)
  bf16* bshuf = out0b;                  // [16][512][16][64] bf16 (after GEMMs)
  // late transposed weights into freed regions
  bf16* wT_out = xn;                    // 2048x1024 (vT_loc dead after attns)
  bf16* wT_sout = xn + 2097152;         // 2048x1024
  bf16* wT_gate = proj;                 // 1024x1024 (proj dead after attns)

  // 1. layernorms (+raw ist16) + merged weight transposes (into out0 scratch)
  ln_kernel<<<4096, 256, 0, stream>>>(x, gamma, nullptr, xn, nullptr);
  ln_kernel<<<512, 256, 0, stream>>>(init_state, s_gamma, state_pos, st, ist16);
  {
    WtPart pa{w_qkv, 3072, wT_qkv, 1024};
    WtPart pb{w_q2s, 1024, wT_q2s, 1024};
    WtPart pc{w_sqkv, 3072, wT_sqkv, 1024};
    WtPart pd{w_qfs, 1024, wT_qfs, 1024};
    wtrans_kernel<<<dim3(16, 128), 256, 0, stream>>>(pa, 48, pb, 64, pc, 112, pd);
  }

  // 2. projections (fused qkv+q2s: N=4096; Bt = wT_qkv||wT_q2s contiguous)
  mfma_gemm<bf16><<<1024, 256, 0, stream>>>(
      32, 16, 8, xn, 1024, nullptr, 0, 0, wT_qkv, proj, 4096, 1024, 0,
      nullptr, nullptr, nullptr);
  mfma_gemm<bf16><<<96, 256, 0, stream>>>(
      24, 0, 0, ist16, 1024, nullptr, 0, 0, wT_sqkv, sqkv, 3072, 1024, 0,
      nullptr, nullptr, nullptr);
  mfma_gemm<bf16><<<32, 256, 0, stream>>>(
      8, 0, 0, st, 1024, nullptr, 0, 0, wT_qfs, qfs, 1024, 1024, 0,
      nullptr, nullptr, nullptr);

  // 3. memories output (raw k/v, before in-place norm)
  memcopy_kernel<<<4096, 256, 0, stream>>>(proj, out_mem);

  // 4. V transposes (into freed xn/st regions) + bias shuffle (out0 free now)
  vtrans_kernel<<<dim3(64, 16), 256, 0, stream>>>(proj, 4096, 2048, 4096, vT_loc);
  vtrans_kernel<<<dim3(8, 16), 256, 0, stream>>>(sqkv, 3072, 2048, 512, vT_s);
  bshuf_kernel<<<dim3(512, 16), 256, 0, stream>>>(rel_bias, bshuf);

  // 5. pre-normalize Q/K (merged: 3 parts per launch)
  {
    L2nPart p0{proj, 4096, 0, q_scale, k_scale, 8.f};
    L2nPart p1{proj, 4096, 1024, nullptr, nullptr, 1.f};
    L2nPart p2{proj, 4096, 3072, ts_qs, ts_ks, 8.f};
    l2n_kernel<<<dim3(4096, 3), 256, 0, stream>>>(p0, p1, p2);
  }
  {
    L2nPart p0{sqkv, 3072, 0, ss_qs, ss_ks, 8.f};
    L2nPart p1{sqkv, 3072, 1024, nullptr, nullptr, 1.f};
    L2nPart p2{qfs, 1024, 0, fs_qs, fs_ks, 8.f};
    l2n_kernel<<<dim3(512, 3), 256, 0, stream>>>(p0, p1, p2);
  }

  // 6. attentions (MFMA flash v6; chunked XCD swizzle, zb fastest)
  attn_mfma<<<1024, 256, 0, stream>>>(
      proj, 4096, proj + 1024, 4096, vT_loc, 4096, bshuf, 1, 1024,
      512, -512, 512, 8, 8, aloc, 1024, 0, 64);
  attn_mfma<<<1024, 256, 0, stream>>>(
      proj + 3072, 4096, sqkv + 1024, 3072, vT_s, 512, nullptr, 0, 512,
      4096, 0, 0, 64, 1, ats, 1024, 0, 64);
  attn_mfma<<<128, 256, 0, stream>>>(
      sqkv, 3072, sqkv + 1024, 3072, vT_s, 512, nullptr, 0, 512,
      512, 0, 0, 8, 1, socat, 2048, 0, 128);
  attn_mfma<<<128, 256, 0, stream>>>(
      qfs, 1024, proj + 1024, 4096, vT_loc, 4096, nullptr, 0, 512,
      512, 3584, 0, 8, 1, socat, 2048, 64, 128);

  // 7. late weight transposes, merged (vT_loc/proj regions now dead)
  {
    WtPart pa{w_out, 1024, wT_out, 2048};
    WtPart pb{w_sout, 1024, wT_sout, 2048};
    WtPart pc{w_gate, 1024, wT_gate, 1024};
    WtPart pd{w_gate, 1024, wT_gate, 1024};  // unused
    wtrans_kernel<<<dim3(32, 48), 256, 0, stream>>>(pa, 16, pb, 32, pc, 48, pd);
  }

  // 8. out0 = [aloc | ats] @ w_out  (fp32 out; overwrites bshuf scratch)
  mfma_gemm<float><<<256, 256, 0, stream>>>(
      8, 8, 4, aloc, 1024, ats, 1024, 1024, wT_out, out0, 1024, 2048, 0,
      nullptr, nullptr, nullptr);

  // 9. state out path (new_states fp32 out)
  mfma_gemm<bf16><<<32, 256, 0, stream>>>(
      8, 0, 0, socat, 2048, nullptr, 0, 0, wT_sout, soproj, 1024, 2048, 0,
      nullptr, nullptr, nullptr);
  mfma_gemm<float><<<32, 256, 0, stream>>>(
      8, 0, 0, soproj, 1024, nullptr, 0, 0, wT_gate, out_ns, 1024, 1024, 1,
      b_gate, ema_beta, init_state);
}

// Round 10
// 426.175 us; speedup vs baseline: 2.2851x; 1.2344x over previous
//
#include <hip/hip_runtime.h>
#include <hip/hip_bf16.h>

using bf16 = __hip_bfloat16;
using bf16x8 = __attribute__((ext_vector_type(8))) short;
using f32x4 = __attribute__((ext_vector_type(4))) float;

static __device__ __forceinline__ float ldv(bf16 v) { return __bfloat162float(v); }
static __device__ __forceinline__ bf16 f2b(float v) { return __float2bfloat16(v); }

// async global->LDS 16B copy: lds dest = wave-uniform base + lane*16 (HW)
static __device__ __forceinline__ void gload_lds16(const bf16* g, bf16* l) {
  __builtin_amdgcn_global_load_lds(
      (const __attribute__((address_space(1))) unsigned int*)g,
      (__attribute__((address_space(3))) unsigned int*)l, 16, 0, 0);
}

struct L2nPart {
  bf16* buf;
  int rs;
  int coff;
  const float* s1;
  const float* s2;
  float mult;
};

struct WtPart {
  const float* src;
  int N;
  bf16* dst;
  int K;
};

struct GemmDesc {
  const bf16* A; int lda;
  const bf16* A2; int lda2; int K1;
  const bf16* Bt;
  void* C; int ldc; int K;
  int nx, cw, ch;
  int ep;    // 0 none, 1 sigmoid-gated EMA, 2 memories side-write
  int cf32;  // C is float
  int nblk;  // blocks in this segment (for XCD swizzle)
};

struct AttnDesc {
  const bf16* qp; int q_rstride;
  const bf16* kp; int k_rstride;
  const bf16* vtp; int v_nstride;
  const bf16* bshuf;
  int causal, nkeys, qrows_per_blk, kbase0, krows_per_blk, nqt, nzb, nblk;
  bf16* op; int o_rstride, o_coff, o_hstride;
};

// ---------------------------------------------------------------------------
// pre_kernel: fused {LayerNorm rows} + {weight transpose+cvt}.
// B < nln: ln (first nln0 rows = set 0, rest = set 1; raw = bf16(x) side out).
// B >= nln: wtrans, flattened 1D: kx = L % nkx, y = L / nkx (y ranges pick part).
// ---------------------------------------------------------------------------
__global__ __launch_bounds__(256) void pre_kernel(
    int nln0, int nln,
    const float* x0, const float* g0, const float* a0, bf16* o0, bf16* r0,
    const float* x1, const float* g1, const float* a1, bf16* o1, bf16* r1,
    int nkx, WtPart pa, int ya, WtPart pb, int yb, WtPart pc, int yc, WtPart pd) {
  __shared__ bf16 tile[64][72];
  __shared__ float red[8];
  const int t = threadIdx.x;
  const int B = blockIdx.x;
  if (B < nln) {
    int row = B;
    const float* x; const float* gamma; const float* add; bf16* out; bf16* raw;
    if (row < nln0) { x = x0; gamma = g0; add = a0; out = o0; raw = r0; }
    else { row -= nln0; x = x1; gamma = g1; add = a1; out = o1; raw = r1; }
    const float* xr = x + (size_t)row * 1024;
    float v[4];
    float s = 0.f, ss = 0.f;
#pragma unroll
    for (int i = 0; i < 4; ++i) {
      v[i] = xr[t + 256 * i];
      s += v[i];
      ss += v[i] * v[i];
    }
    if (raw) {
#pragma unroll
      for (int i = 0; i < 4; ++i) raw[(size_t)row * 1024 + t + 256 * i] = f2b(v[i]);
    }
#pragma unroll
    for (int m = 1; m < 64; m <<= 1) {
      s += __shfl_xor(s, m);
      ss += __shfl_xor(ss, m);
    }
    const int wid = t >> 6;
    if ((t & 63) == 0) { red[wid] = s; red[wid + 4] = ss; }
    __syncthreads();
    s = red[0] + red[1] + red[2] + red[3];
    ss = red[4] + red[5] + red[6] + red[7];
    const float mean = s * (1.f / 1024.f);
    const float var = ss * (1.f / 1024.f) - mean * mean;
    const float rs = rsqrtf(var + 1e-5f);
    bf16* outr = out + (size_t)row * 1024;
#pragma unroll
    for (int i = 0; i < 4; ++i) {
      int c = t + 256 * i;
      float y = (v[i] - mean) * rs * gamma[c];
      if (add) y += add[(size_t)row * 1024 + c];
      outr[c] = f2b(y);
    }
    return;
  }
  // ---- wtrans ----
  const int L = B - nln;
  const int y = L / nkx;
  WtPart p;
  int n0;
  if (y < ya) { p = pa; n0 = y * 64; }
  else if (y < yb) { p = pb; n0 = (y - ya) * 64; }
  else if (y < yc) { p = pc; n0 = (y - yb) * 64; }
  else { p = pd; n0 = (y - yc) * 64; }
  const int k0 = (L % nkx) * 64;
  if (k0 >= p.K) return;
  {
    const int kr = t >> 2, np = (t & 3) * 16;
    const float* s = p.src + (size_t)(k0 + kr) * p.N + n0 + np;
    bf16 tmp[16];
#pragma unroll
    for (int i = 0; i < 16; ++i) tmp[i] = f2b(s[i]);
    *(uint4*)&tile[kr][np] = *(uint4*)&tmp[0];
    *(uint4*)&tile[kr][np + 8] = *(uint4*)&tmp[8];
  }
  __syncthreads();
  {
    const int nr = t >> 2, kp = (t & 3) * 16;
    bf16 tmp[16];
#pragma unroll
    for (int i = 0; i < 16; ++i) tmp[i] = tile[kp + i][nr];
    bf16* d = p.dst + (size_t)(n0 + nr) * p.K + k0 + kp;
    *(uint4*)d = *(uint4*)&tmp[0];
    *(uint4*)(d + 8) = *(uint4*)&tmp[8];
  }
}

// ---------------------------------------------------------------------------
// prep_kernel: fused {V transposes} + {bias pre-shuffle} + {per-head l2norm}.
// [0,1024): vtrans_loc  [1024,1152): vtrans_s  [1152,3200): bshuf (4 q/blk)
// [3200, 3200+3456): l2n (parts 0-2: 4096 rows x 4/blk; 3-5: 512 rows x 4/blk).
// Disjoint address sets: vtrans reads v cols; l2n touches q/k/q2s cols only.
// ---------------------------------------------------------------------------
__global__ __launch_bounds__(256) void prep_kernel(
    const bf16* v0src, int v0rs, int v0co, int v0n, bf16* v0dst,
    const bf16* v1src, int v1rs, int v1co, int v1n, bf16* v1dst,
    const float* bias, bf16* bsh,
    L2nPart q0, L2nPart q1, L2nPart q2, L2nPart q3, L2nPart q4, L2nPart q5) {
  __shared__ bf16 tile[64][72];
  const int t = threadIdx.x;
  int B = blockIdx.x;
  if (B < 1152) {
    const bf16* src; int rstride, coff, nrows; bf16* dst; int n0, h;
    if (B < 1024) {
      src = v0src; rstride = v0rs; coff = v0co; nrows = v0n; dst = v0dst;
      n0 = (B & 63) * 64; h = B >> 6;
    } else {
      const int L = B - 1024;
      src = v1src; rstride = v1rs; coff = v1co; nrows = v1n; dst = v1dst;
      n0 = (L & 7) * 64; h = L >> 3;
    }
    {
      const int nr = t >> 2, dp = (t & 3) * 16;
      const bf16* s = src + (size_t)(n0 + nr) * rstride + coff + h * 64 + dp;
      *(uint4*)&tile[nr][dp] = *(const uint4*)s;
      *(uint4*)&tile[nr][dp + 8] = *(const uint4*)(s + 8);
    }
    __syncthreads();
    {
      const int dr = t >> 2, np = (t & 3) * 16;
      bf16 tmp[16];
#pragma unroll
      for (int i = 0; i < 16; ++i) tmp[i] = tile[np + i][dr];
      bf16* d = dst + (size_t)(h * 64 + dr) * nrows + n0 + np;
      *(uint4*)d = *(uint4*)&tmp[0];
      *(uint4*)(d + 8) = *(uint4*)&tmp[8];
    }
    return;
  }
  B -= 1152;
  if (B < 2048) {
    // bshuf: bsh[h][q][jt][lr*4+j] = bf16(bias[h][q][jt*64 + j*16 + lr])
    const int h = B >> 7, qq0 = (B & 127) * 4;
    const int jt = t >> 4, lr = t & 15;
#pragma unroll
    for (int qi = 0; qi < 4; ++qi) {
      const int q = qq0 + qi;
      const float* src = bias + ((size_t)h * 512 + q) * 1024 + jt * 64 + lr;
      bf16 b[4];
#pragma unroll
      for (int j = 0; j < 4; ++j) b[j] = f2b(src[j * 16]);
      *(ushort4*)(bsh + (((size_t)h * 512 + q) * 16 + jt) * 64 + lr * 4) = *(ushort4*)b;
    }
    return;
  }
  B -= 2048;
  // l2n
  L2nPart p;
  int row0;
  if (B < 3072) {
    const int part = B >> 10;
    row0 = (B & 1023) * 4;
    p = (part == 0) ? q0 : (part == 1) ? q1 : q2;
  } else {
    const int L = B - 3072;
    const int part = L >> 7;
    row0 = (L & 127) * 4;
    p = (part == 0) ? q3 : (part == 1) ? q4 : q5;
  }
  const int d0 = (t & 15) * 4, hoff = (t >> 4) * 64;
#pragma unroll
  for (int ri = 0; ri < 4; ++ri) {
    bf16* ptr = p.buf + (size_t)(row0 + ri) * p.rs + p.coff + hoff + d0;
    bf16 b[4];
    *(ushort4*)b = *(const ushort4*)ptr;
    float v[4], ss = 0.f;
#pragma unroll
    for (int i = 0; i < 4; ++i) { v[i] = ldv(b[i]); ss += v[i] * v[i]; }
    ss += __shfl_xor(ss, 1);
    ss += __shfl_xor(ss, 2);
    ss += __shfl_xor(ss, 4);
    ss += __shfl_xor(ss, 8);
    const float inv = p.mult / fmaxf(sqrtf(ss), 1e-12f);
#pragma unroll
    for (int i = 0; i < 4; ++i) {
      float y = v[i] * inv;
      if (p.s1) y *= p.s1[d0 + i];
      if (p.s2) y *= p.s2[d0 + i];
      b[i] = f2b(y);
    }
    *(ushort4*)ptr = *(ushort4*)b;
  }
}

// ---------------------------------------------------------------------------
// MFMA GEMM v4 (range-dispatched, up to 3 segments per launch).
// C[M,N] = Acat[M,K] @ Bt^T (bf16; Bt [N][K]); BK=64; global_load_lds staging;
// XOR-chunk swizzle both-sides (rule #21); chunked XCD swizzle per segment.
// ep1: sigmoid-gated EMA (new_states). ep2: raw k/v rows 3584+ -> aux (fp32).
// ---------------------------------------------------------------------------
__global__ __launch_bounds__(256) void mfma_gemm(
    GemmDesc d0, int b1, GemmDesc d1, int b2, GemmDesc d2,
    const float* b_gate, const float* ema_beta, const float* init_state,
    float* aux) {
  __shared__ bf16 Asb[128][64];
  __shared__ bf16 Bsb[128][64];
  GemmDesc d;
  int local;
  {
    const int B = blockIdx.x;
    if (B < b1) { d = d0; local = B; }
    else if (B < b2) { d = d1; local = B - b1; }
    else { d = d2; local = B - b2; }
  }
  int bxi, byi;
  if (d.cw) {
    const int c = local & 7, r = local >> 3;
    const int nchx = d.nx / d.cw;
    bxi = (c % nchx) * d.cw + r % d.cw;
    byi = (c / nchx) * d.ch + r / d.cw;
  } else {
    bxi = local % d.nx;
    byi = local / d.nx;
  }
  const int bm = byi * 128, bn = bxi * 128;
  const int tid = threadIdx.x;
  const int w = tid >> 6, lane = tid & 63;
  const int wm = (w >> 1) * 64, wn = (w & 1) * 64;
  const int lr = lane & 15, quad = lane >> 4;
  const int srow = (lane >> 3);
  const int sck = ((lane & 7) ^ (lane >> 3)) * 8;

  f32x4 acc[4][4] = {};

  for (int kt = 0; kt < d.K; kt += 64) {
#pragma unroll
    for (int c = 0; c < 4; ++c) {
      const int m = (w * 4 + c) * 8 + srow;
      const int gk = kt + sck;
      const bf16* ap = (d.A2 && gk >= d.K1)
                           ? (d.A2 + (size_t)(bm + m) * d.lda2 + (gk - d.K1))
                           : (d.A + (size_t)(bm + m) * d.lda + gk);
      gload_lds16(ap, &Asb[0][0] + (w * 4 + c) * 512);
    }
#pragma unroll
    for (int c = 0; c < 4; ++c) {
      const int n = (w * 4 + c) * 8 + srow;
      gload_lds16(d.Bt + (size_t)(bn + n) * d.K + kt + sck,
                  &Bsb[0][0] + (w * 4 + c) * 512);
    }
    __syncthreads();

#pragma unroll
    for (int dc = 0; dc < 2; ++dc) {
      const int csw = (((dc * 4 + quad) ^ (lr & 7))) * 8;
      bf16x8 af[4], bfr[4];
#pragma unroll
      for (int i = 0; i < 4; ++i)
        af[i] = *(const bf16x8*)&Asb[wm + i * 16 + lr][csw];
#pragma unroll
      for (int j = 0; j < 4; ++j)
        bfr[j] = *(const bf16x8*)&Bsb[wn + j * 16 + lr][csw];
#pragma unroll
      for (int i = 0; i < 4; ++i)
#pragma unroll
        for (int j = 0; j < 4; ++j)
          acc[i][j] = __builtin_amdgcn_mfma_f32_16x16x32_bf16(af[i], bfr[j],
                                                              acc[i][j], 0, 0, 0);
    }
    __syncthreads();
  }

#pragma unroll
  for (int i = 0; i < 4; ++i) {
#pragma unroll
    for (int j = 0; j < 4; ++j) {
#pragma unroll
      for (int r = 0; r < 4; ++r) {
        const int row = bm + wm + i * 16 + quad * 4 + r;
        const int col = bn + wn + j * 16 + lr;
        float v = acc[i][j][r];
        if (d.ep == 1) {
          float z = v + b_gate[col];
          float dd = 1.f / (1.f + __expf(-ema_beta[col]));
          v = dd * z + (1.f - dd) * init_state[(size_t)row * 1024 + col];
        }
        if (d.cf32) ((float*)d.C)[(size_t)row * d.ldc + col] = v;
        else ((bf16*)d.C)[(size_t)row * d.ldc + col] = f2b(v);
        if (d.ep == 2 && row >= 3584 && col >= 1024 && col < 3072) {
          const int mm = (col - 1024) >> 10;
          const int hh = (col >> 6) & 15;
          const int dd = col & 63;
          aux[((size_t)((mm * 16 + hh) * 512 + (row - 3584))) * 64 + dd] = v;
        }
      }
    }
  }
}

// ---------------------------------------------------------------------------
// MFMA flash attention v7 (range-dispatched, 4 segments): static-max softmax,
// chunked XCD swizzle, 1-tile-ahead named-register prefetch (no arrays/lambdas
// -> no scratch demotion).
// ---------------------------------------------------------------------------
#define LOAD_KV(JT, K0, K1, V0, V1)                                        \
  {                                                                        \
    const int krow_ = kbase + (JT) + kr;                                   \
    if (krow_ >= 0) {                                                      \
      const bf16* s_ = kp + (size_t)krow_ * k_rstride + h * 64 + kc;       \
      K0 = *(const uint4*)s_;                                              \
      K1 = *(const uint4*)(s_ + 8);                                        \
    } else { K0 = z4; K1 = z4; }                                           \
    const int col_ = kbase + (JT) + kc;                                    \
    if (col_ >= 0) {                                                       \
      const bf16* s_ = vtp + (size_t)(h * 64 + kr) * v_nstride + col_;     \
      V0 = *(const uint4*)s_;                                              \
      V1 = *(const uint4*)(s_ + 8);                                        \
    } else { V0 = z4; V1 = z4; }                                           \
  }

#define STORE_KV(K0, K1, V0, V1)          \
  {                                       \
    *(uint4*)&ksb[kr][kc] = K0;           \
    *(uint4*)&ksb[kr][kc + 8] = K1;       \
    *(uint4*)&vsb[kr][kc] = V0;           \
    *(uint4*)&vsb[kr][kc + 8] = V1;       \
  }

#define LOAD_BIAS(JT, B0, B1, B2, B3)                                      \
  {                                                                        \
    const bf16* bp_ = bshufp + (((size_t)h * 512 + qt * 64 + wq +          \
                                quad * 4) * 16 + ((JT) >> 6)) * 64 + lr * 4; \
    B0 = *(const ushort4*)bp_;                                             \
    B1 = *(const ushort4*)(bp_ + 1024);                                    \
    B2 = *(const ushort4*)(bp_ + 2048);                                    \
    B3 = *(const ushort4*)(bp_ + 3072);                                    \
  }

__global__ __launch_bounds__(256, 4) void attn_mfma(
    AttnDesc d0, int b1, AttnDesc d1, int b2, AttnDesc d2, int b3, AttnDesc d3) {
  __shared__ __align__(16) bf16 ksb[64][72];  // [krow][d]
  __shared__ __align__(16) bf16 vsb[64][72];  // [d][krow]
  __shared__ __align__(16) bf16 psb[64][72];  // [qrow][kcol]
  AttnDesc d;
  int local;
  {
    const int B = blockIdx.x;
    if (B < b1) { d = d0; local = B; }
    else if (B < b2) { d = d1; local = B - b1; }
    else if (B < b3) { d = d2; local = B - b2; }
    else { d = d3; local = B - b3; }
  }
  const bf16* qp = d.qp;
  const int q_rstride = d.q_rstride;
  const bf16* kp = d.kp;
  const int k_rstride = d.k_rstride;
  const bf16* vtp = d.vtp;
  const int v_nstride = d.v_nstride;
  const bf16* bshufp = d.bshuf;
  const int causal = d.causal;

  const int Bp = (local & 7) * (d.nblk >> 3) + (local >> 3);
  const int zb = Bp % d.nzb;
  const int qt = (Bp / d.nzb) % d.nqt;
  const int h = Bp / (d.nzb * d.nqt);
  const int tid = threadIdx.x;
  const int w = tid >> 6, lane = tid & 63;
  const int lr = lane & 15, quad = lane >> 4;
  const int wq = w * 16;
  const int qbase = zb * d.qrows_per_blk + qt * 64;

  bf16x8 qf0, qf1;
  {
    const bf16* qr = qp + (size_t)(qbase + wq + lr) * q_rstride + h * 64 + quad * 8;
    qf0 = *(const bf16x8*)qr;
    qf1 = *(const bf16x8*)(qr + 32);
  }

  float l_i[4] = {0.f, 0.f, 0.f, 0.f};
  f32x4 o_acc[4] = {};

  const int kbase = d.kbase0 + zb * d.krows_per_blk;
  const int ntk = causal ? min(d.nkeys, qt * 64 + 64 + 512) : d.nkeys;
  const int kr = tid >> 2, kc = (tid & 3) * 16;

  const uint4 z4{0, 0, 0, 0};
  uint4 ka0, ka1, va0, va1;
  ushort4 bc0{0,0,0,0}, bc1{0,0,0,0}, bc2{0,0,0,0}, bc3{0,0,0,0};

  LOAD_KV(0, ka0, ka1, va0, va1);
  if (bshufp) LOAD_BIAS(0, bc0, bc1, bc2, bc3);
  STORE_KV(ka0, ka1, va0, va1);

  for (int jt = 0; jt < ntk; jt += 64) {
    __syncthreads();
    const bool pre = jt + 64 < ntk;
    ushort4 bn0{0,0,0,0}, bn1{0,0,0,0}, bn2{0,0,0,0}, bn3{0,0,0,0};
    if (pre) {
      LOAD_KV(jt + 64, ka0, ka1, va0, va1);
      if (bshufp) LOAD_BIAS(jt + 64, bn0, bn1, bn2, bn3);
    }

    // ---- S[16x64] = Q @ K^T ----
    f32x4 s_acc[4] = {};
#pragma unroll
    for (int j = 0; j < 4; ++j) {
      bf16x8 kf = *(const bf16x8*)&ksb[j * 16 + lr][quad * 8];
      s_acc[j] = __builtin_amdgcn_mfma_f32_16x16x32_bf16(qf0, kf, s_acc[j], 0, 0, 0);
    }
#pragma unroll
    for (int j = 0; j < 4; ++j) {
      bf16x8 kf = *(const bf16x8*)&ksb[j * 16 + lr][32 + quad * 8];
      s_acc[j] = __builtin_amdgcn_mfma_f32_16x16x32_bf16(qf1, kf, s_acc[j], 0, 0, 0);
    }

    // ---- bias + causal + static-max softmax (no cross-lane ops) ----
#pragma unroll
    for (int r = 0; r < 4; ++r) {
      const int brow = wq + quad * 4 + r;
      const int qloc = qt * 64 + brow;
      float sv0 = s_acc[0][r], sv1 = s_acc[1][r], sv2 = s_acc[2][r], sv3 = s_acc[3][r];
      if (bshufp) {
        ushort4 bw = (r == 0) ? bc0 : (r == 1) ? bc1 : (r == 2) ? bc2 : bc3;
        bf16 bb[4];
        *(ushort4*)bb = bw;
        sv0 += ldv(bb[0]); sv1 += ldv(bb[1]); sv2 += ldv(bb[2]); sv3 += ldv(bb[3]);
      }
      if (causal) {
        const int lim = qloc + 512;
        if (jt + 0 * 16 + lr > lim) sv0 = -3.0e38f;
        if (jt + 1 * 16 + lr > lim) sv1 = -3.0e38f;
        if (jt + 2 * 16 + lr > lim) sv2 = -3.0e38f;
        if (jt + 3 * 16 + lr > lim) sv3 = -3.0e38f;
      }
      const float p0 = __expf(sv0 - 12.f), p1 = __expf(sv1 - 12.f);
      const float p2 = __expf(sv2 - 12.f), p3 = __expf(sv3 - 12.f);
      l_i[r] += (p0 + p1) + (p2 + p3);
      psb[brow][0 * 16 + lr] = f2b(p0);
      psb[brow][1 * 16 + lr] = f2b(p1);
      psb[brow][2 * 16 + lr] = f2b(p2);
      psb[brow][3 * 16 + lr] = f2b(p3);
    }

    // ---- O[16x64] += P @ V (psb rows wave-private; DS in-order per wave) ----
#pragma unroll
    for (int jc = 0; jc < 2; ++jc) {
      bf16x8 pf = *(const bf16x8*)&psb[wq + lr][jc * 32 + quad * 8];
#pragma unroll
      for (int dt = 0; dt < 4; ++dt) {
        bf16x8 vf = *(const bf16x8*)&vsb[dt * 16 + lr][jc * 32 + quad * 8];
        o_acc[dt] = __builtin_amdgcn_mfma_f32_16x16x32_bf16(pf, vf, o_acc[dt], 0, 0, 0);
      }
    }

    __syncthreads();
    if (pre) {
      STORE_KV(ka0, ka1, va0, va1);
      if (bshufp) { bc0 = bn0; bc1 = bn1; bc2 = bn2; bc3 = bn3; }
    }
  }

  // ---- epilogue: finish the (linear) l reduction across the 16-lane group ----
#pragma unroll
  for (int r = 0; r < 4; ++r) {
#pragma unroll
    for (int mm = 1; mm < 16; mm <<= 1) l_i[r] += __shfl_xor(l_i[r], mm);
    const int qrow = qbase + wq + quad * 4 + r;
    const float invl = 1.f / l_i[r];
    bf16* orow = d.op + (size_t)qrow * d.o_rstride + d.o_coff + (size_t)h * d.o_hstride;
#pragma unroll
    for (int dt = 0; dt < 4; ++dt) orow[dt * 16 + lr] = f2b(o_acc[dt][r] * invl);
  }
}

// ---------------------------------------------------------------------------
extern "C" void kernel_launch(void* const* d_in, const int* in_sizes, int n_in,
                              void* d_out, int out_size, void* d_ws, size_t ws_size,
                              hipStream_t stream) {
  const float* x = (const float*)d_in[0];
  const float* rel_bias = (const float*)d_in[1];
  const float* gamma = (const float*)d_in[2];
  const float* w_qkv = (const float*)d_in[3];
  const float* q_scale = (const float*)d_in[4];
  const float* k_scale = (const float*)d_in[5];
  const float* w_out = (const float*)d_in[6];
  const float* s_gamma = (const float*)d_in[7];
  const float* w_q2s = (const float*)d_in[8];
  const float* w_qfs = (const float*)d_in[9];
  const float* w_sqkv = (const float*)d_in[10];
  const float* init_state = (const float*)d_in[11];
  const float* state_pos = (const float*)d_in[12];
  const float* w_sout = (const float*)d_in[13];
  const float* ts_qs = (const float*)d_in[14];
  const float* ts_ks = (const float*)d_in[15];
  const float* ss_qs = (const float*)d_in[16];
  const float* ss_ks = (const float*)d_in[17];
  const float* fs_qs = (const float*)d_in[18];
  const float* fs_ks = (const float*)d_in[19];
  const float* w_gate = (const float*)d_in[20];
  const float* b_gate = (const float*)d_in[21];
  const float* ema_beta = (const float*)d_in[22];

  // outputs: FP32
  float* out0 = (float*)d_out;         // [4096,1024]
  float* out_mem = out0 + 4194304;     // [2,16,512,64]
  float* out_ns = out0 + 5242880;      // [512,1024]

  // workspace (bf16 intermediates), 64 MiB total
  bf16* xn = (bf16*)d_ws;          // 4096x1024 (reused: vT_loc, then wT_out/sout)
  bf16* proj = xn + 4194304;       // 4096x4096: [q|k|v|q2s] cols 0/1024/2048/3072
  bf16* aloc = proj + 16777216;    // 4096x1024
  bf16* ats = aloc + 4194304;      // 4096x1024
  bf16* st = ats + 4194304;        // 512x1024 (later reused as vT_s)
  bf16* sqkv = st + 524288;        // 512x3072 (q/k parts l2norm'd in place)
  bf16* qfs = sqkv + 1572864;      // 512x1024 (l2norm'd in place)
  bf16* socat = qfs + 524288;      // 512x2048
  bf16* soproj = socat + 1048576;  // 512x1024 (early reuse: ist16)
  bf16* vT_loc = xn;               // [16*64][4096] after proj gemm consumes xn
  bf16* vT_s = st;                 // [16*64][512]  after qfs gemm consumes st
  bf16* ist16 = soproj;            // bf16 copy of init_state (dead before soproj)

  // out0 region as bf16 scratch: early transposed weights, then bshuf
  bf16* out0b = (bf16*)out0;
  bf16* wT_qkv = out0b;                 // 3072x1024 (rows 0-3071 of fused Bt)
  bf16* wT_q2s = wT_qkv + 3145728;      // 1024x1024 (rows 3072-4095, contiguous)
  bf16* wT_sqkv = wT_q2s + 1048576;     // 3072x1024
  bf16* wT_qfs = wT_sqkv + 3145728;     // 1024x1024
  bf16* bshuf = out0b;                  // [16][512][16][64] bf16 (after GEMMs)
  bf16* wT_out = xn;                    // 2048x1024 (vT_loc dead after attns)
  bf16* wT_sout = xn + 2097152;         // 2048x1024
  bf16* wT_gate = proj;                 // 1024x1024 (proj dead after attns)

  // 1. ln(x) + ln(init_state, +raw ist16) + early weight transposes
  {
    WtPart pa{w_qkv, 3072, wT_qkv, 1024};
    WtPart pb{w_q2s, 1024, wT_q2s, 1024};
    WtPart pc{w_sqkv, 3072, wT_sqkv, 1024};
    WtPart pd{w_qfs, 1024, wT_qfs, 1024};
    pre_kernel<<<6656, 256, 0, stream>>>(
        4096, 4608,
        x, gamma, nullptr, xn, nullptr,
        init_state, s_gamma, state_pos, st, ist16,
        16, pa, 48, pb, 64, pc, 112, pd);
  }

  // 2. projections fused: proj(qkv+q2s, ep2 side-writes out_mem) + sqkv + qfs
  {
    GemmDesc dp{xn, 1024, nullptr, 0, 0, wT_qkv, proj, 4096, 1024,
                32, 16, 8, 2, 0, 1024};
    GemmDesc ds{ist16, 1024, nullptr, 0, 0, wT_sqkv, sqkv, 3072, 1024,
                24, 0, 0, 0, 0, 96};
    GemmDesc dq{st, 1024, nullptr, 0, 0, wT_qfs, qfs, 1024, 1024,
                8, 0, 0, 0, 0, 32};
    mfma_gemm<<<1152, 256, 0, stream>>>(dp, 1024, ds, 1120, dq,
                                        b_gate, ema_beta, init_state, out_mem);
  }

  // 3. prep fused: V transposes + bias shuffle (out0 free now) + l2norms
  {
    L2nPart p0{proj, 4096, 0, q_scale, k_scale, 8.f};
    L2nPart p1{proj, 4096, 1024, nullptr, nullptr, 1.f};
    L2nPart p2{proj, 4096, 3072, ts_qs, ts_ks, 8.f};
    L2nPart p3{sqkv, 3072, 0, ss_qs, ss_ks, 8.f};
    L2nPart p4{sqkv, 3072, 1024, nullptr, nullptr, 1.f};
    L2nPart p5{qfs, 1024, 0, fs_qs, fs_ks, 8.f};
    prep_kernel<<<6656, 256, 0, stream>>>(
        proj, 4096, 2048, 4096, vT_loc,
        sqkv, 3072, 2048, 512, vT_s,
        rel_bias, bshuf, p0, p1, p2, p3, p4, p5);
  }

  // 4. attentions fused (4 segments; bases %8==0 keep XCD swizzles valid)
  {
    AttnDesc a1{proj, 4096, proj + 1024, 4096, vT_loc, 4096, bshuf,
                1, 1024, 512, -512, 512, 8, 8, 1024, aloc, 1024, 0, 64};
    AttnDesc a2{proj + 3072, 4096, sqkv + 1024, 3072, vT_s, 512, nullptr,
                0, 512, 4096, 0, 0, 64, 1, 1024, ats, 1024, 0, 64};
    AttnDesc a3{sqkv, 3072, sqkv + 1024, 3072, vT_s, 512, nullptr,
                0, 512, 512, 0, 0, 8, 1, 128, socat, 2048, 0, 128};
    AttnDesc a4{qfs, 1024, proj + 1024, 4096, vT_loc, 4096, nullptr,
                0, 512, 512, 3584, 0, 8, 1, 128, socat, 2048, 64, 128};
    attn_mfma<<<2304, 256, 0, stream>>>(a1, 1024, a2, 2048, a3, 2176, a4);
  }

  // 5. late weight transposes (vT_loc/proj regions now dead)
  {
    WtPart pa{w_out, 1024, wT_out, 2048};
    WtPart pb{w_sout, 1024, wT_sout, 2048};
    WtPart pc{w_gate, 1024, wT_gate, 1024};
    pre_kernel<<<1536, 256, 0, stream>>>(
        0, 0,
        nullptr, nullptr, nullptr, nullptr, nullptr,
        nullptr, nullptr, nullptr, nullptr, nullptr,
        32, pa, 16, pb, 32, pc, 48, pc);
  }

  // 6. out0 = [aloc|ats] @ w_out (fp32, overwrites bshuf) + soproj = socat @ w_sout
  {
    GemmDesc da{aloc, 1024, ats, 1024, 1024, wT_out, out0, 1024, 2048,
                8, 8, 4, 0, 1, 256};
    GemmDesc db{socat, 2048, nullptr, 0, 0, wT_sout, soproj, 1024, 2048,
                8, 0, 0, 0, 0, 32};
    mfma_gemm<<<288, 256, 0, stream>>>(da, 256, db, 288, db,
                                       b_gate, ema_beta, init_state, nullptr);
  }

  // 7. new_states = EMA-gate(soproj @ w_gate) (fp32 out)
  {
    GemmDesc dg{soproj, 1024, nullptr, 0, 0, wT_gate, out_ns, 1024, 1024,
                8, 0, 0, 1, 1, 32};
    mfma_gemm<<<32, 256, 0, stream>>>(dg, 32, dg, 32, dg,
                                      b_gate, ema_beta, init_state, nullptr);
  }
}